// Round 1
// baseline (1266.841 us; speedup 1.0000x reference)
//
#include <hip/hip_runtime.h>
#include <math.h>

// Problem constants (fixed shapes from the reference)
constexpr int CN = 256;        // channels
constexpr int NHEAD = 8;       // attention heads
constexpr int KPG = 88;        // nodes per graph
constexpr int NIDF = 16;       // input node features
constexpr int GATE_DIM = 128;
constexpr int ACT_DIM = 4644;

// ---------------------------------------------------------------------------
// CSR build: count -> scan -> fill
// ---------------------------------------------------------------------------
__global__ void count_kernel(const int* __restrict__ dst, int* __restrict__ cnt, int E) {
    int e = blockIdx.x * 256 + threadIdx.x;
    if (e < E) atomicAdd(&cnt[dst[e]], 1);
}

__global__ __launch_bounds__(1024) void scan_kernel(const int* __restrict__ cnt,
                                                    int* __restrict__ rowptr, int n) {
    __shared__ int buf[1024];
    __shared__ int running_s;
    int tid = threadIdx.x;
    if (tid == 0) running_s = 0;
    __syncthreads();
    for (int base = 0; base < n; base += 1024) {
        int i = base + tid;
        int v = (i < n) ? cnt[i] : 0;
        buf[tid] = v;
        __syncthreads();
        for (int off = 1; off < 1024; off <<= 1) {
            int t = (tid >= off) ? buf[tid - off] : 0;
            __syncthreads();
            buf[tid] += t;
            __syncthreads();
        }
        if (i < n) rowptr[i] = running_s + buf[tid] - v;  // exclusive
        int tot = buf[1023];
        __syncthreads();
        if (tid == 0) running_s += tot;
        __syncthreads();
    }
    if (tid == 0) rowptr[n] = running_s;
}

__global__ void fill_kernel(const int* __restrict__ src, const int* __restrict__ dst,
                            const int* __restrict__ rowptr, int* __restrict__ cursor,
                            int* __restrict__ csrc, int E) {
    int e = blockIdx.x * 256 + threadIdx.x;
    if (e < E) {
        int d = dst[e];
        int p = atomicAdd(&cursor[d], 1);
        csrc[rowptr[d] + p] = src[e];
    }
}

// ---------------------------------------------------------------------------
// Embedding: h = relu(x @ W_emb + b_emb) + pos_emb[n % 88]
// block = 256 threads (one per channel), 16 nodes per block
// ---------------------------------------------------------------------------
__global__ __launch_bounds__(256) void embed_kernel(const float* __restrict__ x,
                                                    const float* __restrict__ Wemb,
                                                    const float* __restrict__ bemb,
                                                    const float* __restrict__ pos,
                                                    float* __restrict__ h) {
    __shared__ float Wl[NIDF][CN];  // 16 KB
    int tid = threadIdx.x;
    for (int i = tid; i < NIDF * CN; i += 256) Wl[i >> 8][i & 255] = Wemb[i];
    __syncthreads();
    float bias = bemb[tid];
    int node0 = blockIdx.x * 16;
    for (int q = 0; q < 16; ++q) {
        int n = node0 + q;
        float acc = bias;
        #pragma unroll
        for (int k = 0; k < NIDF; ++k) acc += x[n * NIDF + k] * Wl[k][tid];
        h[(size_t)n * CN + tid] = fmaxf(acc, 0.f) + pos[(n % KPG) * CN + tid];
    }
}

// ---------------------------------------------------------------------------
// Generic fp32 SGEMM: C[M,N] = A[M,K] @ B[K,N] (+bias). BM=BN=64, BK=16,
// 256 threads, 4x4 micro-tile. M % 64 == 0 assumed; N guarded.
// ---------------------------------------------------------------------------
template <bool BIAS>
__global__ __launch_bounds__(256) void sgemm64(const float* __restrict__ A,
                                               const float* __restrict__ B,
                                               const float* __restrict__ bias,
                                               float* __restrict__ Cm,
                                               int M, int N, int K) {
    __shared__ float As[16][68];
    __shared__ float Bs[16][68];
    int tid = threadIdx.x;
    int row0 = blockIdx.x * 64;
    int col0 = blockIdx.y * 64;
    int tm = tid >> 4, tn = tid & 15;
    float acc[4][4] = {};

    int ar = tid >> 2;            // row in A tile (0..63)
    int akq = (tid & 3) * 4;      // k quad
    int bkk = tid >> 6;           // k row for B loads (0..3)
    int bcc = tid & 63;           // col in B tile

    for (int k0 = 0; k0 < K; k0 += 16) {
        float4 av = *reinterpret_cast<const float4*>(A + (size_t)(row0 + ar) * K + k0 + akq);
        As[akq + 0][ar] = av.x;
        As[akq + 1][ar] = av.y;
        As[akq + 2][ar] = av.z;
        As[akq + 3][ar] = av.w;
        #pragma unroll
        for (int i = 0; i < 4; ++i) {
            int kk = bkk + i * 4;
            int col = col0 + bcc;
            Bs[kk][bcc] = (col < N) ? B[(size_t)(k0 + kk) * N + col] : 0.f;
        }
        __syncthreads();
        #pragma unroll
        for (int kk = 0; kk < 16; ++kk) {
            float4 a4 = *reinterpret_cast<const float4*>(&As[kk][tm * 4]);
            float4 b4 = *reinterpret_cast<const float4*>(&Bs[kk][tn * 4]);
            float a[4] = {a4.x, a4.y, a4.z, a4.w};
            float b[4] = {b4.x, b4.y, b4.z, b4.w};
            #pragma unroll
            for (int i = 0; i < 4; ++i)
                #pragma unroll
                for (int j = 0; j < 4; ++j) acc[i][j] += a[i] * b[j];
        }
        __syncthreads();
    }
    #pragma unroll
    for (int i = 0; i < 4; ++i) {
        int row = row0 + tm * 4 + i;
        #pragma unroll
        for (int j = 0; j < 4; ++j) {
            int col = col0 + tn * 4 + j;
            if (col < N) {
                float r = acc[i][j];
                if (BIAS) r += bias[col];
                Cm[(size_t)row * N + col] = r;
            }
        }
    }
}

// ---------------------------------------------------------------------------
// GAT aggregation (one block per destination node, 256 threads = channels):
// e_h = sum_d leaky(xl[src]+xr[dst]) * att ; online segment softmax per head;
// out = sum alpha * xl[src]; then +bias, relu, residual, layernorm -> h
// ---------------------------------------------------------------------------
__global__ __launch_bounds__(256) void gat_aggregate(
    const float* __restrict__ xl, const float* __restrict__ xr,
    const int* __restrict__ rowptr, const int* __restrict__ csrc,
    const float* __restrict__ att, const float* __restrict__ bias,
    const float* __restrict__ lng, const float* __restrict__ lnb,
    float* __restrict__ h) {
    constexpr int CHUNK = 64;
    __shared__ float xr_l[CN], att_l[CN];
    __shared__ float e_lds[CHUNK][NHEAD];
    __shared__ int srcbuf[CHUNK];
    __shared__ float m_sh[NHEAD], s_sh[NHEAD], f_sh[NHEAD];
    __shared__ float rsum[4], rsq[4];

    int n = blockIdx.x;
    int tid = threadIdx.x;
    int head = tid >> 5;
    int lane = tid & 63;
    int wid = tid >> 6;

    xr_l[tid] = xr[(size_t)n * CN + tid];
    att_l[tid] = att[tid];
    if (tid < NHEAD) { m_sh[tid] = -INFINITY; s_sh[tid] = 0.f; }
    int e0 = rowptr[n], e1 = rowptr[n + 1];
    float hres = h[(size_t)n * CN + tid];
    float acc = 0.f;
    __syncthreads();

    for (int cs = e0; cs < e1; cs += CHUNK) {
        int cnt = min(CHUNK, e1 - cs);
        if (tid < cnt) srcbuf[tid] = csrc[cs + tid];
        __syncthreads();
        // e per edge, wave-parallel (4 waves)
        for (int je = wid; je < cnt; je += 4) {
            const float* xls = xl + (size_t)srcbuf[je] * CN;
            #pragma unroll
            for (int i = 0; i < 4; ++i) {
                int cc = i * 64 + lane;
                float z = xls[cc] + xr_l[cc];
                z = z >= 0.f ? z : 0.2f * z;
                float p = z * att_l[cc];
                p += __shfl_xor(p, 16); p += __shfl_xor(p, 8);
                p += __shfl_xor(p, 4);  p += __shfl_xor(p, 2); p += __shfl_xor(p, 1);
                if ((lane & 31) == 0) e_lds[je][i * 2 + (lane >> 5)] = p;
            }
        }
        __syncthreads();
        // per-head online softmax bookkeeping (8 threads, cnt is small)
        if (tid < NHEAD) {
            float m_old = m_sh[tid];
            float cm = m_old;
            for (int je = 0; je < cnt; ++je) cm = fmaxf(cm, e_lds[je][tid]);
            float f = (m_old == -INFINITY) ? 0.f : expf(m_old - cm);
            float s = s_sh[tid] * f;
            for (int je = 0; je < cnt; ++je) {
                float w = expf(e_lds[je][tid] - cm);
                e_lds[je][tid] = w;
                s += w;
            }
            m_sh[tid] = cm; s_sh[tid] = s; f_sh[tid] = f;
        }
        __syncthreads();
        acc *= f_sh[head];
        for (int je = 0; je < cnt; ++je)
            acc += e_lds[je][head] * xl[(size_t)srcbuf[je] * CN + tid];
        __syncthreads();
    }

    float out = acc / s_sh[head] + bias[tid];
    float v = hres + fmaxf(out, 0.f);
    // LayerNorm over 256 channels
    float sum = v, sq = v * v;
    #pragma unroll
    for (int o = 32; o; o >>= 1) { sum += __shfl_xor(sum, o); sq += __shfl_xor(sq, o); }
    if (lane == 0) { rsum[wid] = sum; rsq[wid] = sq; }
    __syncthreads();
    sum = rsum[0] + rsum[1] + rsum[2] + rsum[3];
    sq  = rsq[0] + rsq[1] + rsq[2] + rsq[3];
    float mu = sum / CN;
    float var = sq / CN - mu * mu;
    float inv = rsqrtf(var + 1e-5f);
    h[(size_t)n * CN + tid] = (v - mu) * inv * lng[tid] + lnb[tid];
}

// ---------------------------------------------------------------------------
// Gate: gate[n] = relu(h[n] @ gW1 + gb1) @ gW2 + gb2 ; 8 nodes per block
// ---------------------------------------------------------------------------
__global__ __launch_bounds__(256) void gate_kernel(const float* __restrict__ h,
    const float* __restrict__ gW1, const float* __restrict__ gb1,
    const float* __restrict__ gW2, const float* __restrict__ gb2,
    float* __restrict__ gate) {
    __shared__ float hrows[8][CN];   // 8 KB
    __shared__ float part[4][4];
    int tid = threadIdx.x;
    int j = tid & 127, half = tid >> 7;
    int n0 = blockIdx.x * 8;
    for (int i = tid; i < 8 * CN; i += 256) hrows[i >> 8][i & 255] = h[(size_t)n0 * CN + i];
    __syncthreads();
    float t[4] = {};
    for (int k = 0; k < CN; ++k) {
        float w = gW1[k * GATE_DIM + j];
        #pragma unroll
        for (int q = 0; q < 4; ++q) t[q] += hrows[half * 4 + q][k] * w;
    }
    float b1 = gb1[j], w2 = gW2[j];
    float contrib[4];
    #pragma unroll
    for (int q = 0; q < 4; ++q) contrib[q] = fmaxf(t[q] + b1, 0.f) * w2;
    #pragma unroll
    for (int q = 0; q < 4; ++q)
        #pragma unroll
        for (int o = 32; o; o >>= 1) contrib[q] += __shfl_xor(contrib[q], o);
    int wid = tid >> 6, lane = tid & 63;
    if (lane == 0)
        for (int q = 0; q < 4; ++q) part[wid][q] = contrib[q];
    __syncthreads();
    if (tid < 8) {
        int hh = tid >> 2, q = tid & 3;
        gate[n0 + hh * 4 + q] = part[hh * 2][q] + part[hh * 2 + 1][q] + gb2[0];
    }
}

// ---------------------------------------------------------------------------
// Pool: segment softmax over contiguous 88-node graphs + weighted sum -> emb
// ---------------------------------------------------------------------------
__global__ __launch_bounds__(256) void pool_kernel(const float* __restrict__ gate,
                                                   const float* __restrict__ h,
                                                   float* __restrict__ emb) {
    __shared__ float a[KPG];
    __shared__ float wm[4];
    int g = blockIdx.x, tid = threadIdx.x;
    int wid = tid >> 6, lane = tid & 63;
    float gv = (tid < KPG) ? gate[g * KPG + tid] : -INFINITY;
    float m = gv;
    #pragma unroll
    for (int o = 32; o; o >>= 1) m = fmaxf(m, __shfl_xor(m, o));
    if (lane == 0) wm[wid] = m;
    __syncthreads();
    m = fmaxf(fmaxf(wm[0], wm[1]), fmaxf(wm[2], wm[3]));
    __syncthreads();
    float av = (tid < KPG) ? expf(gv - m) : 0.f;
    if (tid < KPG) a[tid] = av;
    float s = av;
    #pragma unroll
    for (int o = 32; o; o >>= 1) s += __shfl_xor(s, o);
    if (lane == 0) wm[wid] = s;
    __syncthreads();
    s = wm[0] + wm[1] + wm[2] + wm[3];
    float inv = 1.f / s;
    float acc = 0.f;
    const float* hg = h + (size_t)g * KPG * CN;
    for (int i = 0; i < KPG; ++i) acc += a[i] * hg[i * CN + tid];
    emb[(size_t)g * CN + tid] = acc * inv;
}

// ---------------------------------------------------------------------------
// Heads: t1 = relu(LN(emb@pW1+pb1)); value = tanh(relu(emb@vW1+vb1)@vW2+vb2)
// one block per graph
// ---------------------------------------------------------------------------
__global__ __launch_bounds__(256) void head_kernel(const float* __restrict__ emb,
    const float* __restrict__ pW1, const float* __restrict__ pb1,
    const float* __restrict__ plng, const float* __restrict__ plnb,
    const float* __restrict__ vW1, const float* __restrict__ vb1,
    const float* __restrict__ vW2, const float* __restrict__ vb2,
    float* __restrict__ t1, float* __restrict__ value_out) {
    __shared__ float e_l[CN];
    __shared__ float rsum[4], rsq[4];
    int g = blockIdx.x, tid = threadIdx.x;
    int wid = tid >> 6, lane = tid & 63;
    e_l[tid] = emb[(size_t)g * CN + tid];
    __syncthreads();
    float p = pb1[tid], v = vb1[tid];
    for (int k = 0; k < CN; ++k) {
        float e = e_l[k];
        p += e * pW1[k * CN + tid];
        v += e * vW1[k * CN + tid];
    }
    // LN(p)
    float sum = p, sq = p * p;
    #pragma unroll
    for (int o = 32; o; o >>= 1) { sum += __shfl_xor(sum, o); sq += __shfl_xor(sq, o); }
    if (lane == 0) { rsum[wid] = sum; rsq[wid] = sq; }
    __syncthreads();
    sum = rsum[0] + rsum[1] + rsum[2] + rsum[3];
    sq  = rsq[0] + rsq[1] + rsq[2] + rsq[3];
    float mu = sum / CN;
    float var = sq / CN - mu * mu;
    float inv = rsqrtf(var + 1e-5f);
    t1[(size_t)g * CN + tid] = fmaxf((p - mu) * inv * plng[tid] + plnb[tid], 0.f);
    // value head
    float contrib = fmaxf(v, 0.f) * vW2[tid];
    __syncthreads();
    #pragma unroll
    for (int o = 32; o; o >>= 1) contrib += __shfl_xor(contrib, o);
    if (lane == 0) rsum[wid] = contrib;
    __syncthreads();
    if (tid == 0)
        value_out[g] = tanhf(rsum[0] + rsum[1] + rsum[2] + rsum[3] + vb2[0]);
}

// ---------------------------------------------------------------------------
extern "C" void kernel_launch(void* const* d_in, const int* in_sizes, int n_in,
                              void* d_out, int out_size, void* d_ws, size_t ws_size,
                              hipStream_t stream) {
    const float* x        = (const float*)d_in[0];
    const int*   ei       = (const int*)d_in[1];
    const float* W_emb    = (const float*)d_in[4];
    const float* b_emb    = (const float*)d_in[5];
    const float* pos_emb  = (const float*)d_in[6];
    const float* gat_Wsrc = (const float*)d_in[7];
    const float* gat_Wdst = (const float*)d_in[8];
    const float* gat_att  = (const float*)d_in[9];
    const float* gat_bias = (const float*)d_in[10];
    const float* ln_g     = (const float*)d_in[11];
    const float* ln_b     = (const float*)d_in[12];
    const float* gW1      = (const float*)d_in[13];
    const float* gb1      = (const float*)d_in[14];
    const float* gW2      = (const float*)d_in[15];
    const float* gb2      = (const float*)d_in[16];
    const float* pW1      = (const float*)d_in[17];
    const float* pb1      = (const float*)d_in[18];
    const float* p_ln_g   = (const float*)d_in[19];
    const float* p_ln_b   = (const float*)d_in[20];
    const float* pW2      = (const float*)d_in[21];
    const float* pb2      = (const float*)d_in[22];
    const float* vW1      = (const float*)d_in[23];
    const float* vb1      = (const float*)d_in[24];
    const float* vW2      = (const float*)d_in[25];
    const float* vb2      = (const float*)d_in[26];

    const int N = in_sizes[2];      // 22528
    const int E = in_sizes[1] / 2;  // 382976
    const int G = N / KPG;          // 256

    char* ws = (char*)d_ws;
    size_t off = 0;
    auto alloc = [&](size_t nbytes) {
        void* pp = ws + off;
        off = (off + nbytes + 255) & ~(size_t)255;
        return pp;
    };
    float* h      = (float*)alloc((size_t)N * CN * 4);
    float* xl     = (float*)alloc((size_t)N * CN * 4);
    float* xr     = (float*)alloc((size_t)N * CN * 4);
    float* gate   = (float*)alloc((size_t)N * 4);
    float* emb    = (float*)alloc((size_t)G * CN * 4);
    float* t1     = (float*)alloc((size_t)G * CN * 4);
    int*   rowptr = (int*)alloc((size_t)(N + 1) * 4);
    int*   cnt    = (int*)alloc((size_t)N * 4);
    int*   cursor = (int*)alloc((size_t)N * 4);
    int*   csrc   = (int*)alloc((size_t)E * 4);

    const int* e_src = ei;
    const int* e_dst = ei + E;

    hipMemsetAsync(cnt, 0, (size_t)N * 4, stream);
    hipMemsetAsync(cursor, 0, (size_t)N * 4, stream);
    count_kernel<<<(E + 255) / 256, 256, 0, stream>>>(e_dst, cnt, E);
    scan_kernel<<<1, 1024, 0, stream>>>(cnt, rowptr, N);
    fill_kernel<<<(E + 255) / 256, 256, 0, stream>>>(e_src, e_dst, rowptr, cursor, csrc, E);
    embed_kernel<<<N / 16, 256, 0, stream>>>(x, W_emb, b_emb, pos_emb, h);

    for (int l = 0; l < 4; ++l) {
        dim3 g1(N / 64, CN / 64);
        sgemm64<false><<<g1, 256, 0, stream>>>(h, gat_Wsrc + (size_t)l * CN * CN, nullptr, xl, N, CN, CN);
        sgemm64<false><<<g1, 256, 0, stream>>>(h, gat_Wdst + (size_t)l * CN * CN, nullptr, xr, N, CN, CN);
        gat_aggregate<<<N, 256, 0, stream>>>(xl, xr, rowptr, csrc,
            gat_att + l * CN, gat_bias + l * CN, ln_g + l * CN, ln_b + l * CN, h);
    }

    gate_kernel<<<N / 8, 256, 0, stream>>>(h, gW1, gb1, gW2, gb2, gate);
    pool_kernel<<<G, 256, 0, stream>>>(gate, h, emb);

    float* policy = (float*)d_out;
    float* value  = (float*)d_out + (size_t)G * ACT_DIM;
    head_kernel<<<G, 256, 0, stream>>>(emb, pW1, pb1, p_ln_g, p_ln_b,
                                       vW1, vb1, vW2, vb2, t1, value);
    dim3 g2(G / 64, (ACT_DIM + 63) / 64);
    sgemm64<true><<<g2, 256, 0, stream>>>(t1, pW2, pb2, policy, G, ACT_DIM, CN);
}

// Round 2
// 1105.396 us; speedup vs baseline: 1.1461x; 1.1461x over previous
//
#include <hip/hip_runtime.h>
#include <math.h>

constexpr int CN = 256;        // channels
constexpr int NHEAD = 8;       // attention heads
constexpr int KPG = 88;        // nodes per graph
constexpr int NIDF = 16;       // input node features
constexpr int GATE_DIM = 128;
constexpr int ACT_DIM = 4644;

// ---------------------------------------------------------------------------
// CSR build: count -> hierarchical scan -> fill (csrc + cdst)
// ---------------------------------------------------------------------------
__global__ void count_kernel(const int* __restrict__ dst, int* __restrict__ cnt, int E) {
    int e = blockIdx.x * 256 + threadIdx.x;
    if (e < E) atomicAdd(&cnt[dst[e]], 1);
}

__global__ __launch_bounds__(1024) void scan1_kernel(const int* __restrict__ cnt,
                                                     int* __restrict__ rowptr,
                                                     int* __restrict__ btot, int n) {
    __shared__ int buf[1024];
    int tid = threadIdx.x;
    int i = blockIdx.x * 1024 + tid;
    int v = (i < n) ? cnt[i] : 0;
    buf[tid] = v;
    __syncthreads();
    for (int off = 1; off < 1024; off <<= 1) {
        int t = (tid >= off) ? buf[tid - off] : 0;
        __syncthreads();
        buf[tid] += t;
        __syncthreads();
    }
    if (i < n) rowptr[i] = buf[tid] - v;  // block-local exclusive
    if (tid == 1023) btot[blockIdx.x] = buf[1023];
}

__global__ void scan2_kernel(int* __restrict__ btot, int nb) {
    if (threadIdx.x == 0 && blockIdx.x == 0) {
        int s = 0;
        for (int b = 0; b < nb; ++b) { int t = btot[b]; btot[b] = s; s += t; }
        btot[nb] = s;
    }
}

__global__ __launch_bounds__(1024) void scan3_kernel(int* __restrict__ rowptr,
                                                     const int* __restrict__ btot,
                                                     int n, int nb) {
    int i = blockIdx.x * 1024 + threadIdx.x;
    if (i < n) rowptr[i] += btot[i >> 10];
    else if (i == n) rowptr[n] = btot[nb];
}

__global__ void fill_kernel(const int* __restrict__ src, const int* __restrict__ dst,
                            const int* __restrict__ rowptr, int* __restrict__ cursor,
                            int* __restrict__ csrc, int* __restrict__ cdst, int E) {
    int e = blockIdx.x * 256 + threadIdx.x;
    if (e < E) {
        int d = dst[e];
        int p = atomicAdd(&cursor[d], 1);
        csrc[rowptr[d] + p] = src[e];
        cdst[rowptr[d] + p] = d;
    }
}

// ---------------------------------------------------------------------------
// Embedding: h = relu(x @ W_emb + b_emb) + pos_emb[n % 88]
// ---------------------------------------------------------------------------
__global__ __launch_bounds__(256) void embed_kernel(const float* __restrict__ x,
                                                    const float* __restrict__ Wemb,
                                                    const float* __restrict__ bemb,
                                                    const float* __restrict__ pos,
                                                    float* __restrict__ h) {
    __shared__ float Wl[NIDF][CN];
    int tid = threadIdx.x;
    for (int i = tid; i < NIDF * CN; i += 256) Wl[i >> 8][i & 255] = Wemb[i];
    __syncthreads();
    float bias = bemb[tid];
    int node0 = blockIdx.x * 16;
    for (int q = 0; q < 16; ++q) {
        int n = node0 + q;
        float acc = bias;
        #pragma unroll
        for (int k = 0; k < NIDF; ++k) acc += x[n * NIDF + k] * Wl[k][tid];
        h[(size_t)n * CN + tid] = fmaxf(acc, 0.f) + pos[(n % KPG) * CN + tid];
    }
}

// ---------------------------------------------------------------------------
// Wcat[l] = [Wsrc[l] | Wdst[l]]  ->  [256, 512] per layer
// ---------------------------------------------------------------------------
__global__ void wcat_kernel(const float* __restrict__ Ws, const float* __restrict__ Wd,
                            float* __restrict__ Wcat) {
    int i = blockIdx.x * 256 + threadIdx.x;   // 4 * 256 * 512 total
    int l = i >> 17;
    int r = (i >> 9) & 255;
    int c = i & 511;
    Wcat[i] = (c < 256) ? Ws[((size_t)l * 256 + r) * 256 + c]
                        : Wd[((size_t)l * 256 + r) * 256 + (c - 256)];
}

// ---------------------------------------------------------------------------
// fp32 SGEMM: C[M,N] = A[M,K] @ B[K,N] (+bias). 128x128 tile, BK=16,
// 256 threads, 8x8 micro-tile. M % 128 == 0, K % 16 == 0; N guarded.
// ---------------------------------------------------------------------------
template <bool BIAS>
__global__ __launch_bounds__(256) void sgemm128(const float* __restrict__ A,
                                                const float* __restrict__ B,
                                                const float* __restrict__ bias,
                                                float* __restrict__ Cm,
                                                int M, int N, int K) {
    __shared__ float As[16][132];
    __shared__ float Bs[16][132];
    int tid = threadIdx.x;
    int row0 = blockIdx.x * 128;
    int col0 = blockIdx.y * 128;
    int tm = tid >> 4, tn = tid & 15;

    float acc[8][8] = {};

    int ar = tid >> 2, ak = (tid & 3) * 4;     // A: 64 rows x 16 k per pass (x2)
    int br = tid >> 5, bc = (tid & 31) * 4;    // B: 8 rows x 128 cols per pass (x2)

    for (int k0 = 0; k0 < K; k0 += 16) {
        float4 a0 = *reinterpret_cast<const float4*>(A + (size_t)(row0 + ar) * K + k0 + ak);
        float4 a1 = *reinterpret_cast<const float4*>(A + (size_t)(row0 + ar + 64) * K + k0 + ak);
        As[ak + 0][ar] = a0.x; As[ak + 1][ar] = a0.y; As[ak + 2][ar] = a0.z; As[ak + 3][ar] = a0.w;
        As[ak + 0][ar + 64] = a1.x; As[ak + 1][ar + 64] = a1.y;
        As[ak + 2][ar + 64] = a1.z; As[ak + 3][ar + 64] = a1.w;

        #pragma unroll
        for (int i = 0; i < 2; ++i) {
            int kk = br + i * 8;
            int col = col0 + bc;
            float4 bv;
            if (col + 3 < N) {
                bv = *reinterpret_cast<const float4*>(B + (size_t)(k0 + kk) * N + col);
            } else {
                bv.x = (col + 0 < N) ? B[(size_t)(k0 + kk) * N + col + 0] : 0.f;
                bv.y = (col + 1 < N) ? B[(size_t)(k0 + kk) * N + col + 1] : 0.f;
                bv.z = (col + 2 < N) ? B[(size_t)(k0 + kk) * N + col + 2] : 0.f;
                bv.w = (col + 3 < N) ? B[(size_t)(k0 + kk) * N + col + 3] : 0.f;
            }
            *reinterpret_cast<float4*>(&Bs[kk][bc]) = bv;
        }
        __syncthreads();

        #pragma unroll
        for (int kk = 0; kk < 16; ++kk) {
            float a[8], b[8];
            *reinterpret_cast<float4*>(&a[0]) = *reinterpret_cast<const float4*>(&As[kk][tm * 8]);
            *reinterpret_cast<float4*>(&a[4]) = *reinterpret_cast<const float4*>(&As[kk][tm * 8 + 4]);
            *reinterpret_cast<float4*>(&b[0]) = *reinterpret_cast<const float4*>(&Bs[kk][tn * 8]);
            *reinterpret_cast<float4*>(&b[4]) = *reinterpret_cast<const float4*>(&Bs[kk][tn * 8 + 4]);
            #pragma unroll
            for (int i = 0; i < 8; ++i)
                #pragma unroll
                for (int j = 0; j < 8; ++j) acc[i][j] += a[i] * b[j];
        }
        __syncthreads();
    }

    #pragma unroll
    for (int i = 0; i < 8; ++i) {
        int row = row0 + tm * 8 + i;
        #pragma unroll
        for (int j = 0; j < 8; ++j) {
            int col = col0 + tn * 8 + j;
            if (col < N) {
                float r = acc[i][j];
                if (BIAS) r += bias[col];
                Cm[(size_t)row * N + col] = r;
            }
        }
    }
}

// ---------------------------------------------------------------------------
// Edge scores (one wave per CSR edge):
// esc[h][p] = sum_c leaky(xl[src][c] + xr[dst][c]) * att[c],  c = 4*lane + i
// xlr layout: [N][512], xl = cols 0..255, xr = cols 256..511
// ---------------------------------------------------------------------------
__global__ __launch_bounds__(256) void edge_scores(const float* __restrict__ xlr,
                                                   const int* __restrict__ csrc,
                                                   const int* __restrict__ cdst,
                                                   const float* __restrict__ att,
                                                   float* __restrict__ esc, int E) {
    int p = blockIdx.x * 4 + (threadIdx.x >> 6);
    if (p >= E) return;
    int lane = threadIdx.x & 63;
    int s = csrc[p], d = cdst[p];
    float4 xl4 = *reinterpret_cast<const float4*>(xlr + (size_t)s * 512 + lane * 4);
    float4 xr4 = *reinterpret_cast<const float4*>(xlr + (size_t)d * 512 + 256 + lane * 4);
    float4 at4 = *reinterpret_cast<const float4*>(att + lane * 4);
    float z, ps = 0.f;
    z = xl4.x + xr4.x; z = z >= 0.f ? z : 0.2f * z; ps += z * at4.x;
    z = xl4.y + xr4.y; z = z >= 0.f ? z : 0.2f * z; ps += z * at4.y;
    z = xl4.z + xr4.z; z = z >= 0.f ? z : 0.2f * z; ps += z * at4.z;
    z = xl4.w + xr4.w; z = z >= 0.f ? z : 0.2f * z; ps += z * at4.w;
    // head = (4*lane)>>5 = lane>>3 : reduce within 8-lane groups
    ps += __shfl_xor(ps, 4);
    ps += __shfl_xor(ps, 2);
    ps += __shfl_xor(ps, 1);
    if ((lane & 7) == 0) esc[(size_t)(lane >> 3) * E + p] = ps;
}

// ---------------------------------------------------------------------------
// GAT aggregate (one block per dst node, 256 threads = channels):
// wave-parallel online segment softmax (32 threads per head, state in regs),
// 4x-unrolled weighted gather, then bias/relu/residual/LayerNorm.
// ---------------------------------------------------------------------------
__global__ __launch_bounds__(256) void gat_agg(const float* __restrict__ xlr,
                                               const float* __restrict__ esc,
                                               const int* __restrict__ rowptr,
                                               const int* __restrict__ csrc,
                                               const float* __restrict__ bias,
                                               const float* __restrict__ lng,
                                               const float* __restrict__ lnb,
                                               float* __restrict__ h, int E) {
    __shared__ float e_ch[NHEAD][64];
    __shared__ int srcbuf[64];
    __shared__ float rsum[4], rsq[4];

    int n = blockIdx.x;
    int tid = threadIdx.x;
    int head = tid >> 5;
    int gl = tid & 31;          // lane within head group
    int e0 = rowptr[n], e1 = rowptr[n + 1];
    float hres = h[(size_t)n * CN + tid];
    float acc = 0.f, m_reg = -INFINITY, s_reg = 0.f;

    for (int cs = e0; cs < e1; cs += 64) {
        int cnt = min(64, e1 - cs);
        if (tid < cnt) srcbuf[tid] = csrc[cs + tid];
        float v0 = (gl < cnt) ? esc[(size_t)head * E + cs + gl] : -INFINITY;
        float v1 = (gl + 32 < cnt) ? esc[(size_t)head * E + cs + gl + 32] : -INFINITY;
        // chunk max (butterfly within the 32-lane head group)
        float cm = fmaxf(v0, v1);
        cm = fmaxf(cm, __shfl_xor(cm, 16));
        cm = fmaxf(cm, __shfl_xor(cm, 8));
        cm = fmaxf(cm, __shfl_xor(cm, 4));
        cm = fmaxf(cm, __shfl_xor(cm, 2));
        cm = fmaxf(cm, __shfl_xor(cm, 1));
        float nm = fmaxf(m_reg, cm);
        float f = expf(m_reg - nm);            // first chunk: exp(-inf)=0
        float w0 = (gl < cnt) ? expf(v0 - nm) : 0.f;
        float w1 = (gl + 32 < cnt) ? expf(v1 - nm) : 0.f;
        float t = w0 + w1;
        t += __shfl_xor(t, 16);
        t += __shfl_xor(t, 8);
        t += __shfl_xor(t, 4);
        t += __shfl_xor(t, 2);
        t += __shfl_xor(t, 1);
        s_reg = s_reg * f + t;
        m_reg = nm;
        e_ch[head][gl] = w0;
        e_ch[head][gl + 32] = w1;
        acc *= f;
        __syncthreads();

        int je = 0;
        for (; je + 4 <= cnt; je += 4) {
            float a0 = e_ch[head][je + 0];
            float a1 = e_ch[head][je + 1];
            float a2 = e_ch[head][je + 2];
            float a3 = e_ch[head][je + 3];
            const float* r0 = xlr + (size_t)srcbuf[je + 0] * 512;
            const float* r1 = xlr + (size_t)srcbuf[je + 1] * 512;
            const float* r2 = xlr + (size_t)srcbuf[je + 2] * 512;
            const float* r3 = xlr + (size_t)srcbuf[je + 3] * 512;
            acc += a0 * r0[tid];
            acc += a1 * r1[tid];
            acc += a2 * r2[tid];
            acc += a3 * r3[tid];
        }
        for (; je < cnt; ++je)
            acc += e_ch[head][je] * xlr[(size_t)srcbuf[je] * 512 + tid];
        __syncthreads();
    }

    float out = acc / s_reg + bias[tid];
    float v = hres + fmaxf(out, 0.f);
    // LayerNorm over 256 channels
    int wid = tid >> 6, lane64 = tid & 63;
    float sum = v, sq = v * v;
    #pragma unroll
    for (int o = 32; o; o >>= 1) { sum += __shfl_xor(sum, o); sq += __shfl_xor(sq, o); }
    if (lane64 == 0) { rsum[wid] = sum; rsq[wid] = sq; }
    __syncthreads();
    sum = rsum[0] + rsum[1] + rsum[2] + rsum[3];
    sq  = rsq[0] + rsq[1] + rsq[2] + rsq[3];
    float mu = sum / CN;
    float var = sq / CN - mu * mu;
    float inv = rsqrtf(var + 1e-5f);
    h[(size_t)n * CN + tid] = (v - mu) * inv * lng[tid] + lnb[tid];
}

// ---------------------------------------------------------------------------
// gate[n] = relu(gtmp[n]) . gW2 + gb2   (gtmp = h@gW1+gb1 via sgemm128)
// ---------------------------------------------------------------------------
__global__ __launch_bounds__(256) void gate2_kernel(const float* __restrict__ gtmp,
                                                    const float* __restrict__ gW2,
                                                    const float* __restrict__ gb2,
                                                    float* __restrict__ gate, int N) {
    int n = blockIdx.x * 4 + (threadIdx.x >> 6);
    if (n >= N) return;
    int lane = threadIdx.x & 63;
    float2 t = *reinterpret_cast<const float2*>(gtmp + (size_t)n * GATE_DIM + lane * 2);
    float2 w = *reinterpret_cast<const float2*>(gW2 + lane * 2);
    float c = fmaxf(t.x, 0.f) * w.x + fmaxf(t.y, 0.f) * w.y;
    #pragma unroll
    for (int o = 32; o; o >>= 1) c += __shfl_xor(c, o);
    if (lane == 0) gate[n] = c + gb2[0];
}

// ---------------------------------------------------------------------------
// Pool: segment softmax over contiguous 88-node graphs + weighted sum -> emb
// ---------------------------------------------------------------------------
__global__ __launch_bounds__(256) void pool_kernel(const float* __restrict__ gate,
                                                   const float* __restrict__ h,
                                                   float* __restrict__ emb) {
    __shared__ float a[KPG];
    __shared__ float wm[4];
    int g = blockIdx.x, tid = threadIdx.x;
    int wid = tid >> 6, lane = tid & 63;
    float gv = (tid < KPG) ? gate[g * KPG + tid] : -INFINITY;
    float m = gv;
    #pragma unroll
    for (int o = 32; o; o >>= 1) m = fmaxf(m, __shfl_xor(m, o));
    if (lane == 0) wm[wid] = m;
    __syncthreads();
    m = fmaxf(fmaxf(wm[0], wm[1]), fmaxf(wm[2], wm[3]));
    __syncthreads();
    float av = (tid < KPG) ? expf(gv - m) : 0.f;
    if (tid < KPG) a[tid] = av;
    float s = av;
    #pragma unroll
    for (int o = 32; o; o >>= 1) s += __shfl_xor(s, o);
    if (lane == 0) wm[wid] = s;
    __syncthreads();
    s = wm[0] + wm[1] + wm[2] + wm[3];
    float inv = 1.f / s;
    float acc = 0.f;
    const float* hg = h + (size_t)g * KPG * CN;
    for (int i = 0; i < KPG; ++i) acc += a[i] * hg[i * CN + tid];
    emb[(size_t)g * CN + tid] = acc * inv;
}

// ---------------------------------------------------------------------------
// Heads: t1 = relu(LN(emb@pW1+pb1)); value = tanh(relu(emb@vW1+vb1)@vW2+vb2)
// ---------------------------------------------------------------------------
__global__ __launch_bounds__(256) void head_kernel(const float* __restrict__ emb,
    const float* __restrict__ pW1, const float* __restrict__ pb1,
    const float* __restrict__ plng, const float* __restrict__ plnb,
    const float* __restrict__ vW1, const float* __restrict__ vb1,
    const float* __restrict__ vW2, const float* __restrict__ vb2,
    float* __restrict__ t1, float* __restrict__ value_out) {
    __shared__ float e_l[CN];
    __shared__ float rsum[4], rsq[4];
    int g = blockIdx.x, tid = threadIdx.x;
    int wid = tid >> 6, lane = tid & 63;
    e_l[tid] = emb[(size_t)g * CN + tid];
    __syncthreads();
    float p = pb1[tid], v = vb1[tid];
    for (int k = 0; k < CN; ++k) {
        float e = e_l[k];
        p += e * pW1[k * CN + tid];
        v += e * vW1[k * CN + tid];
    }
    float sum = p, sq = p * p;
    #pragma unroll
    for (int o = 32; o; o >>= 1) { sum += __shfl_xor(sum, o); sq += __shfl_xor(sq, o); }
    if (lane == 0) { rsum[wid] = sum; rsq[wid] = sq; }
    __syncthreads();
    sum = rsum[0] + rsum[1] + rsum[2] + rsum[3];
    sq  = rsq[0] + rsq[1] + rsq[2] + rsq[3];
    float mu = sum / CN;
    float var = sq / CN - mu * mu;
    float inv = rsqrtf(var + 1e-5f);
    t1[(size_t)g * CN + tid] = fmaxf((p - mu) * inv * plng[tid] + plnb[tid], 0.f);
    float contrib = fmaxf(v, 0.f) * vW2[tid];
    __syncthreads();
    #pragma unroll
    for (int o = 32; o; o >>= 1) contrib += __shfl_xor(contrib, o);
    if (lane == 0) rsum[wid] = contrib;
    __syncthreads();
    if (tid == 0)
        value_out[g] = tanhf(rsum[0] + rsum[1] + rsum[2] + rsum[3] + vb2[0]);
}

// ---------------------------------------------------------------------------
extern "C" void kernel_launch(void* const* d_in, const int* in_sizes, int n_in,
                              void* d_out, int out_size, void* d_ws, size_t ws_size,
                              hipStream_t stream) {
    const float* x        = (const float*)d_in[0];
    const int*   ei       = (const int*)d_in[1];
    const float* W_emb    = (const float*)d_in[4];
    const float* b_emb    = (const float*)d_in[5];
    const float* pos_emb  = (const float*)d_in[6];
    const float* gat_Wsrc = (const float*)d_in[7];
    const float* gat_Wdst = (const float*)d_in[8];
    const float* gat_att  = (const float*)d_in[9];
    const float* gat_bias = (const float*)d_in[10];
    const float* ln_g     = (const float*)d_in[11];
    const float* ln_b     = (const float*)d_in[12];
    const float* gW1      = (const float*)d_in[13];
    const float* gb1      = (const float*)d_in[14];
    const float* gW2      = (const float*)d_in[15];
    const float* gb2      = (const float*)d_in[16];
    const float* pW1      = (const float*)d_in[17];
    const float* pb1      = (const float*)d_in[18];
    const float* p_ln_g   = (const float*)d_in[19];
    const float* p_ln_b   = (const float*)d_in[20];
    const float* pW2      = (const float*)d_in[21];
    const float* pb2      = (const float*)d_in[22];
    const float* vW1      = (const float*)d_in[23];
    const float* vb1      = (const float*)d_in[24];
    const float* vW2      = (const float*)d_in[25];
    const float* vb2      = (const float*)d_in[26];

    const int N = in_sizes[2];      // 22528
    const int E = in_sizes[1] / 2;  // 405504
    const int G = N / KPG;          // 256
    const int NB = (N + 1023) / 1024;

    char* ws = (char*)d_ws;
    size_t off = 0;
    auto alloc = [&](size_t nbytes) {
        void* pp = ws + off;
        off = (off + nbytes + 255) & ~(size_t)255;
        return pp;
    };
    float* h      = (float*)alloc((size_t)N * CN * 4);
    float* xlr    = (float*)alloc((size_t)N * 512 * 4);
    float* esc    = (float*)alloc((size_t)NHEAD * E * 4);   // also reused as gtmp
    float* Wcat   = (float*)alloc((size_t)4 * 256 * 512 * 4);
    float* gate   = (float*)alloc((size_t)N * 4);
    float* emb    = (float*)alloc((size_t)G * CN * 4);
    float* t1     = (float*)alloc((size_t)G * CN * 4);
    int*   rowptr = (int*)alloc((size_t)(N + 1) * 4);
    int*   cnt    = (int*)alloc((size_t)N * 4);
    int*   cursor = (int*)alloc((size_t)N * 4);
    int*   btot   = (int*)alloc((size_t)64 * 4);
    int*   csrc   = (int*)alloc((size_t)E * 4);
    int*   cdst   = (int*)alloc((size_t)E * 4);
    float* gtmp   = esc;  // N*128 floats <= 8*E floats

    const int* e_src = ei;
    const int* e_dst = ei + E;

    hipMemsetAsync(cnt, 0, (size_t)N * 4, stream);
    hipMemsetAsync(cursor, 0, (size_t)N * 4, stream);
    count_kernel<<<(E + 255) / 256, 256, 0, stream>>>(e_dst, cnt, E);
    scan1_kernel<<<NB, 1024, 0, stream>>>(cnt, rowptr, btot, N);
    scan2_kernel<<<1, 64, 0, stream>>>(btot, NB);
    scan3_kernel<<<(N + 1024) / 1024, 1024, 0, stream>>>(rowptr, btot, N, NB);
    fill_kernel<<<(E + 255) / 256, 256, 0, stream>>>(e_src, e_dst, rowptr, cursor, csrc, cdst, E);

    embed_kernel<<<N / 16, 256, 0, stream>>>(x, W_emb, b_emb, pos_emb, h);
    wcat_kernel<<<(4 * 256 * 512) / 256, 256, 0, stream>>>(gat_Wsrc, gat_Wdst, Wcat);

    for (int l = 0; l < 4; ++l) {
        dim3 g1(N / 128, 512 / 128);
        sgemm128<false><<<g1, 256, 0, stream>>>(h, Wcat + (size_t)l * 256 * 512, nullptr,
                                                xlr, N, 512, CN);
        edge_scores<<<(E + 3) / 4, 256, 0, stream>>>(xlr, csrc, cdst,
                                                     gat_att + l * CN, esc, E);
        gat_agg<<<N, 256, 0, stream>>>(xlr, esc, rowptr, csrc,
                                       gat_bias + l * CN, ln_g + l * CN, ln_b + l * CN, h, E);
    }

    // gate MLP
    {
        dim3 g1(N / 128, 1);
        sgemm128<true><<<g1, 256, 0, stream>>>(h, gW1, gb1, gtmp, N, GATE_DIM, CN);
        gate2_kernel<<<(N + 3) / 4, 256, 0, stream>>>(gtmp, gW2, gb2, gate, N);
    }
    pool_kernel<<<G, 256, 0, stream>>>(gate, h, emb);

    float* policy = (float*)d_out;
    float* value  = (float*)d_out + (size_t)G * ACT_DIM;
    head_kernel<<<G, 256, 0, stream>>>(emb, pW1, pb1, p_ln_g, p_ln_b,
                                       vW1, vb1, vW2, vb2, t1, value);
    dim3 g2(G / 128, (ACT_DIM + 127) / 128);
    sgemm128<true><<<g2, 256, 0, stream>>>(t1, pW2, pb2, policy, G, ACT_DIM, CN);
}

// Round 3
// 975.745 us; speedup vs baseline: 1.2983x; 1.1329x over previous
//
#include <hip/hip_runtime.h>
#include <math.h>

constexpr int CN = 256;        // channels
constexpr int NHEAD = 8;       // attention heads
constexpr int KPG = 88;        // nodes per graph
constexpr int NIDF = 16;       // input node features
constexpr int GATE_DIM = 128;
constexpr int ACT_DIM = 4644;

typedef __attribute__((ext_vector_type(8))) short bf16x8;
typedef __attribute__((ext_vector_type(4))) float f32x4;

__device__ __forceinline__ unsigned short f2bf(float f) {
    unsigned int u = __float_as_uint(f);
    unsigned int r = (u + 0x7fffu + ((u >> 16) & 1u)) >> 16;
    return (unsigned short)r;
}
__device__ __forceinline__ float bf2f(unsigned short h) {
    return __uint_as_float(((unsigned int)h) << 16);
}

__device__ __forceinline__ void glds16(const void* g, void* l) {
    __builtin_amdgcn_global_load_lds(
        (const __attribute__((address_space(1))) unsigned int*)g,
        (__attribute__((address_space(3))) unsigned int*)l, 16, 0, 0);
}

// ---------------------------------------------------------------------------
// CSR build: count -> hierarchical scan -> fill
// ---------------------------------------------------------------------------
__global__ void count_kernel(const int* __restrict__ dst, int* __restrict__ cnt, int E) {
    int e = blockIdx.x * 256 + threadIdx.x;
    if (e < E) atomicAdd(&cnt[dst[e]], 1);
}

__global__ __launch_bounds__(1024) void scan1_kernel(const int* __restrict__ cnt,
                                                     int* __restrict__ rowptr,
                                                     int* __restrict__ btot, int n) {
    __shared__ int buf[1024];
    int tid = threadIdx.x;
    int i = blockIdx.x * 1024 + tid;
    int v = (i < n) ? cnt[i] : 0;
    buf[tid] = v;
    __syncthreads();
    for (int off = 1; off < 1024; off <<= 1) {
        int t = (tid >= off) ? buf[tid - off] : 0;
        __syncthreads();
        buf[tid] += t;
        __syncthreads();
    }
    if (i < n) rowptr[i] = buf[tid] - v;
    if (tid == 1023) btot[blockIdx.x] = buf[1023];
}

__global__ void scan2_kernel(int* __restrict__ btot, int nb) {
    if (threadIdx.x == 0 && blockIdx.x == 0) {
        int s = 0;
        for (int b = 0; b < nb; ++b) { int t = btot[b]; btot[b] = s; s += t; }
        btot[nb] = s;
    }
}

__global__ __launch_bounds__(1024) void scan3_kernel(int* __restrict__ rowptr,
                                                     const int* __restrict__ btot,
                                                     int n, int nb) {
    int i = blockIdx.x * 1024 + threadIdx.x;
    if (i < n) rowptr[i] += btot[i >> 10];
    else if (i == n) rowptr[n] = btot[nb];
}

__global__ void fill_kernel(const int* __restrict__ src, const int* __restrict__ dst,
                            const int* __restrict__ rowptr, int* __restrict__ cursor,
                            int* __restrict__ csrc, int E) {
    int e = blockIdx.x * 256 + threadIdx.x;
    if (e < E) {
        int d = dst[e];
        int p = atomicAdd(&cursor[d], 1);
        csrc[rowptr[d] + p] = src[e];
    }
}

// ---------------------------------------------------------------------------
// Embedding: h = relu(x @ W_emb + b_emb) + pos_emb[n % 88]
// ---------------------------------------------------------------------------
__global__ __launch_bounds__(256) void embed_kernel(const float* __restrict__ x,
                                                    const float* __restrict__ Wemb,
                                                    const float* __restrict__ bemb,
                                                    const float* __restrict__ pos,
                                                    float* __restrict__ h) {
    __shared__ float Wl[NIDF][CN];
    int tid = threadIdx.x;
    for (int i = tid; i < NIDF * CN; i += 256) Wl[i >> 8][i & 255] = Wemb[i];
    __syncthreads();
    float bias = bemb[tid];
    int node0 = blockIdx.x * 16;
    for (int q = 0; q < 16; ++q) {
        int n = node0 + q;
        float acc = bias;
        #pragma unroll
        for (int k = 0; k < NIDF; ++k) acc += x[n * NIDF + k] * Wl[k][tid];
        h[(size_t)n * CN + tid] = fmaxf(acc, 0.f) + pos[(n % KPG) * CN + tid];
    }
}

// ---------------------------------------------------------------------------
// Wcat[l] = [Wsrc[l] | Wdst[l]]  ->  [256, 512] per layer (fp32)
// ---------------------------------------------------------------------------
__global__ void wcat_kernel(const float* __restrict__ Ws, const float* __restrict__ Wd,
                            float* __restrict__ Wcat) {
    int i = blockIdx.x * 256 + threadIdx.x;
    int l = i >> 17;
    int r = (i >> 9) & 255;
    int c = i & 511;
    Wcat[i] = (c < 256) ? Ws[((size_t)l * 256 + r) * 256 + c]
                        : Wd[((size_t)l * 256 + r) * 256 + (c - 256)];
}

// ---------------------------------------------------------------------------
// Weight decompose + fragment-order relayout:
// out[kb][nb][lane][j] = W[kb*32 + (lane>>4)*8 + j][nb*16 + (lane&15)]
// hi = bf16(v), lo = bf16(v - hi). Zero-pad cols >= Nn.
// ---------------------------------------------------------------------------
__global__ void wconv_kernel(const float* __restrict__ W, unsigned short* __restrict__ Bh,
                             unsigned short* __restrict__ Bl, int Nn, int NB, int tot) {
    int o = blockIdx.x * 256 + threadIdx.x;
    if (o >= tot) return;
    int idx = o & 511;
    int nb = (o >> 9) % NB;
    int kb = o / (512 * NB);
    int l = idx >> 3, j = idx & 7;
    int k = kb * 32 + (l >> 4) * 8 + j;
    int c = nb * 16 + (l & 15);
    float v = (c < Nn) ? W[(size_t)k * Nn + c] : 0.f;
    unsigned short hh = f2bf(v);
    Bh[o] = hh;
    Bl[o] = f2bf(v - bf2f(hh));
}

// ---------------------------------------------------------------------------
// MFMA GEMM, bf16 split 3-product: C = A(f32)[M,K] @ B[K,N] (+bias)
// tile 128x128, BK=32, 256 threads (4 waves 2x2, wave tile 64x64).
// B pre-laid fragment-order (Bh/Bl). K%32==0, M%128==0; cols guarded vs Nlog.
// ---------------------------------------------------------------------------
template <bool BIAS>
__global__ __launch_bounds__(256) void mgemm(const float* __restrict__ A,
                                             const unsigned short* __restrict__ Bh,
                                             const unsigned short* __restrict__ Bl,
                                             const float* __restrict__ bias,
                                             float* __restrict__ C,
                                             int M, int Nlog, int NB, int K) {
    __shared__ unsigned short Ah[8 * 64 * 8];
    __shared__ unsigned short Al[8 * 64 * 8];
    __shared__ unsigned short Bsh[8 * 64 * 8];
    __shared__ unsigned short Bsl[8 * 64 * 8];
    int tid = threadIdx.x;
    int wid = tid >> 6, lane = tid & 63;
    int row0 = blockIdx.x * 128;
    int cb = blockIdx.y;
    int wr = wid >> 1, wc = wid & 1;

    f32x4 acc[4][4] = {};

    int r = tid >> 1, kh = (tid & 1) * 16;      // A staging assignment
    int mb = r >> 4, rr = r & 15;

    for (int k0 = 0; k0 < K; k0 += 32) {
        int kb = k0 >> 5;
        // ---- stage A (fp32 -> hi/lo bf16, fragment order) ----
        {
            const float* ap = A + (size_t)(row0 + r) * K + k0 + kh;
            float4 f0 = *reinterpret_cast<const float4*>(ap);
            float4 f1 = *reinterpret_cast<const float4*>(ap + 4);
            float4 f2 = *reinterpret_cast<const float4*>(ap + 8);
            float4 f3 = *reinterpret_cast<const float4*>(ap + 12);
            float vv[16] = {f0.x, f0.y, f0.z, f0.w, f1.x, f1.y, f1.z, f1.w,
                            f2.x, f2.y, f2.z, f2.w, f3.x, f3.y, f3.z, f3.w};
            #pragma unroll
            for (int s = 0; s < 2; ++s) {
                bf16x8 ph, pl;
                #pragma unroll
                for (int j = 0; j < 8; ++j) {
                    float v = vv[s * 8 + j];
                    unsigned short hb = f2bf(v);
                    ph[j] = (short)hb;
                    pl[j] = (short)f2bf(v - bf2f(hb));
                }
                int l = (kh / 8 + s) * 16 + rr;
                int off = (mb * 64 + l) * 8;
                *reinterpret_cast<bf16x8*>(&Ah[off]) = ph;
                *reinterpret_cast<bf16x8*>(&Al[off]) = pl;
            }
        }
        // ---- stage B (async copy, already fragment order) ----
        {
            size_t base = ((size_t)kb * NB + (size_t)cb * 8) * 512;
            for (int ch = wid; ch < 8; ch += 4) {
                glds16(Bh + base + ch * 512 + lane * 8, &Bsh[ch * 512]);
                glds16(Bl + base + ch * 512 + lane * 8, &Bsl[ch * 512]);
            }
        }
        __syncthreads();
        // ---- fragments + MFMA ----
        bf16x8 a_h[4], a_l[4], b_h[4], b_l[4];
        #pragma unroll
        for (int mf = 0; mf < 4; ++mf) {
            int off = ((wr * 4 + mf) * 64 + lane) * 8;
            a_h[mf] = *reinterpret_cast<const bf16x8*>(&Ah[off]);
            a_l[mf] = *reinterpret_cast<const bf16x8*>(&Al[off]);
        }
        #pragma unroll
        for (int nf = 0; nf < 4; ++nf) {
            int off = ((wc * 4 + nf) * 64 + lane) * 8;
            b_h[nf] = *reinterpret_cast<const bf16x8*>(&Bsh[off]);
            b_l[nf] = *reinterpret_cast<const bf16x8*>(&Bsl[off]);
        }
        #pragma unroll
        for (int mf = 0; mf < 4; ++mf)
            #pragma unroll
            for (int nf = 0; nf < 4; ++nf) {
                acc[mf][nf] = __builtin_amdgcn_mfma_f32_16x16x32_bf16(a_h[mf], b_h[nf], acc[mf][nf], 0, 0, 0);
                acc[mf][nf] = __builtin_amdgcn_mfma_f32_16x16x32_bf16(a_h[mf], b_l[nf], acc[mf][nf], 0, 0, 0);
                acc[mf][nf] = __builtin_amdgcn_mfma_f32_16x16x32_bf16(a_l[mf], b_h[nf], acc[mf][nf], 0, 0, 0);
            }
        __syncthreads();
    }
    // ---- epilogue ----
    #pragma unroll
    for (int mf = 0; mf < 4; ++mf) {
        #pragma unroll
        for (int nf = 0; nf < 4; ++nf) {
            int col = cb * 128 + wc * 64 + nf * 16 + (lane & 15);
            if (col < Nlog) {
                float bv = BIAS ? bias[col] : 0.f;
                #pragma unroll
                for (int rg = 0; rg < 4; ++rg) {
                    int row = row0 + wr * 64 + mf * 16 + (lane >> 4) * 4 + rg;
                    C[(size_t)row * Nlog + col] = acc[mf][nf][rg] + bv;
                }
            }
        }
    }
}

// ---------------------------------------------------------------------------
// Fused GAT layer aggregate (one block per dst node, 256 threads = channels):
// per 64-edge chunk: stage xl[src] rows to LDS (global_load_lds), compute
// scores wave-parallel, online softmax (32 lanes/head), gather from LDS.
// Then bias/relu/residual/LayerNorm.
// ---------------------------------------------------------------------------
__global__ __launch_bounds__(256) void gat_agg(const float* __restrict__ xlr,
                                               const int* __restrict__ rowptr,
                                               const int* __restrict__ csrc,
                                               const float* __restrict__ att,
                                               const float* __restrict__ bias,
                                               const float* __restrict__ lng,
                                               const float* __restrict__ lnb,
                                               float* __restrict__ h) {
    __shared__ float xlL[64][256];       // 64KB staged xl rows
    __shared__ float xr_l[CN], att_l[CN];
    __shared__ float e_ch[64][NHEAD];
    __shared__ int srcbuf[64];
    __shared__ float rsum[4], rsq[4];

    int n = blockIdx.x;
    int tid = threadIdx.x;
    int wid = tid >> 6, lane = tid & 63;
    int head = tid >> 5, gl = tid & 31;

    xr_l[tid] = xlr[(size_t)n * 512 + 256 + tid];
    att_l[tid] = att[tid];
    int e0 = rowptr[n], e1 = rowptr[n + 1];
    float hres = h[(size_t)n * CN + tid];
    float acc = 0.f, m_reg = -INFINITY, s_reg = 0.f;
    __syncthreads();

    for (int cs = e0; cs < e1; cs += 64) {
        int cnt = min(64, e1 - cs);
        if (tid < cnt) srcbuf[tid] = csrc[cs + tid];
        __syncthreads();
        // stage xl rows: wave w stages rows je = w, w+4, ...
        for (int je = wid; je < cnt; je += 4) {
            const float* src = xlr + (size_t)srcbuf[je] * 512 + lane * 4;
            glds16(src, &xlL[je][0]);
        }
        __syncthreads();
        // scores: wave w handles edges je = w, w+4, ... ; lane owns 4 channels
        for (int je = wid; je < cnt; je += 4) {
            float4 xl4 = *reinterpret_cast<const float4*>(&xlL[je][lane * 4]);
            float4 xr4 = *reinterpret_cast<const float4*>(&xr_l[lane * 4]);
            float4 at4 = *reinterpret_cast<const float4*>(&att_l[lane * 4]);
            float z, p = 0.f;
            z = xl4.x + xr4.x; z = z >= 0.f ? z : 0.2f * z; p += z * at4.x;
            z = xl4.y + xr4.y; z = z >= 0.f ? z : 0.2f * z; p += z * at4.y;
            z = xl4.z + xr4.z; z = z >= 0.f ? z : 0.2f * z; p += z * at4.z;
            z = xl4.w + xr4.w; z = z >= 0.f ? z : 0.2f * z; p += z * at4.w;
            p += __shfl_xor(p, 4);
            p += __shfl_xor(p, 2);
            p += __shfl_xor(p, 1);
            if ((lane & 7) == 0) e_ch[je][lane >> 3] = p;
        }
        __syncthreads();
        // online softmax per head (32 lanes per head, state in regs)
        float v0 = (gl < cnt) ? e_ch[gl][head] : -INFINITY;
        float v1 = (gl + 32 < cnt) ? e_ch[gl + 32][head] : -INFINITY;
        float cm = fmaxf(v0, v1);
        cm = fmaxf(cm, __shfl_xor(cm, 16));
        cm = fmaxf(cm, __shfl_xor(cm, 8));
        cm = fmaxf(cm, __shfl_xor(cm, 4));
        cm = fmaxf(cm, __shfl_xor(cm, 2));
        cm = fmaxf(cm, __shfl_xor(cm, 1));
        float nm = fmaxf(m_reg, cm);
        float f = expf(m_reg - nm);
        float w0 = (gl < cnt) ? expf(v0 - nm) : 0.f;
        float w1 = (gl + 32 < cnt) ? expf(v1 - nm) : 0.f;
        float t = w0 + w1;
        t += __shfl_xor(t, 16);
        t += __shfl_xor(t, 8);
        t += __shfl_xor(t, 4);
        t += __shfl_xor(t, 2);
        t += __shfl_xor(t, 1);
        s_reg = s_reg * f + t;
        m_reg = nm;
        e_ch[gl][head] = w0;
        e_ch[gl + 32][head] = w1;
        acc *= f;
        __syncthreads();
        // gather
        int je = 0;
        for (; je + 4 <= cnt; je += 4) {
            acc += e_ch[je + 0][head] * xlL[je + 0][tid];
            acc += e_ch[je + 1][head] * xlL[je + 1][tid];
            acc += e_ch[je + 2][head] * xlL[je + 2][tid];
            acc += e_ch[je + 3][head] * xlL[je + 3][tid];
        }
        for (; je < cnt; ++je) acc += e_ch[je][head] * xlL[je][tid];
        __syncthreads();
    }

    float out = acc / s_reg + bias[tid];
    float v = hres + fmaxf(out, 0.f);
    float sum = v, sq = v * v;
    #pragma unroll
    for (int o = 32; o; o >>= 1) { sum += __shfl_xor(sum, o); sq += __shfl_xor(sq, o); }
    if (lane == 0) { rsum[wid] = sum; rsq[wid] = sq; }
    __syncthreads();
    sum = rsum[0] + rsum[1] + rsum[2] + rsum[3];
    sq  = rsq[0] + rsq[1] + rsq[2] + rsq[3];
    float mu = sum / CN;
    float var = sq / CN - mu * mu;
    float inv = rsqrtf(var + 1e-5f);
    h[(size_t)n * CN + tid] = (v - mu) * inv * lng[tid] + lnb[tid];
}

// ---------------------------------------------------------------------------
// gate[n] = relu(gtmp[n]) . gW2 + gb2
// ---------------------------------------------------------------------------
__global__ __launch_bounds__(256) void gate2_kernel(const float* __restrict__ gtmp,
                                                    const float* __restrict__ gW2,
                                                    const float* __restrict__ gb2,
                                                    float* __restrict__ gate, int N) {
    int n = blockIdx.x * 4 + (threadIdx.x >> 6);
    if (n >= N) return;
    int lane = threadIdx.x & 63;
    float2 t = *reinterpret_cast<const float2*>(gtmp + (size_t)n * GATE_DIM + lane * 2);
    float2 w = *reinterpret_cast<const float2*>(gW2 + lane * 2);
    float c = fmaxf(t.x, 0.f) * w.x + fmaxf(t.y, 0.f) * w.y;
    #pragma unroll
    for (int o = 32; o; o >>= 1) c += __shfl_xor(c, o);
    if (lane == 0) gate[n] = c + gb2[0];
}

// ---------------------------------------------------------------------------
// Pool: segment softmax over contiguous 88-node graphs + weighted sum -> emb
// ---------------------------------------------------------------------------
__global__ __launch_bounds__(256) void pool_kernel(const float* __restrict__ gate,
                                                   const float* __restrict__ h,
                                                   float* __restrict__ emb) {
    __shared__ float a[KPG];
    __shared__ float wm[4];
    int g = blockIdx.x, tid = threadIdx.x;
    int wid = tid >> 6, lane = tid & 63;
    float gv = (tid < KPG) ? gate[g * KPG + tid] : -INFINITY;
    float m = gv;
    #pragma unroll
    for (int o = 32; o; o >>= 1) m = fmaxf(m, __shfl_xor(m, o));
    if (lane == 0) wm[wid] = m;
    __syncthreads();
    m = fmaxf(fmaxf(wm[0], wm[1]), fmaxf(wm[2], wm[3]));
    __syncthreads();
    float av = (tid < KPG) ? expf(gv - m) : 0.f;
    if (tid < KPG) a[tid] = av;
    float s = av;
    #pragma unroll
    for (int o = 32; o; o >>= 1) s += __shfl_xor(s, o);
    if (lane == 0) wm[wid] = s;
    __syncthreads();
    s = wm[0] + wm[1] + wm[2] + wm[3];
    float inv = 1.f / s;
    float acc = 0.f;
    const float* hg = h + (size_t)g * KPG * CN;
    for (int i = 0; i < KPG; ++i) acc += a[i] * hg[i * CN + tid];
    emb[(size_t)g * CN + tid] = acc * inv;
}

// ---------------------------------------------------------------------------
// Heads: t1 = relu(LN(emb@pW1+pb1)); value = tanh(relu(emb@vW1+vb1)@vW2+vb2)
// ---------------------------------------------------------------------------
__global__ __launch_bounds__(256) void head_kernel(const float* __restrict__ emb,
    const float* __restrict__ pW1, const float* __restrict__ pb1,
    const float* __restrict__ plng, const float* __restrict__ plnb,
    const float* __restrict__ vW1, const float* __restrict__ vb1,
    const float* __restrict__ vW2, const float* __restrict__ vb2,
    float* __restrict__ t1, float* __restrict__ value_out) {
    __shared__ float e_l[CN];
    __shared__ float rsum[4], rsq[4];
    int g = blockIdx.x, tid = threadIdx.x;
    int wid = tid >> 6, lane = tid & 63;
    e_l[tid] = emb[(size_t)g * CN + tid];
    __syncthreads();
    float p = pb1[tid], v = vb1[tid];
    for (int k = 0; k < CN; ++k) {
        float e = e_l[k];
        p += e * pW1[k * CN + tid];
        v += e * vW1[k * CN + tid];
    }
    float sum = p, sq = p * p;
    #pragma unroll
    for (int o = 32; o; o >>= 1) { sum += __shfl_xor(sum, o); sq += __shfl_xor(sq, o); }
    if (lane == 0) { rsum[wid] = sum; rsq[wid] = sq; }
    __syncthreads();
    sum = rsum[0] + rsum[1] + rsum[2] + rsum[3];
    sq  = rsq[0] + rsq[1] + rsq[2] + rsq[3];
    float mu = sum / CN;
    float var = sq / CN - mu * mu;
    float inv = rsqrtf(var + 1e-5f);
    t1[(size_t)g * CN + tid] = fmaxf((p - mu) * inv * plng[tid] + plnb[tid], 0.f);
    float contrib = fmaxf(v, 0.f) * vW2[tid];
    __syncthreads();
    #pragma unroll
    for (int o = 32; o; o >>= 1) contrib += __shfl_xor(contrib, o);
    if (lane == 0) rsum[wid] = contrib;
    __syncthreads();
    if (tid == 0)
        value_out[g] = tanhf(rsum[0] + rsum[1] + rsum[2] + rsum[3] + vb2[0]);
}

// ---------------------------------------------------------------------------
extern "C" void kernel_launch(void* const* d_in, const int* in_sizes, int n_in,
                              void* d_out, int out_size, void* d_ws, size_t ws_size,
                              hipStream_t stream) {
    const float* x        = (const float*)d_in[0];
    const int*   ei       = (const int*)d_in[1];
    const float* W_emb    = (const float*)d_in[4];
    const float* b_emb    = (const float*)d_in[5];
    const float* pos_emb  = (const float*)d_in[6];
    const float* gat_Wsrc = (const float*)d_in[7];
    const float* gat_Wdst = (const float*)d_in[8];
    const float* gat_att  = (const float*)d_in[9];
    const float* gat_bias = (const float*)d_in[10];
    const float* ln_g     = (const float*)d_in[11];
    const float* ln_b     = (const float*)d_in[12];
    const float* gW1      = (const float*)d_in[13];
    const float* gb1      = (const float*)d_in[14];
    const float* gW2      = (const float*)d_in[15];
    const float* gb2      = (const float*)d_in[16];
    const float* pW1      = (const float*)d_in[17];
    const float* pb1      = (const float*)d_in[18];
    const float* p_ln_g   = (const float*)d_in[19];
    const float* p_ln_b   = (const float*)d_in[20];
    const float* pW2      = (const float*)d_in[21];
    const float* pb2      = (const float*)d_in[22];
    const float* vW1      = (const float*)d_in[23];
    const float* vb1      = (const float*)d_in[24];
    const float* vW2      = (const float*)d_in[25];
    const float* vb2      = (const float*)d_in[26];

    const int N = in_sizes[2];      // 22528
    const int E = in_sizes[1] / 2;  // 382976
    const int G = N / KPG;          // 256
    const int NB_SC = (N + 1023) / 1024;

    // GEMM geometry
    const int NB_CAT = 32;                        // 512/16
    const int NB_G1  = 8;                         // 128/16
    const int GY_POL = (ACT_DIM + 127) / 128;     // 37
    const int NB_POL = GY_POL * 8;                // 296 (padded)

    char* ws = (char*)d_ws;
    size_t off = 0;
    auto alloc = [&](size_t nbytes) {
        void* pp = ws + off;
        off = (off + nbytes + 255) & ~(size_t)255;
        return pp;
    };
    float* h      = (float*)alloc((size_t)N * CN * 4);
    float* xlr    = (float*)alloc((size_t)N * 512 * 4);       // reused as gtmp
    float* Wcat   = (float*)alloc((size_t)4 * 256 * 512 * 4);
    unsigned short* WcatH = (unsigned short*)alloc((size_t)4 * 8 * NB_CAT * 512 * 2);
    unsigned short* WcatL = (unsigned short*)alloc((size_t)4 * 8 * NB_CAT * 512 * 2);
    unsigned short* gW1H  = (unsigned short*)alloc((size_t)8 * NB_G1 * 512 * 2);
    unsigned short* gW1L  = (unsigned short*)alloc((size_t)8 * NB_G1 * 512 * 2);
    unsigned short* pW2H  = (unsigned short*)alloc((size_t)8 * NB_POL * 512 * 2);
    unsigned short* pW2L  = (unsigned short*)alloc((size_t)8 * NB_POL * 512 * 2);
    float* gate   = (float*)alloc((size_t)N * 4);
    float* emb    = (float*)alloc((size_t)G * CN * 4);
    float* t1     = (float*)alloc((size_t)G * CN * 4);
    int*   rowptr = (int*)alloc((size_t)(N + 1) * 4);
    int*   cnt    = (int*)alloc((size_t)N * 4);
    int*   cursor = (int*)alloc((size_t)N * 4);
    int*   btot   = (int*)alloc((size_t)64 * 4);
    int*   csrc   = (int*)alloc((size_t)E * 4);
    float* gtmp   = xlr;

    const int* e_src = ei;
    const int* e_dst = ei + E;

    hipMemsetAsync(cnt, 0, (size_t)N * 4, stream);
    hipMemsetAsync(cursor, 0, (size_t)N * 4, stream);
    count_kernel<<<(E + 255) / 256, 256, 0, stream>>>(e_dst, cnt, E);
    scan1_kernel<<<NB_SC, 1024, 0, stream>>>(cnt, rowptr, btot, N);
    scan2_kernel<<<1, 64, 0, stream>>>(btot, NB_SC);
    scan3_kernel<<<(N + 1024) / 1024, 1024, 0, stream>>>(rowptr, btot, N, NB_SC);
    fill_kernel<<<(E + 255) / 256, 256, 0, stream>>>(e_src, e_dst, rowptr, cursor, csrc, E);

    embed_kernel<<<N / 16, 256, 0, stream>>>(x, W_emb, b_emb, pos_emb, h);
    wcat_kernel<<<(4 * 256 * 512) / 256, 256, 0, stream>>>(gat_Wsrc, gat_Wdst, Wcat);

    // weight decompose + relayout
    {
        int totc = 8 * NB_CAT * 512;
        for (int l = 0; l < 4; ++l)
            wconv_kernel<<<(totc + 255) / 256, 256, 0, stream>>>(
                Wcat + (size_t)l * 256 * 512, WcatH + (size_t)l * totc,
                WcatL + (size_t)l * totc, 512, NB_CAT, totc);
        int totg = 8 * NB_G1 * 512;
        wconv_kernel<<<(totg + 255) / 256, 256, 0, stream>>>(gW1, gW1H, gW1L, GATE_DIM, NB_G1, totg);
        int totp = 8 * NB_POL * 512;
        wconv_kernel<<<(totp + 255) / 256, 256, 0, stream>>>(pW2, pW2H, pW2L, ACT_DIM, NB_POL, totp);
    }

    for (int l = 0; l < 4; ++l) {
        size_t wo = (size_t)l * 8 * NB_CAT * 512;
        dim3 g1(N / 128, 512 / 128);
        mgemm<false><<<g1, 256, 0, stream>>>(h, WcatH + wo, WcatL + wo, nullptr,
                                             xlr, N, 512, NB_CAT, CN);
        gat_agg<<<N, 256, 0, stream>>>(xlr, rowptr, csrc, gat_att + l * CN,
                                       gat_bias + l * CN, ln_g + l * CN, ln_b + l * CN, h);
    }

    // gate MLP
    {
        dim3 g1(N / 128, 1);
        mgemm<true><<<g1, 256, 0, stream>>>(h, gW1H, gW1L, gb1, gtmp, N, GATE_DIM, NB_G1, CN);
        gate2_kernel<<<(N + 3) / 4, 256, 0, stream>>>(gtmp, gW2, gb2, gate, N);
    }
    pool_kernel<<<G, 256, 0, stream>>>(gate, h, emb);

    float* policy = (float*)d_out;
    float* value  = (float*)d_out + (size_t)G * ACT_DIM;
    head_kernel<<<G, 256, 0, stream>>>(emb, pW1, pb1, p_ln_g, p_ln_b,
                                       vW1, vb1, vW2, vb2, t1, value);
    dim3 g2(G / 128, GY_POL);
    mgemm<true><<<g2, 256, 0, stream>>>(t1, pW2H, pW2L, pb2, policy, G, ACT_DIM, NB_POL, CN);
}

// Round 4
// 468.513 us; speedup vs baseline: 2.7040x; 2.0826x over previous
//
#include <hip/hip_runtime.h>
#include <math.h>

constexpr int CN = 256;        // channels
constexpr int NHEAD = 8;       // attention heads
constexpr int KPG = 88;        // nodes per graph
constexpr int NIDF = 16;       // input node features
constexpr int GATE_DIM = 128;
constexpr int ACT_DIM = 4644;

typedef __attribute__((ext_vector_type(8))) short bf16x8;
typedef __attribute__((ext_vector_type(4))) float f32x4;

__device__ __forceinline__ unsigned short f2bf(float f) {
    unsigned int u = __float_as_uint(f);
    unsigned int r = (u + 0x7fffu + ((u >> 16) & 1u)) >> 16;
    return (unsigned short)r;
}
__device__ __forceinline__ float bf2f(unsigned short h) {
    return __uint_as_float(((unsigned int)h) << 16);
}

__device__ __forceinline__ void glds16(const void* g, void* l) {
    __builtin_amdgcn_global_load_lds(
        (const __attribute__((address_space(1))) unsigned int*)g,
        (__attribute__((address_space(3))) unsigned int*)l, 16, 0, 0);
}

// ---------------------------------------------------------------------------
// CSR build: count -> hierarchical scan -> fill
// ---------------------------------------------------------------------------
__global__ void count_kernel(const int* __restrict__ dst, int* __restrict__ cnt, int E) {
    int e = blockIdx.x * 256 + threadIdx.x;
    if (e < E) atomicAdd(&cnt[dst[e]], 1);
}

__global__ __launch_bounds__(1024) void scan1_kernel(const int* __restrict__ cnt,
                                                     int* __restrict__ rowptr,
                                                     int* __restrict__ btot, int n) {
    __shared__ int buf[1024];
    int tid = threadIdx.x;
    int i = blockIdx.x * 1024 + tid;
    int v = (i < n) ? cnt[i] : 0;
    buf[tid] = v;
    __syncthreads();
    for (int off = 1; off < 1024; off <<= 1) {
        int t = (tid >= off) ? buf[tid - off] : 0;
        __syncthreads();
        buf[tid] += t;
        __syncthreads();
    }
    if (i < n) rowptr[i] = buf[tid] - v;
    if (tid == 1023) btot[blockIdx.x] = buf[1023];
}

__global__ void scan2_kernel(int* __restrict__ btot, int nb) {
    if (threadIdx.x == 0 && blockIdx.x == 0) {
        int s = 0;
        for (int b = 0; b < nb; ++b) { int t = btot[b]; btot[b] = s; s += t; }
        btot[nb] = s;
    }
}

__global__ __launch_bounds__(1024) void scan3_kernel(int* __restrict__ rowptr,
                                                     const int* __restrict__ btot,
                                                     int n, int nb) {
    int i = blockIdx.x * 1024 + threadIdx.x;
    if (i < n) rowptr[i] += btot[i >> 10];
    else if (i == n) rowptr[n] = btot[nb];
}

__global__ void fill_kernel(const int* __restrict__ src, const int* __restrict__ dst,
                            const int* __restrict__ rowptr, int* __restrict__ cursor,
                            int* __restrict__ csrc, int E) {
    int e = blockIdx.x * 256 + threadIdx.x;
    if (e < E) {
        int d = dst[e];
        int p = atomicAdd(&cursor[d], 1);
        csrc[rowptr[d] + p] = src[e];
    }
}

// ---------------------------------------------------------------------------
// Embedding: h = relu(x @ W_emb + b_emb) + pos_emb[n % 88]
// ---------------------------------------------------------------------------
__global__ __launch_bounds__(256) void embed_kernel(const float* __restrict__ x,
                                                    const float* __restrict__ Wemb,
                                                    const float* __restrict__ bemb,
                                                    const float* __restrict__ pos,
                                                    float* __restrict__ h) {
    __shared__ float Wl[NIDF][CN];
    int tid = threadIdx.x;
    for (int i = tid; i < NIDF * CN; i += 256) Wl[i >> 8][i & 255] = Wemb[i];
    __syncthreads();
    float bias = bemb[tid];
    int node0 = blockIdx.x * 16;
    for (int q = 0; q < 16; ++q) {
        int n = node0 + q;
        float acc = bias;
        #pragma unroll
        for (int k = 0; k < NIDF; ++k) acc += x[n * NIDF + k] * Wl[k][tid];
        h[(size_t)n * CN + tid] = fmaxf(acc, 0.f) + pos[(n % KPG) * CN + tid];
    }
}

// ---------------------------------------------------------------------------
// Wcat[l] = [Wsrc[l] | Wdst[l]]  ->  [256, 512] per layer (fp32)
// ---------------------------------------------------------------------------
__global__ void wcat_kernel(const float* __restrict__ Ws, const float* __restrict__ Wd,
                            float* __restrict__ Wcat) {
    int i = blockIdx.x * 256 + threadIdx.x;
    int l = i >> 17;
    int r = (i >> 9) & 255;
    int c = i & 511;
    Wcat[i] = (c < 256) ? Ws[((size_t)l * 256 + r) * 256 + c]
                        : Wd[((size_t)l * 256 + r) * 256 + (c - 256)];
}

// ---------------------------------------------------------------------------
// Weight decompose + fragment-order relayout:
// out[kb][nb][lane][j] = W[kb*32 + (lane>>4)*8 + j][nb*16 + (lane&15)]
// ---------------------------------------------------------------------------
__global__ void wconv_kernel(const float* __restrict__ W, unsigned short* __restrict__ Bh,
                             unsigned short* __restrict__ Bl, int Nn, int NB, int tot) {
    int o = blockIdx.x * 256 + threadIdx.x;
    if (o >= tot) return;
    int idx = o & 511;
    int nb = (o >> 9) % NB;
    int kb = o / (512 * NB);
    int l = idx >> 3, j = idx & 7;
    int k = kb * 32 + (l >> 4) * 8 + j;
    int c = nb * 16 + (l & 15);
    float v = (c < Nn) ? W[(size_t)k * Nn + c] : 0.f;
    unsigned short hh = f2bf(v);
    Bh[o] = hh;
    Bl[o] = f2bf(v - bf2f(hh));
}

// ---------------------------------------------------------------------------
// MFMA GEMM, bf16 split 3-product: C = A(f32)[M,K] @ B[K,N] (+bias)
// tile 128x128, BK=32, 256 threads (4 waves 2x2, wave tile 64x64).
// ---------------------------------------------------------------------------
template <bool BIAS>
__global__ __launch_bounds__(256) void mgemm(const float* __restrict__ A,
                                             const unsigned short* __restrict__ Bh,
                                             const unsigned short* __restrict__ Bl,
                                             const float* __restrict__ bias,
                                             float* __restrict__ C,
                                             int M, int Nlog, int NB, int K) {
    __shared__ unsigned short Ah[8 * 64 * 8];
    __shared__ unsigned short Al[8 * 64 * 8];
    __shared__ unsigned short Bsh[8 * 64 * 8];
    __shared__ unsigned short Bsl[8 * 64 * 8];
    int tid = threadIdx.x;
    int wid = tid >> 6, lane = tid & 63;
    int row0 = blockIdx.x * 128;
    int cb = blockIdx.y;
    int wr = wid >> 1, wc = wid & 1;

    f32x4 acc[4][4] = {};

    int r = tid >> 1, kh = (tid & 1) * 16;
    int mb = r >> 4, rr = r & 15;

    for (int k0 = 0; k0 < K; k0 += 32) {
        int kb = k0 >> 5;
        // ---- stage A (fp32 -> hi/lo bf16, fragment order) ----
        {
            const float* ap = A + (size_t)(row0 + r) * K + k0 + kh;
            float4 f0 = *reinterpret_cast<const float4*>(ap);
            float4 f1 = *reinterpret_cast<const float4*>(ap + 4);
            float4 f2 = *reinterpret_cast<const float4*>(ap + 8);
            float4 f3 = *reinterpret_cast<const float4*>(ap + 12);
            float vv[16] = {f0.x, f0.y, f0.z, f0.w, f1.x, f1.y, f1.z, f1.w,
                            f2.x, f2.y, f2.z, f2.w, f3.x, f3.y, f3.z, f3.w};
            #pragma unroll
            for (int s = 0; s < 2; ++s) {
                bf16x8 ph, pl;
                #pragma unroll
                for (int j = 0; j < 8; ++j) {
                    float v = vv[s * 8 + j];
                    unsigned short hb = f2bf(v);
                    ph[j] = (short)hb;
                    pl[j] = (short)f2bf(v - bf2f(hb));
                }
                int l = (kh / 8 + s) * 16 + rr;
                int off = (mb * 64 + l) * 8;
                *reinterpret_cast<bf16x8*>(&Ah[off]) = ph;
                *reinterpret_cast<bf16x8*>(&Al[off]) = pl;
            }
        }
        // ---- stage B (async copy, already fragment order) ----
        {
            size_t base = ((size_t)kb * NB + (size_t)cb * 8) * 512;
            for (int ch = wid; ch < 8; ch += 4) {
                glds16(Bh + base + ch * 512 + lane * 8, &Bsh[ch * 512]);
                glds16(Bl + base + ch * 512 + lane * 8, &Bsl[ch * 512]);
            }
        }
        __syncthreads();
        // ---- fragments + MFMA ----
        bf16x8 a_h[4], a_l[4], b_h[4], b_l[4];
        #pragma unroll
        for (int mf = 0; mf < 4; ++mf) {
            int off = ((wr * 4 + mf) * 64 + lane) * 8;
            a_h[mf] = *reinterpret_cast<const bf16x8*>(&Ah[off]);
            a_l[mf] = *reinterpret_cast<const bf16x8*>(&Al[off]);
        }
        #pragma unroll
        for (int nf = 0; nf < 4; ++nf) {
            int off = ((wc * 4 + nf) * 64 + lane) * 8;
            b_h[nf] = *reinterpret_cast<const bf16x8*>(&Bsh[off]);
            b_l[nf] = *reinterpret_cast<const bf16x8*>(&Bsl[off]);
        }
        #pragma unroll
        for (int mf = 0; mf < 4; ++mf)
            #pragma unroll
            for (int nf = 0; nf < 4; ++nf) {
                acc[mf][nf] = __builtin_amdgcn_mfma_f32_16x16x32_bf16(a_h[mf], b_h[nf], acc[mf][nf], 0, 0, 0);
                acc[mf][nf] = __builtin_amdgcn_mfma_f32_16x16x32_bf16(a_h[mf], b_l[nf], acc[mf][nf], 0, 0, 0);
                acc[mf][nf] = __builtin_amdgcn_mfma_f32_16x16x32_bf16(a_l[mf], b_h[nf], acc[mf][nf], 0, 0, 0);
            }
        __syncthreads();
    }
    // ---- epilogue ----
    #pragma unroll
    for (int mf = 0; mf < 4; ++mf) {
        #pragma unroll
        for (int nf = 0; nf < 4; ++nf) {
            int col = cb * 128 + wc * 64 + nf * 16 + (lane & 15);
            if (col < Nlog) {
                float bv = BIAS ? bias[col] : 0.f;
                #pragma unroll
                for (int rg = 0; rg < 4; ++rg) {
                    int row = row0 + wr * 64 + mf * 16 + (lane >> 4) * 4 + rg;
                    C[(size_t)row * Nlog + col] = acc[mf][nf][rg] + bv;
                }
            }
        }
    }
}

// ---------------------------------------------------------------------------
// GAT aggregate v3: ONE WAVE PER NODE, no LDS, no barriers.
// Lane l owns channels 4l..4l+3 (all in head l>>3). Per edge: float4 gather
// of xl[src] (L2), leaky+dot, 3-shfl reduce in 8-lane head group, per-lane
// online softmax, reuse xl4 regs for weighted accumulation. Software-
// pipelined one edge ahead. Epilogue: bias/relu/residual/LN via wave shfl.
// 8 waves/block (8 nodes). Bijective XCD swizzle (grid % 8 == 0).
// ---------------------------------------------------------------------------
__global__ __launch_bounds__(512) void gat_agg(const float* __restrict__ xlr,
                                               const int* __restrict__ rowptr,
                                               const int* __restrict__ csrc,
                                               const float* __restrict__ att,
                                               const float* __restrict__ bias,
                                               const float* __restrict__ lng,
                                               const float* __restrict__ lnb,
                                               float* __restrict__ h) {
    int cpx = gridDim.x >> 3;                      // blocks per XCD slice
    int swz = (blockIdx.x & 7) * cpx + (blockIdx.x >> 3);
    int wid = threadIdx.x >> 6, lane = threadIdx.x & 63;
    int n = swz * 8 + wid;

    float4 xr4 = *reinterpret_cast<const float4*>(xlr + (size_t)n * 512 + 256 + lane * 4);
    float4 at4 = *reinterpret_cast<const float4*>(att + lane * 4);
    float4 hr4 = *reinterpret_cast<const float4*>(h + (size_t)n * CN + lane * 4);

    int e0 = rowptr[n], e1 = rowptr[n + 1];
    float m_r = -INFINITY, s_r = 0.f;
    float a0 = 0.f, a1 = 0.f, a2 = 0.f, a3 = 0.f;

    // software pipeline: one edge ahead
    float4 nxt = *reinterpret_cast<const float4*>(xlr + (size_t)csrc[e0] * 512 + lane * 4);
    for (int e = e0; e < e1; ++e) {
        float4 xl4 = nxt;
        if (e + 1 < e1)
            nxt = *reinterpret_cast<const float4*>(xlr + (size_t)csrc[e + 1] * 512 + lane * 4);
        float z, p = 0.f;
        z = xl4.x + xr4.x; z = z >= 0.f ? z : 0.2f * z; p += z * at4.x;
        z = xl4.y + xr4.y; z = z >= 0.f ? z : 0.2f * z; p += z * at4.y;
        z = xl4.z + xr4.z; z = z >= 0.f ? z : 0.2f * z; p += z * at4.z;
        z = xl4.w + xr4.w; z = z >= 0.f ? z : 0.2f * z; p += z * at4.w;
        p += __shfl_xor(p, 4);
        p += __shfl_xor(p, 2);
        p += __shfl_xor(p, 1);          // all 8 lanes of the head group hold e
        float nm = fmaxf(m_r, p);
        float f = expf(m_r - nm);        // first iter: exp(-inf) = 0
        float w = expf(p - nm);
        s_r = s_r * f + w;
        m_r = nm;
        a0 = a0 * f + w * xl4.x;
        a1 = a1 * f + w * xl4.y;
        a2 = a2 * f + w * xl4.z;
        a3 = a3 * f + w * xl4.w;
    }

    float inv = 1.f / s_r;
    float4 bi4 = *reinterpret_cast<const float4*>(bias + lane * 4);
    float v0 = hr4.x + fmaxf(a0 * inv + bi4.x, 0.f);
    float v1 = hr4.y + fmaxf(a1 * inv + bi4.y, 0.f);
    float v2 = hr4.z + fmaxf(a2 * inv + bi4.z, 0.f);
    float v3 = hr4.w + fmaxf(a3 * inv + bi4.w, 0.f);

    float sum = v0 + v1 + v2 + v3;
    float sq = v0 * v0 + v1 * v1 + v2 * v2 + v3 * v3;
    #pragma unroll
    for (int o = 32; o; o >>= 1) { sum += __shfl_xor(sum, o); sq += __shfl_xor(sq, o); }
    float mu = sum / CN;
    float var = sq / CN - mu * mu;
    float ninv = rsqrtf(var + 1e-5f);
    float4 lg4 = *reinterpret_cast<const float4*>(lng + lane * 4);
    float4 lb4 = *reinterpret_cast<const float4*>(lnb + lane * 4);
    float4 out;
    out.x = (v0 - mu) * ninv * lg4.x + lb4.x;
    out.y = (v1 - mu) * ninv * lg4.y + lb4.y;
    out.z = (v2 - mu) * ninv * lg4.z + lb4.z;
    out.w = (v3 - mu) * ninv * lg4.w + lb4.w;
    *reinterpret_cast<float4*>(h + (size_t)n * CN + lane * 4) = out;
}

// ---------------------------------------------------------------------------
// gate[n] = relu(gtmp[n]) . gW2 + gb2
// ---------------------------------------------------------------------------
__global__ __launch_bounds__(256) void gate2_kernel(const float* __restrict__ gtmp,
                                                    const float* __restrict__ gW2,
                                                    const float* __restrict__ gb2,
                                                    float* __restrict__ gate, int N) {
    int n = blockIdx.x * 4 + (threadIdx.x >> 6);
    if (n >= N) return;
    int lane = threadIdx.x & 63;
    float2 t = *reinterpret_cast<const float2*>(gtmp + (size_t)n * GATE_DIM + lane * 2);
    float2 w = *reinterpret_cast<const float2*>(gW2 + lane * 2);
    float c = fmaxf(t.x, 0.f) * w.x + fmaxf(t.y, 0.f) * w.y;
    #pragma unroll
    for (int o = 32; o; o >>= 1) c += __shfl_xor(c, o);
    if (lane == 0) gate[n] = c + gb2[0];
}

// ---------------------------------------------------------------------------
// Pool: segment softmax over contiguous 88-node graphs + weighted sum -> emb
// ---------------------------------------------------------------------------
__global__ __launch_bounds__(256) void pool_kernel(const float* __restrict__ gate,
                                                   const float* __restrict__ h,
                                                   float* __restrict__ emb) {
    __shared__ float a[KPG];
    __shared__ float wm[4];
    int g = blockIdx.x, tid = threadIdx.x;
    int wid = tid >> 6, lane = tid & 63;
    float gv = (tid < KPG) ? gate[g * KPG + tid] : -INFINITY;
    float m = gv;
    #pragma unroll
    for (int o = 32; o; o >>= 1) m = fmaxf(m, __shfl_xor(m, o));
    if (lane == 0) wm[wid] = m;
    __syncthreads();
    m = fmaxf(fmaxf(wm[0], wm[1]), fmaxf(wm[2], wm[3]));
    __syncthreads();
    float av = (tid < KPG) ? expf(gv - m) : 0.f;
    if (tid < KPG) a[tid] = av;
    float s = av;
    #pragma unroll
    for (int o = 32; o; o >>= 1) s += __shfl_xor(s, o);
    if (lane == 0) wm[wid] = s;
    __syncthreads();
    s = wm[0] + wm[1] + wm[2] + wm[3];
    float inv = 1.f / s;
    float acc = 0.f;
    const float* hg = h + (size_t)g * KPG * CN;
    for (int i = 0; i < KPG; ++i) acc += a[i] * hg[i * CN + tid];
    emb[(size_t)g * CN + tid] = acc * inv;
}

// ---------------------------------------------------------------------------
// Heads: t1 = relu(LN(emb@pW1+pb1)); value = tanh(relu(emb@vW1+vb1)@vW2+vb2)
// ---------------------------------------------------------------------------
__global__ __launch_bounds__(256) void head_kernel(const float* __restrict__ emb,
    const float* __restrict__ pW1, const float* __restrict__ pb1,
    const float* __restrict__ plng, const float* __restrict__ plnb,
    const float* __restrict__ vW1, const float* __restrict__ vb1,
    const float* __restrict__ vW2, const float* __restrict__ vb2,
    float* __restrict__ t1, float* __restrict__ value_out) {
    __shared__ float e_l[CN];
    __shared__ float rsum[4], rsq[4];
    int g = blockIdx.x, tid = threadIdx.x;
    int wid = tid >> 6, lane = tid & 63;
    e_l[tid] = emb[(size_t)g * CN + tid];
    __syncthreads();
    float p = pb1[tid], v = vb1[tid];
    for (int k = 0; k < CN; ++k) {
        float e = e_l[k];
        p += e * pW1[k * CN + tid];
        v += e * vW1[k * CN + tid];
    }
    float sum = p, sq = p * p;
    #pragma unroll
    for (int o = 32; o; o >>= 1) { sum += __shfl_xor(sum, o); sq += __shfl_xor(sq, o); }
    if (lane == 0) { rsum[wid] = sum; rsq[wid] = sq; }
    __syncthreads();
    sum = rsum[0] + rsum[1] + rsum[2] + rsum[3];
    sq  = rsq[0] + rsq[1] + rsq[2] + rsq[3];
    float mu = sum / CN;
    float var = sq / CN - mu * mu;
    float inv = rsqrtf(var + 1e-5f);
    t1[(size_t)g * CN + tid] = fmaxf((p - mu) * inv * plng[tid] + plnb[tid], 0.f);
    float contrib = fmaxf(v, 0.f) * vW2[tid];
    __syncthreads();
    #pragma unroll
    for (int o = 32; o; o >>= 1) contrib += __shfl_xor(contrib, o);
    if (lane == 0) rsum[wid] = contrib;
    __syncthreads();
    if (tid == 0)
        value_out[g] = tanhf(rsum[0] + rsum[1] + rsum[2] + rsum[3] + vb2[0]);
}

// ---------------------------------------------------------------------------
extern "C" void kernel_launch(void* const* d_in, const int* in_sizes, int n_in,
                              void* d_out, int out_size, void* d_ws, size_t ws_size,
                              hipStream_t stream) {
    const float* x        = (const float*)d_in[0];
    const int*   ei       = (const int*)d_in[1];
    const float* W_emb    = (const float*)d_in[4];
    const float* b_emb    = (const float*)d_in[5];
    const float* pos_emb  = (const float*)d_in[6];
    const float* gat_Wsrc = (const float*)d_in[7];
    const float* gat_Wdst = (const float*)d_in[8];
    const float* gat_att  = (const float*)d_in[9];
    const float* gat_bias = (const float*)d_in[10];
    const float* ln_g     = (const float*)d_in[11];
    const float* ln_b     = (const float*)d_in[12];
    const float* gW1      = (const float*)d_in[13];
    const float* gb1      = (const float*)d_in[14];
    const float* gW2      = (const float*)d_in[15];
    const float* gb2      = (const float*)d_in[16];
    const float* pW1      = (const float*)d_in[17];
    const float* pb1      = (const float*)d_in[18];
    const float* p_ln_g   = (const float*)d_in[19];
    const float* p_ln_b   = (const float*)d_in[20];
    const float* pW2      = (const float*)d_in[21];
    const float* pb2      = (const float*)d_in[22];
    const float* vW1      = (const float*)d_in[23];
    const float* vb1      = (const float*)d_in[24];
    const float* vW2      = (const float*)d_in[25];
    const float* vb2      = (const float*)d_in[26];

    const int N = in_sizes[2];      // 22528
    const int E = in_sizes[1] / 2;  // 405504
    const int G = N / KPG;          // 256
    const int NB_SC = (N + 1023) / 1024;

    const int NB_CAT = 32;                        // 512/16
    const int NB_G1  = 8;                         // 128/16
    const int GY_POL = (ACT_DIM + 127) / 128;     // 37
    const int NB_POL = GY_POL * 8;                // 296 (padded)

    char* ws = (char*)d_ws;
    size_t off = 0;
    auto alloc = [&](size_t nbytes) {
        void* pp = ws + off;
        off = (off + nbytes + 255) & ~(size_t)255;
        return pp;
    };
    float* h      = (float*)alloc((size_t)N * CN * 4);
    float* xlr    = (float*)alloc((size_t)N * 512 * 4);       // reused as gtmp
    float* Wcat   = (float*)alloc((size_t)4 * 256 * 512 * 4);
    unsigned short* WcatH = (unsigned short*)alloc((size_t)4 * 8 * NB_CAT * 512 * 2);
    unsigned short* WcatL = (unsigned short*)alloc((size_t)4 * 8 * NB_CAT * 512 * 2);
    unsigned short* gW1H  = (unsigned short*)alloc((size_t)8 * NB_G1 * 512 * 2);
    unsigned short* gW1L  = (unsigned short*)alloc((size_t)8 * NB_G1 * 512 * 2);
    unsigned short* pW2H  = (unsigned short*)alloc((size_t)8 * NB_POL * 512 * 2);
    unsigned short* pW2L  = (unsigned short*)alloc((size_t)8 * NB_POL * 512 * 2);
    float* gate   = (float*)alloc((size_t)N * 4);
    float* emb    = (float*)alloc((size_t)G * CN * 4);
    float* t1     = (float*)alloc((size_t)G * CN * 4);
    int*   rowptr = (int*)alloc((size_t)(N + 1) * 4);
    int*   cnt    = (int*)alloc((size_t)N * 4);
    int*   cursor = (int*)alloc((size_t)N * 4);
    int*   btot   = (int*)alloc((size_t)64 * 4);
    int*   csrc   = (int*)alloc((size_t)E * 4);
    float* gtmp   = xlr;

    const int* e_src = ei;
    const int* e_dst = ei + E;

    hipMemsetAsync(cnt, 0, (size_t)N * 4, stream);
    hipMemsetAsync(cursor, 0, (size_t)N * 4, stream);
    count_kernel<<<(E + 255) / 256, 256, 0, stream>>>(e_dst, cnt, E);
    scan1_kernel<<<NB_SC, 1024, 0, stream>>>(cnt, rowptr, btot, N);
    scan2_kernel<<<1, 64, 0, stream>>>(btot, NB_SC);
    scan3_kernel<<<(N + 1024) / 1024, 1024, 0, stream>>>(rowptr, btot, N, NB_SC);
    fill_kernel<<<(E + 255) / 256, 256, 0, stream>>>(e_src, e_dst, rowptr, cursor, csrc, E);

    embed_kernel<<<N / 16, 256, 0, stream>>>(x, W_emb, b_emb, pos_emb, h);
    wcat_kernel<<<(4 * 256 * 512) / 256, 256, 0, stream>>>(gat_Wsrc, gat_Wdst, Wcat);

    {
        int totc = 8 * NB_CAT * 512;
        for (int l = 0; l < 4; ++l)
            wconv_kernel<<<(totc + 255) / 256, 256, 0, stream>>>(
                Wcat + (size_t)l * 256 * 512, WcatH + (size_t)l * totc,
                WcatL + (size_t)l * totc, 512, NB_CAT, totc);
        int totg = 8 * NB_G1 * 512;
        wconv_kernel<<<(totg + 255) / 256, 256, 0, stream>>>(gW1, gW1H, gW1L, GATE_DIM, NB_G1, totg);
        int totp = 8 * NB_POL * 512;
        wconv_kernel<<<(totp + 255) / 256, 256, 0, stream>>>(pW2, pW2H, pW2L, ACT_DIM, NB_POL, totp);
    }

    for (int l = 0; l < 4; ++l) {
        size_t wo = (size_t)l * 8 * NB_CAT * 512;
        dim3 g1(N / 128, 512 / 128);
        mgemm<false><<<g1, 256, 0, stream>>>(h, WcatH + wo, WcatL + wo, nullptr,
                                             xlr, N, 512, NB_CAT, CN);
        gat_agg<<<N / 8, 512, 0, stream>>>(xlr, rowptr, csrc, gat_att + l * CN,
                                           gat_bias + l * CN, ln_g + l * CN, ln_b + l * CN, h);
    }

    // gate MLP
    {
        dim3 g1(N / 128, 1);
        mgemm<true><<<g1, 256, 0, stream>>>(h, gW1H, gW1L, gb1, gtmp, N, GATE_DIM, NB_G1, CN);
        gate2_kernel<<<(N + 3) / 4, 256, 0, stream>>>(gtmp, gW2, gb2, gate, N);
    }
    pool_kernel<<<G, 256, 0, stream>>>(gate, h, emb);

    float* policy = (float*)d_out;
    float* value  = (float*)d_out + (size_t)G * ACT_DIM;
    head_kernel<<<G, 256, 0, stream>>>(emb, pW1, pb1, p_ln_g, p_ln_b,
                                       vW1, vb1, vW2, vb2, t1, value);
    dim3 g2(G / 128, GY_POL);
    mgemm<true><<<g2, 256, 0, stream>>>(t1, pW2H, pW2L, pb2, policy, G, ACT_DIM, NB_POL, CN);
}

// Round 5
// 438.301 us; speedup vs baseline: 2.8903x; 1.0689x over previous
//
#include <hip/hip_runtime.h>
#include <math.h>

constexpr int CN = 256;        // channels
constexpr int NHEAD = 8;       // attention heads
constexpr int KPG = 88;        // nodes per graph
constexpr int NIDF = 16;       // input node features
constexpr int GATE_DIM = 128;
constexpr int ACT_DIM = 4644;

typedef __attribute__((ext_vector_type(8))) short bf16x8;
typedef __attribute__((ext_vector_type(4))) float f32x4;

__device__ __forceinline__ unsigned short f2bf(float f) {
    unsigned int u = __float_as_uint(f);
    unsigned int r = (u + 0x7fffu + ((u >> 16) & 1u)) >> 16;
    return (unsigned short)r;
}
__device__ __forceinline__ float bf2f(unsigned short h) {
    return __uint_as_float(((unsigned int)h) << 16);
}

__device__ __forceinline__ void glds16(const void* g, void* l) {
    __builtin_amdgcn_global_load_lds(
        (const __attribute__((address_space(1))) unsigned int*)g,
        (__attribute__((address_space(3))) unsigned int*)l, 16, 0, 0);
}

// 8-lane group sum via DPP (VALU-speed, no LDS pipe):
// quad_perm xor1 (0xB1), quad_perm xor2 (0x4E), row_half_mirror (0x141)
__device__ __forceinline__ float grp8_sum(float p) {
    int t;
    t = __builtin_amdgcn_mov_dpp(__float_as_int(p), 0xB1, 0xF, 0xF, true);
    p += __int_as_float(t);
    t = __builtin_amdgcn_mov_dpp(__float_as_int(p), 0x4E, 0xF, 0xF, true);
    p += __int_as_float(t);
    t = __builtin_amdgcn_mov_dpp(__float_as_int(p), 0x141, 0xF, 0xF, true);
    p += __int_as_float(t);
    return p;
}

// ---------------------------------------------------------------------------
// CSR build: count -> hierarchical scan -> fill
// ---------------------------------------------------------------------------
__global__ void count_kernel(const int* __restrict__ dst, int* __restrict__ cnt, int E) {
    int e = blockIdx.x * 256 + threadIdx.x;
    if (e < E) atomicAdd(&cnt[dst[e]], 1);
}

__global__ __launch_bounds__(1024) void scan1_kernel(const int* __restrict__ cnt,
                                                     int* __restrict__ rowptr,
                                                     int* __restrict__ btot, int n) {
    __shared__ int buf[1024];
    int tid = threadIdx.x;
    int i = blockIdx.x * 1024 + tid;
    int v = (i < n) ? cnt[i] : 0;
    buf[tid] = v;
    __syncthreads();
    for (int off = 1; off < 1024; off <<= 1) {
        int t = (tid >= off) ? buf[tid - off] : 0;
        __syncthreads();
        buf[tid] += t;
        __syncthreads();
    }
    if (i < n) rowptr[i] = buf[tid] - v;
    if (tid == 1023) btot[blockIdx.x] = buf[1023];
}

__global__ void scan2_kernel(int* __restrict__ btot, int nb) {
    if (threadIdx.x == 0 && blockIdx.x == 0) {
        int s = 0;
        for (int b = 0; b < nb; ++b) { int t = btot[b]; btot[b] = s; s += t; }
        btot[nb] = s;
    }
}

__global__ __launch_bounds__(1024) void scan3_kernel(int* __restrict__ rowptr,
                                                     const int* __restrict__ btot,
                                                     int n, int nb) {
    int i = blockIdx.x * 1024 + threadIdx.x;
    if (i < n) rowptr[i] += btot[i >> 10];
    else if (i == n) rowptr[n] = btot[nb];
}

__global__ void fill_kernel(const int* __restrict__ src, const int* __restrict__ dst,
                            const int* __restrict__ rowptr, int* __restrict__ cursor,
                            int* __restrict__ csrc, int E) {
    int e = blockIdx.x * 256 + threadIdx.x;
    if (e < E) {
        int d = dst[e];
        int p = atomicAdd(&cursor[d], 1);
        csrc[rowptr[d] + p] = src[e];
    }
}

// ---------------------------------------------------------------------------
// Embedding: h = relu(x @ W_emb + b_emb) + pos_emb[n % 88]; also bf16 hi/lo
// ---------------------------------------------------------------------------
__global__ __launch_bounds__(256) void embed_kernel(const float* __restrict__ x,
                                                    const float* __restrict__ Wemb,
                                                    const float* __restrict__ bemb,
                                                    const float* __restrict__ pos,
                                                    float* __restrict__ h,
                                                    unsigned short* __restrict__ hh,
                                                    unsigned short* __restrict__ hl) {
    __shared__ float Wl[NIDF][CN];
    int tid = threadIdx.x;
    for (int i = tid; i < NIDF * CN; i += 256) Wl[i >> 8][i & 255] = Wemb[i];
    __syncthreads();
    float bias = bemb[tid];
    int node0 = blockIdx.x * 16;
    for (int q = 0; q < 16; ++q) {
        int n = node0 + q;
        float acc = bias;
        #pragma unroll
        for (int k = 0; k < NIDF; ++k) acc += x[n * NIDF + k] * Wl[k][tid];
        float val = fmaxf(acc, 0.f) + pos[(n % KPG) * CN + tid];
        h[(size_t)n * CN + tid] = val;
        unsigned short vh = f2bf(val);
        hh[(size_t)n * CN + tid] = vh;
        hl[(size_t)n * CN + tid] = f2bf(val - bf2f(vh));
    }
}

// ---------------------------------------------------------------------------
// Weight decompose + fragment-order relayout (concat of Ws|Wd, 512 cols):
// out[kb][nb][lane][j] = W[kb*32 + (lane>>4)*8 + j][nb*16 + (lane&15)]
// ---------------------------------------------------------------------------
__global__ void wconv_cat_kernel(const float* __restrict__ Ws, const float* __restrict__ Wd,
                                 unsigned short* __restrict__ Bh,
                                 unsigned short* __restrict__ Bl, int NB, int tot) {
    int o = blockIdx.x * 256 + threadIdx.x;
    if (o >= tot) return;
    int idx = o & 511;
    int nb = (o >> 9) % NB;
    int kb = o / (512 * NB);
    int l = idx >> 3, j = idx & 7;
    int k = kb * 32 + (l >> 4) * 8 + j;
    int c = nb * 16 + (l & 15);
    float v = (c < 256) ? Ws[(size_t)k * 256 + c] : Wd[(size_t)k * 256 + (c - 256)];
    unsigned short hh = f2bf(v);
    Bh[o] = hh;
    Bl[o] = f2bf(v - bf2f(hh));
}

__global__ void wconv_kernel(const float* __restrict__ W, unsigned short* __restrict__ Bh,
                             unsigned short* __restrict__ Bl, int Nn, int NB, int tot) {
    int o = blockIdx.x * 256 + threadIdx.x;
    if (o >= tot) return;
    int idx = o & 511;
    int nb = (o >> 9) % NB;
    int kb = o / (512 * NB);
    int l = idx >> 3, j = idx & 7;
    int k = kb * 32 + (l >> 4) * 8 + j;
    int c = nb * 16 + (l & 15);
    float v = (c < Nn) ? W[(size_t)k * Nn + c] : 0.f;
    unsigned short hh = f2bf(v);
    Bh[o] = hh;
    Bl[o] = f2bf(v - bf2f(hh));
}

// ---------------------------------------------------------------------------
// MFMA GEMM, bf16 split 3-product: C = A[M,K] @ B[K,N] (+bias)
// A given pre-split row-major bf16 (Ah/Al); B pre-laid fragment-order.
// tile 128x128, BK=32, 256 threads (4 waves 2x2, wave tile 64x64).
// All staging via global_load_lds (no VALU repack).
// ---------------------------------------------------------------------------
template <bool BIAS>
__global__ __launch_bounds__(256) void mgemm(const unsigned short* __restrict__ Ah,
                                             const unsigned short* __restrict__ Al,
                                             const unsigned short* __restrict__ Bh,
                                             const unsigned short* __restrict__ Bl,
                                             const float* __restrict__ bias,
                                             float* __restrict__ C,
                                             int M, int Nlog, int NB, int K) {
    __shared__ unsigned short AhL[8 * 64 * 8];
    __shared__ unsigned short AlL[8 * 64 * 8];
    __shared__ unsigned short BhL[8 * 64 * 8];
    __shared__ unsigned short BlL[8 * 64 * 8];
    int tid = threadIdx.x;
    int wid = tid >> 6, lane = tid & 63;
    int row0 = blockIdx.x * 128;
    int cb = blockIdx.y;
    int wr = wid >> 1, wc = wid & 1;

    int rr = lane & 15, kq = lane >> 4;     // A staging: row-in-16, k-octet

    f32x4 acc[4][4] = {};

    for (int k0 = 0; k0 < K; k0 += 32) {
        int kb = k0 >> 5;
        // ---- stage A: wave w covers mb = 2w, 2w+1 (16 rows x 32 k each) ----
        {
            int mb0 = wid * 2;
            const unsigned short* s0 = Ah + (size_t)(row0 + mb0 * 16 + rr) * K + k0 + kq * 8;
            const unsigned short* s1 = Ah + (size_t)(row0 + mb0 * 16 + 16 + rr) * K + k0 + kq * 8;
            glds16(s0, &AhL[mb0 * 512]);
            glds16(s1, &AhL[mb0 * 512 + 512]);
            const unsigned short* t0 = Al + (size_t)(row0 + mb0 * 16 + rr) * K + k0 + kq * 8;
            const unsigned short* t1 = Al + (size_t)(row0 + mb0 * 16 + 16 + rr) * K + k0 + kq * 8;
            glds16(t0, &AlL[mb0 * 512]);
            glds16(t1, &AlL[mb0 * 512 + 512]);
        }
        // ---- stage B (fragment order) ----
        {
            size_t base = ((size_t)kb * NB + (size_t)cb * 8) * 512;
            for (int ch = wid; ch < 8; ch += 4) {
                glds16(Bh + base + ch * 512 + lane * 8, &BhL[ch * 512]);
                glds16(Bl + base + ch * 512 + lane * 8, &BlL[ch * 512]);
            }
        }
        __syncthreads();
        // ---- fragments + MFMA ----
        bf16x8 a_h[4], a_l[4], b_h[4], b_l[4];
        #pragma unroll
        for (int mf = 0; mf < 4; ++mf) {
            int off = ((wr * 4 + mf) * 64 + lane) * 8;
            a_h[mf] = *reinterpret_cast<const bf16x8*>(&AhL[off]);
            a_l[mf] = *reinterpret_cast<const bf16x8*>(&AlL[off]);
        }
        #pragma unroll
        for (int nf = 0; nf < 4; ++nf) {
            int off = ((wc * 4 + nf) * 64 + lane) * 8;
            b_h[nf] = *reinterpret_cast<const bf16x8*>(&BhL[off]);
            b_l[nf] = *reinterpret_cast<const bf16x8*>(&BlL[off]);
        }
        #pragma unroll
        for (int mf = 0; mf < 4; ++mf)
            #pragma unroll
            for (int nf = 0; nf < 4; ++nf) {
                acc[mf][nf] = __builtin_amdgcn_mfma_f32_16x16x32_bf16(a_h[mf], b_h[nf], acc[mf][nf], 0, 0, 0);
                acc[mf][nf] = __builtin_amdgcn_mfma_f32_16x16x32_bf16(a_h[mf], b_l[nf], acc[mf][nf], 0, 0, 0);
                acc[mf][nf] = __builtin_amdgcn_mfma_f32_16x16x32_bf16(a_l[mf], b_h[nf], acc[mf][nf], 0, 0, 0);
            }
        __syncthreads();
    }
    // ---- epilogue ----
    #pragma unroll
    for (int mf = 0; mf < 4; ++mf) {
        #pragma unroll
        for (int nf = 0; nf < 4; ++nf) {
            int col = cb * 128 + wc * 64 + nf * 16 + (lane & 15);
            if (col < Nlog) {
                float bv = BIAS ? bias[col] : 0.f;
                #pragma unroll
                for (int rg = 0; rg < 4; ++rg) {
                    int row = row0 + wr * 64 + mf * 16 + (lane >> 4) * 4 + rg;
                    C[(size_t)row * Nlog + col] = acc[mf][nf][rg] + bv;
                }
            }
        }
    }
}

// ---------------------------------------------------------------------------
// GAT aggregate v4: one wave per node, no LDS/barriers; unroll-2 edges with
// combined online-softmax update; DPP 8-lane score reduce; epilogue writes
// h (fp32) + hi/lo bf16 split for the next layer's MFMA GEMM.
// ---------------------------------------------------------------------------
__global__ __launch_bounds__(512) void gat_agg(const float* __restrict__ xlr,
                                               const int* __restrict__ rowptr,
                                               const int* __restrict__ csrc,
                                               const float* __restrict__ att,
                                               const float* __restrict__ bias,
                                               const float* __restrict__ lng,
                                               const float* __restrict__ lnb,
                                               float* __restrict__ h,
                                               unsigned short* __restrict__ hh,
                                               unsigned short* __restrict__ hl) {
    int cpx = gridDim.x >> 3;
    int swz = (blockIdx.x & 7) * cpx + (blockIdx.x >> 3);
    int wid = threadIdx.x >> 6, lane = threadIdx.x & 63;
    int n = swz * 8 + wid;

    float4 xr4 = *reinterpret_cast<const float4*>(xlr + (size_t)n * 512 + 256 + lane * 4);
    float4 at4 = *reinterpret_cast<const float4*>(att + lane * 4);
    float4 hr4 = *reinterpret_cast<const float4*>(h + (size_t)n * CN + lane * 4);

    int e0 = rowptr[n], e1 = rowptr[n + 1];
    float m_r = -INFINITY, s_r = 0.f;
    float a0 = 0.f, a1 = 0.f, a2 = 0.f, a3 = 0.f;

    float4 A4 = *reinterpret_cast<const float4*>(xlr + (size_t)csrc[e0] * 512 + lane * 4);
    float4 B4 = make_float4(0.f, 0.f, 0.f, 0.f);
    if (e0 + 1 < e1)
        B4 = *reinterpret_cast<const float4*>(xlr + (size_t)csrc[e0 + 1] * 512 + lane * 4);

    for (int e = e0; e < e1; e += 2) {
        bool two = (e + 1 < e1);
        float4 xa = A4, xb = B4;
        if (e + 2 < e1)
            A4 = *reinterpret_cast<const float4*>(xlr + (size_t)csrc[e + 2] * 512 + lane * 4);
        if (e + 3 < e1)
            B4 = *reinterpret_cast<const float4*>(xlr + (size_t)csrc[e + 3] * 512 + lane * 4);

        float z, pa = 0.f, pb = 0.f;
        z = xa.x + xr4.x; z = z >= 0.f ? z : 0.2f * z; pa += z * at4.x;
        z = xa.y + xr4.y; z = z >= 0.f ? z : 0.2f * z; pa += z * at4.y;
        z = xa.z + xr4.z; z = z >= 0.f ? z : 0.2f * z; pa += z * at4.z;
        z = xa.w + xr4.w; z = z >= 0.f ? z : 0.2f * z; pa += z * at4.w;
        z = xb.x + xr4.x; z = z >= 0.f ? z : 0.2f * z; pb += z * at4.x;
        z = xb.y + xr4.y; z = z >= 0.f ? z : 0.2f * z; pb += z * at4.y;
        z = xb.z + xr4.z; z = z >= 0.f ? z : 0.2f * z; pb += z * at4.z;
        z = xb.w + xr4.w; z = z >= 0.f ? z : 0.2f * z; pb += z * at4.w;
        pa = grp8_sum(pa);
        pb = grp8_sum(pb);
        pb = two ? pb : -INFINITY;

        float pm = fmaxf(pa, pb);
        float nm = fmaxf(m_r, pm);
        float f  = expf(m_r - nm);          // first iter: exp(-inf) = 0
        float wa = expf(pa - nm);
        float wb = expf(pb - nm);           // !two: exp(-inf) = 0
        s_r = s_r * f + wa + wb;
        m_r = nm;
        a0 = a0 * f + wa * xa.x + wb * xb.x;
        a1 = a1 * f + wa * xa.y + wb * xb.y;
        a2 = a2 * f + wa * xa.z + wb * xb.z;
        a3 = a3 * f + wa * xa.w + wb * xb.w;
    }

    float inv = 1.f / s_r;
    float4 bi4 = *reinterpret_cast<const float4*>(bias + lane * 4);
    float v0 = hr4.x + fmaxf(a0 * inv + bi4.x, 0.f);
    float v1 = hr4.y + fmaxf(a1 * inv + bi4.y, 0.f);
    float v2 = hr4.z + fmaxf(a2 * inv + bi4.z, 0.f);
    float v3 = hr4.w + fmaxf(a3 * inv + bi4.w, 0.f);

    float sum = v0 + v1 + v2 + v3;
    float sq = v0 * v0 + v1 * v1 + v2 * v2 + v3 * v3;
    #pragma unroll
    for (int o = 32; o; o >>= 1) { sum += __shfl_xor(sum, o); sq += __shfl_xor(sq, o); }
    float mu = sum / CN;
    float var = sq / CN - mu * mu;
    float ninv = rsqrtf(var + 1e-5f);
    float4 lg4 = *reinterpret_cast<const float4*>(lng + lane * 4);
    float4 lb4 = *reinterpret_cast<const float4*>(lnb + lane * 4);
    float o0 = (v0 - mu) * ninv * lg4.x + lb4.x;
    float o1 = (v1 - mu) * ninv * lg4.y + lb4.y;
    float o2 = (v2 - mu) * ninv * lg4.z + lb4.z;
    float o3 = (v3 - mu) * ninv * lg4.w + lb4.w;
    float4 out = make_float4(o0, o1, o2, o3);
    *reinterpret_cast<float4*>(h + (size_t)n * CN + lane * 4) = out;

    // bf16 hi/lo split for next GEMM
    ushort4 uh, ul;
    unsigned short t;
    t = f2bf(o0); uh.x = t; ul.x = f2bf(o0 - bf2f(t));
    t = f2bf(o1); uh.y = t; ul.y = f2bf(o1 - bf2f(t));
    t = f2bf(o2); uh.z = t; ul.z = f2bf(o2 - bf2f(t));
    t = f2bf(o3); uh.w = t; ul.w = f2bf(o3 - bf2f(t));
    *reinterpret_cast<ushort4*>(hh + (size_t)n * CN + lane * 4) = uh;
    *reinterpret_cast<ushort4*>(hl + (size_t)n * CN + lane * 4) = ul;
}

// ---------------------------------------------------------------------------
// gate[n] = relu(gtmp[n]) . gW2 + gb2
// ---------------------------------------------------------------------------
__global__ __launch_bounds__(256) void gate2_kernel(const float* __restrict__ gtmp,
                                                    const float* __restrict__ gW2,
                                                    const float* __restrict__ gb2,
                                                    float* __restrict__ gate, int N) {
    int n = blockIdx.x * 4 + (threadIdx.x >> 6);
    if (n >= N) return;
    int lane = threadIdx.x & 63;
    float2 t = *reinterpret_cast<const float2*>(gtmp + (size_t)n * GATE_DIM + lane * 2);
    float2 w = *reinterpret_cast<const float2*>(gW2 + lane * 2);
    float c = fmaxf(t.x, 0.f) * w.x + fmaxf(t.y, 0.f) * w.y;
    #pragma unroll
    for (int o = 32; o; o >>= 1) c += __shfl_xor(c, o);
    if (lane == 0) gate[n] = c + gb2[0];
}

// ---------------------------------------------------------------------------
// Pool: segment softmax over contiguous 88-node graphs + weighted sum -> emb
// ---------------------------------------------------------------------------
__global__ __launch_bounds__(256) void pool_kernel(const float* __restrict__ gate,
                                                   const float* __restrict__ h,
                                                   float* __restrict__ emb) {
    __shared__ float a[KPG];
    __shared__ float wm[4];
    int g = blockIdx.x, tid = threadIdx.x;
    int wid = tid >> 6, lane = tid & 63;
    float gv = (tid < KPG) ? gate[g * KPG + tid] : -INFINITY;
    float m = gv;
    #pragma unroll
    for (int o = 32; o; o >>= 1) m = fmaxf(m, __shfl_xor(m, o));
    if (lane == 0) wm[wid] = m;
    __syncthreads();
    m = fmaxf(fmaxf(wm[0], wm[1]), fmaxf(wm[2], wm[3]));
    __syncthreads();
    float av = (tid < KPG) ? expf(gv - m) : 0.f;
    if (tid < KPG) a[tid] = av;
    float s = av;
    #pragma unroll
    for (int o = 32; o; o >>= 1) s += __shfl_xor(s, o);
    if (lane == 0) wm[wid] = s;
    __syncthreads();
    s = wm[0] + wm[1] + wm[2] + wm[3];
    float inv = 1.f / s;
    float acc = 0.f;
    const float* hg = h + (size_t)g * KPG * CN;
    for (int i = 0; i < KPG; ++i) acc += a[i] * hg[i * CN + tid];
    emb[(size_t)g * CN + tid] = acc * inv;
}

// ---------------------------------------------------------------------------
// Heads: t1 = relu(LN(emb@pW1+pb1)) (bf16 split out); value head full
// ---------------------------------------------------------------------------
__global__ __launch_bounds__(256) void head_kernel(const float* __restrict__ emb,
    const float* __restrict__ pW1, const float* __restrict__ pb1,
    const float* __restrict__ plng, const float* __restrict__ plnb,
    const float* __restrict__ vW1, const float* __restrict__ vb1,
    const float* __restrict__ vW2, const float* __restrict__ vb2,
    unsigned short* __restrict__ t1h, unsigned short* __restrict__ t1l,
    float* __restrict__ value_out) {
    __shared__ float e_l[CN];
    __shared__ float rsum[4], rsq[4];
    int g = blockIdx.x, tid = threadIdx.x;
    int wid = tid >> 6, lane = tid & 63;
    e_l[tid] = emb[(size_t)g * CN + tid];
    __syncthreads();
    float p = pb1[tid], v = vb1[tid];
    for (int k = 0; k < CN; ++k) {
        float e = e_l[k];
        p += e * pW1[k * CN + tid];
        v += e * vW1[k * CN + tid];
    }
    float sum = p, sq = p * p;
    #pragma unroll
    for (int o = 32; o; o >>= 1) { sum += __shfl_xor(sum, o); sq += __shfl_xor(sq, o); }
    if (lane == 0) { rsum[wid] = sum; rsq[wid] = sq; }
    __syncthreads();
    sum = rsum[0] + rsum[1] + rsum[2] + rsum[3];
    sq  = rsq[0] + rsq[1] + rsq[2] + rsq[3];
    float mu = sum / CN;
    float var = sq / CN - mu * mu;
    float inv = rsqrtf(var + 1e-5f);
    float t1v = fmaxf((p - mu) * inv * plng[tid] + plnb[tid], 0.f);
    unsigned short th = f2bf(t1v);
    t1h[(size_t)g * CN + tid] = th;
    t1l[(size_t)g * CN + tid] = f2bf(t1v - bf2f(th));
    float contrib = fmaxf(v, 0.f) * vW2[tid];
    __syncthreads();
    #pragma unroll
    for (int o = 32; o; o >>= 1) contrib += __shfl_xor(contrib, o);
    if (lane == 0) rsum[wid] = contrib;
    __syncthreads();
    if (tid == 0)
        value_out[g] = tanhf(rsum[0] + rsum[1] + rsum[2] + rsum[3] + vb2[0]);
}

// ---------------------------------------------------------------------------
extern "C" void kernel_launch(void* const* d_in, const int* in_sizes, int n_in,
                              void* d_out, int out_size, void* d_ws, size_t ws_size,
                              hipStream_t stream) {
    const float* x        = (const float*)d_in[0];
    const int*   ei       = (const int*)d_in[1];
    const float* W_emb    = (const float*)d_in[4];
    const float* b_emb    = (const float*)d_in[5];
    const float* pos_emb  = (const float*)d_in[6];
    const float* gat_Wsrc = (const float*)d_in[7];
    const float* gat_Wdst = (const float*)d_in[8];
    const float* gat_att  = (const float*)d_in[9];
    const float* gat_bias = (const float*)d_in[10];
    const float* ln_g     = (const float*)d_in[11];
    const float* ln_b     = (const float*)d_in[12];
    const float* gW1      = (const float*)d_in[13];
    const float* gb1      = (const float*)d_in[14];
    const float* gW2      = (const float*)d_in[15];
    const float* gb2      = (const float*)d_in[16];
    const float* pW1      = (const float*)d_in[17];
    const float* pb1      = (const float*)d_in[18];
    const float* p_ln_g   = (const float*)d_in[19];
    const float* p_ln_b   = (const float*)d_in[20];
    const float* pW2      = (const float*)d_in[21];
    const float* pb2      = (const float*)d_in[22];
    const float* vW1      = (const float*)d_in[23];
    const float* vb1      = (const float*)d_in[24];
    const float* vW2      = (const float*)d_in[25];
    const float* vb2      = (const float*)d_in[26];

    const int N = in_sizes[2];      // 22528
    const int E = in_sizes[1] / 2;  // 405504
    const int G = N / KPG;          // 256
    const int NB_SC = (N + 1023) / 1024;

    const int NB_CAT = 32;                        // 512/16
    const int NB_G1  = 8;                         // 128/16
    const int GY_POL = (ACT_DIM + 127) / 128;     // 37
    const int NB_POL = GY_POL * 8;                // 296 (padded)

    char* ws = (char*)d_ws;
    size_t off = 0;
    auto alloc = [&](size_t nbytes) {
        void* pp = ws + off;
        off = (off + nbytes + 255) & ~(size_t)255;
        return pp;
    };
    float* h      = (float*)alloc((size_t)N * CN * 4);
    unsigned short* hh = (unsigned short*)alloc((size_t)N * CN * 2);
    unsigned short* hl = (unsigned short*)alloc((size_t)N * CN * 2);
    float* xlr    = (float*)alloc((size_t)N * 512 * 4);       // reused as gtmp
    unsigned short* WcatH = (unsigned short*)alloc((size_t)4 * 8 * NB_CAT * 512 * 2);
    unsigned short* WcatL = (unsigned short*)alloc((size_t)4 * 8 * NB_CAT * 512 * 2);
    unsigned short* gW1H  = (unsigned short*)alloc((size_t)8 * NB_G1 * 512 * 2);
    unsigned short* gW1L  = (unsigned short*)alloc((size_t)8 * NB_G1 * 512 * 2);
    unsigned short* pW2H  = (unsigned short*)alloc((size_t)8 * NB_POL * 512 * 2);
    unsigned short* pW2L  = (unsigned short*)alloc((size_t)8 * NB_POL * 512 * 2);
    float* gate   = (float*)alloc((size_t)N * 4);
    float* emb    = (float*)alloc((size_t)G * CN * 4);
    unsigned short* t1h = (unsigned short*)alloc((size_t)G * CN * 2);
    unsigned short* t1l = (unsigned short*)alloc((size_t)G * CN * 2);
    int*   rowptr = (int*)alloc((size_t)(N + 1) * 4);
    int*   cnt    = (int*)alloc((size_t)N * 4);
    int*   cursor = (int*)alloc((size_t)N * 4);
    int*   btot   = (int*)alloc((size_t)64 * 4);
    int*   csrc   = (int*)alloc((size_t)E * 4);
    float* gtmp   = xlr;

    const int* e_src = ei;
    const int* e_dst = ei + E;

    hipMemsetAsync(cnt, 0, (size_t)N * 4, stream);
    hipMemsetAsync(cursor, 0, (size_t)N * 4, stream);
    count_kernel<<<(E + 255) / 256, 256, 0, stream>>>(e_dst, cnt, E);
    scan1_kernel<<<NB_SC, 1024, 0, stream>>>(cnt, rowptr, btot, N);
    scan2_kernel<<<1, 64, 0, stream>>>(btot, NB_SC);
    scan3_kernel<<<(N + 1024) / 1024, 1024, 0, stream>>>(rowptr, btot, N, NB_SC);
    fill_kernel<<<(E + 255) / 256, 256, 0, stream>>>(e_src, e_dst, rowptr, cursor, csrc, E);

    embed_kernel<<<N / 16, 256, 0, stream>>>(x, W_emb, b_emb, pos_emb, h, hh, hl);

    {
        int totc = 8 * NB_CAT * 512;
        for (int l = 0; l < 4; ++l)
            wconv_cat_kernel<<<(totc + 255) / 256, 256, 0, stream>>>(
                gat_Wsrc + (size_t)l * 256 * 256, gat_Wdst + (size_t)l * 256 * 256,
                WcatH + (size_t)l * totc, WcatL + (size_t)l * totc, NB_CAT, totc);
        int totg = 8 * NB_G1 * 512;
        wconv_kernel<<<(totg + 255) / 256, 256, 0, stream>>>(gW1, gW1H, gW1L, GATE_DIM, NB_G1, totg);
        int totp = 8 * NB_POL * 512;
        wconv_kernel<<<(totp + 255) / 256, 256, 0, stream>>>(pW2, pW2H, pW2L, ACT_DIM, NB_POL, totp);
    }

    for (int l = 0; l < 4; ++l) {
        size_t wo = (size_t)l * 8 * NB_CAT * 512;
        dim3 g1(N / 128, 512 / 128);
        mgemm<false><<<g1, 256, 0, stream>>>(hh, hl, WcatH + wo, WcatL + wo, nullptr,
                                             xlr, N, 512, NB_CAT, CN);
        gat_agg<<<N / 8, 512, 0, stream>>>(xlr, rowptr, csrc, gat_att + l * CN,
                                           gat_bias + l * CN, ln_g + l * CN, ln_b + l * CN,
                                           h, hh, hl);
    }

    // gate MLP
    {
        dim3 g1(N / 128, 1);
        mgemm<true><<<g1, 256, 0, stream>>>(hh, hl, gW1H, gW1L, gb1, gtmp, N, GATE_DIM, NB_G1, CN);
        gate2_kernel<<<(N + 3) / 4, 256, 0, stream>>>(gtmp, gW2, gb2, gate, N);
    }
    pool_kernel<<<G, 256, 0, stream>>>(gate, h, emb);

    float* policy = (float*)d_out;
    float* value  = (float*)d_out + (size_t)G * ACT_DIM;
    head_kernel<<<G, 256, 0, stream>>>(emb, pW1, pb1, p_ln_g, p_ln_b,
                                       vW1, vb1, vW2, vb2, t1h, t1l, value);
    dim3 g2(G / 128, GY_POL);
    mgemm<true><<<g2, 256, 0, stream>>>(t1h, t1l, pW2H, pW2L, pb2, policy, G, ACT_DIM, NB_POL, CN);
}

// Round 6
// 399.390 us; speedup vs baseline: 3.1719x; 1.0974x over previous
//
#include <hip/hip_runtime.h>
#include <math.h>

constexpr int CN = 256;        // channels
constexpr int NHEAD = 8;       // attention heads
constexpr int KPG = 88;        // nodes per graph
constexpr int NIDF = 16;       // input node features
constexpr int GATE_DIM = 128;
constexpr int ACT_DIM = 4644;

typedef __attribute__((ext_vector_type(8))) short bf16x8;
typedef __attribute__((ext_vector_type(4))) float f32x4;

__device__ __forceinline__ unsigned short f2bf(float f) {
    unsigned int u = __float_as_uint(f);
    unsigned int r = (u + 0x7fffu + ((u >> 16) & 1u)) >> 16;
    return (unsigned short)r;
}
__device__ __forceinline__ float bf2f(unsigned short h) {
    return __uint_as_float(((unsigned int)h) << 16);
}

__device__ __forceinline__ void glds16(const void* g, void* l) {
    __builtin_amdgcn_global_load_lds(
        (const __attribute__((address_space(1))) unsigned int*)g,
        (__attribute__((address_space(3))) unsigned int*)l, 16, 0, 0);
}

// 8-lane group sum via DPP (VALU-speed, no LDS pipe)
__device__ __forceinline__ float grp8_sum(float p) {
    int t;
    t = __builtin_amdgcn_mov_dpp(__float_as_int(p), 0xB1, 0xF, 0xF, true);
    p += __int_as_float(t);
    t = __builtin_amdgcn_mov_dpp(__float_as_int(p), 0x4E, 0xF, 0xF, true);
    p += __int_as_float(t);
    t = __builtin_amdgcn_mov_dpp(__float_as_int(p), 0x141, 0xF, 0xF, true);
    p += __int_as_float(t);
    return p;
}

// ---------------------------------------------------------------------------
// CSR build: count -> hierarchical scan -> fill (csrcB = byte offsets)
// ---------------------------------------------------------------------------
__global__ void count_kernel(const int* __restrict__ dst, int* __restrict__ cnt, int E) {
    int e = blockIdx.x * 256 + threadIdx.x;
    if (e < E) atomicAdd(&cnt[dst[e]], 1);
}

__global__ __launch_bounds__(1024) void scan1_kernel(const int* __restrict__ cnt,
                                                     int* __restrict__ rowptr,
                                                     int* __restrict__ btot, int n) {
    __shared__ int buf[1024];
    int tid = threadIdx.x;
    int i = blockIdx.x * 1024 + tid;
    int v = (i < n) ? cnt[i] : 0;
    buf[tid] = v;
    __syncthreads();
    for (int off = 1; off < 1024; off <<= 1) {
        int t = (tid >= off) ? buf[tid - off] : 0;
        __syncthreads();
        buf[tid] += t;
        __syncthreads();
    }
    if (i < n) rowptr[i] = buf[tid] - v;
    if (tid == 1023) btot[blockIdx.x] = buf[1023];
}

__global__ void scan2_kernel(int* __restrict__ btot, int nb) {
    if (threadIdx.x == 0 && blockIdx.x == 0) {
        int s = 0;
        for (int b = 0; b < nb; ++b) { int t = btot[b]; btot[b] = s; s += t; }
        btot[nb] = s;
    }
}

__global__ __launch_bounds__(1024) void scan3_kernel(int* __restrict__ rowptr,
                                                     const int* __restrict__ btot,
                                                     int n, int nb) {
    int i = blockIdx.x * 1024 + threadIdx.x;
    if (i < n) rowptr[i] += btot[i >> 10];
    else if (i == n) rowptr[n] = btot[nb];
}

__global__ void fill_kernel(const int* __restrict__ src, const int* __restrict__ dst,
                            const int* __restrict__ rowptr, int* __restrict__ cursor,
                            int* __restrict__ csrcB, int E) {
    int e = blockIdx.x * 256 + threadIdx.x;
    if (e < E) {
        int d = dst[e];
        int p = atomicAdd(&cursor[d], 1);
        csrcB[rowptr[d] + p] = src[e] * 2048;   // byte offset into xlr (512 f32/row)
    }
}

// ---------------------------------------------------------------------------
// Embedding: h = relu(x @ W_emb + b_emb) + pos_emb[n % 88]; also bf16 hi/lo
// ---------------------------------------------------------------------------
__global__ __launch_bounds__(256) void embed_kernel(const float* __restrict__ x,
                                                    const float* __restrict__ Wemb,
                                                    const float* __restrict__ bemb,
                                                    const float* __restrict__ pos,
                                                    float* __restrict__ h,
                                                    unsigned short* __restrict__ hh,
                                                    unsigned short* __restrict__ hl) {
    __shared__ float Wl[NIDF][CN];
    int tid = threadIdx.x;
    for (int i = tid; i < NIDF * CN; i += 256) Wl[i >> 8][i & 255] = Wemb[i];
    __syncthreads();
    float bias = bemb[tid];
    int node0 = blockIdx.x * 16;
    for (int q = 0; q < 16; ++q) {
        int n = node0 + q;
        float acc = bias;
        #pragma unroll
        for (int k = 0; k < NIDF; ++k) acc += x[n * NIDF + k] * Wl[k][tid];
        float val = fmaxf(acc, 0.f) + pos[(n % KPG) * CN + tid];
        h[(size_t)n * CN + tid] = val;
        unsigned short vh = f2bf(val);
        hh[(size_t)n * CN + tid] = vh;
        hl[(size_t)n * CN + tid] = f2bf(val - bf2f(vh));
    }
}

// ---------------------------------------------------------------------------
// Weight decompose + fragment-order relayout (concat Ws|Wd), all 4 layers
// ---------------------------------------------------------------------------
__global__ void wconv_cat_kernel(const float* __restrict__ Ws, const float* __restrict__ Wd,
                                 unsigned short* __restrict__ Bh,
                                 unsigned short* __restrict__ Bl, int NB, int tot) {
    int o = blockIdx.x * 256 + threadIdx.x;
    if (o >= tot) return;
    int l4 = blockIdx.y;
    const float* ws = Ws + (size_t)l4 * 256 * 256;
    const float* wd = Wd + (size_t)l4 * 256 * 256;
    int idx = o & 511;
    int nb = (o >> 9) % NB;
    int kb = o / (512 * NB);
    int l = idx >> 3, j = idx & 7;
    int k = kb * 32 + (l >> 4) * 8 + j;
    int c = nb * 16 + (l & 15);
    float v = (c < 256) ? ws[(size_t)k * 256 + c] : wd[(size_t)k * 256 + (c - 256)];
    unsigned short hh = f2bf(v);
    Bh[(size_t)l4 * tot + o] = hh;
    Bl[(size_t)l4 * tot + o] = f2bf(v - bf2f(hh));
}

__global__ void wconv_kernel(const float* __restrict__ W, unsigned short* __restrict__ Bh,
                             unsigned short* __restrict__ Bl, int Nn, int NB, int tot) {
    int o = blockIdx.x * 256 + threadIdx.x;
    if (o >= tot) return;
    int idx = o & 511;
    int nb = (o >> 9) % NB;
    int kb = o / (512 * NB);
    int l = idx >> 3, j = idx & 7;
    int k = kb * 32 + (l >> 4) * 8 + j;
    int c = nb * 16 + (l & 15);
    float v = (c < Nn) ? W[(size_t)k * Nn + c] : 0.f;
    unsigned short hh = f2bf(v);
    Bh[o] = hh;
    Bl[o] = f2bf(v - bf2f(hh));
}

// ---------------------------------------------------------------------------
// MFMA GEMM, bf16 split 3-product: C = A[M,K] @ B[K,N] (+bias)
// ---------------------------------------------------------------------------
template <bool BIAS>
__global__ __launch_bounds__(256) void mgemm(const unsigned short* __restrict__ Ah,
                                             const unsigned short* __restrict__ Al,
                                             const unsigned short* __restrict__ Bh,
                                             const unsigned short* __restrict__ Bl,
                                             const float* __restrict__ bias,
                                             float* __restrict__ C,
                                             int M, int Nlog, int NB, int K) {
    __shared__ unsigned short AhL[8 * 64 * 8];
    __shared__ unsigned short AlL[8 * 64 * 8];
    __shared__ unsigned short BhL[8 * 64 * 8];
    __shared__ unsigned short BlL[8 * 64 * 8];
    int tid = threadIdx.x;
    int wid = tid >> 6, lane = tid & 63;
    int row0 = blockIdx.x * 128;
    int cb = blockIdx.y;
    int wr = wid >> 1, wc = wid & 1;

    int rr = lane & 15, kq = lane >> 4;

    f32x4 acc[4][4] = {};

    for (int k0 = 0; k0 < K; k0 += 32) {
        int kb = k0 >> 5;
        {
            int mb0 = wid * 2;
            const unsigned short* s0 = Ah + (size_t)(row0 + mb0 * 16 + rr) * K + k0 + kq * 8;
            const unsigned short* s1 = Ah + (size_t)(row0 + mb0 * 16 + 16 + rr) * K + k0 + kq * 8;
            glds16(s0, &AhL[mb0 * 512]);
            glds16(s1, &AhL[mb0 * 512 + 512]);
            const unsigned short* t0 = Al + (size_t)(row0 + mb0 * 16 + rr) * K + k0 + kq * 8;
            const unsigned short* t1 = Al + (size_t)(row0 + mb0 * 16 + 16 + rr) * K + k0 + kq * 8;
            glds16(t0, &AlL[mb0 * 512]);
            glds16(t1, &AlL[mb0 * 512 + 512]);
        }
        {
            size_t base = ((size_t)kb * NB + (size_t)cb * 8) * 512;
            for (int ch = wid; ch < 8; ch += 4) {
                glds16(Bh + base + ch * 512 + lane * 8, &BhL[ch * 512]);
                glds16(Bl + base + ch * 512 + lane * 8, &BlL[ch * 512]);
            }
        }
        __syncthreads();
        bf16x8 a_h[4], a_l[4], b_h[4], b_l[4];
        #pragma unroll
        for (int mf = 0; mf < 4; ++mf) {
            int off = ((wr * 4 + mf) * 64 + lane) * 8;
            a_h[mf] = *reinterpret_cast<const bf16x8*>(&AhL[off]);
            a_l[mf] = *reinterpret_cast<const bf16x8*>(&AlL[off]);
        }
        #pragma unroll
        for (int nf = 0; nf < 4; ++nf) {
            int off = ((wc * 4 + nf) * 64 + lane) * 8;
            b_h[nf] = *reinterpret_cast<const bf16x8*>(&BhL[off]);
            b_l[nf] = *reinterpret_cast<const bf16x8*>(&BlL[off]);
        }
        #pragma unroll
        for (int mf = 0; mf < 4; ++mf)
            #pragma unroll
            for (int nf = 0; nf < 4; ++nf) {
                acc[mf][nf] = __builtin_amdgcn_mfma_f32_16x16x32_bf16(a_h[mf], b_h[nf], acc[mf][nf], 0, 0, 0);
                acc[mf][nf] = __builtin_amdgcn_mfma_f32_16x16x32_bf16(a_h[mf], b_l[nf], acc[mf][nf], 0, 0, 0);
                acc[mf][nf] = __builtin_amdgcn_mfma_f32_16x16x32_bf16(a_l[mf], b_h[nf], acc[mf][nf], 0, 0, 0);
            }
        __syncthreads();
    }
    #pragma unroll
    for (int mf = 0; mf < 4; ++mf) {
        #pragma unroll
        for (int nf = 0; nf < 4; ++nf) {
            int col = cb * 128 + wc * 64 + nf * 16 + (lane & 15);
            if (col < Nlog) {
                float bv = BIAS ? bias[col] : 0.f;
                #pragma unroll
                for (int rg = 0; rg < 4; ++rg) {
                    int row = row0 + wr * 64 + mf * 16 + (lane >> 4) * 4 + rg;
                    C[(size_t)row * Nlog + col] = acc[mf][nf][rg] + bv;
                }
            }
        }
    }
}

// ---------------------------------------------------------------------------
// GAT aggregate v5: one wave per node, 4 nodes/block, no LDS/barriers.
// NO-MAX softmax: exp(min(p,60)) directly (shift-invariance; scores from
// LayerNormed features are small; clamp = overflow insurance).
// leaky(z) = max(z, 0.2z). Unroll-2 edges, 2-ahead pipeline, DPP reduce.
// ---------------------------------------------------------------------------
__global__ __launch_bounds__(256) void gat_agg(const float* __restrict__ xlr,
                                               const int* __restrict__ rowptr,
                                               const int* __restrict__ csrcB,
                                               const float* __restrict__ att,
                                               const float* __restrict__ bias,
                                               const float* __restrict__ lng,
                                               const float* __restrict__ lnb,
                                               float* __restrict__ h,
                                               unsigned short* __restrict__ hh,
                                               unsigned short* __restrict__ hl) {
    int cpx = gridDim.x >> 3;
    int swz = (blockIdx.x & 7) * cpx + (blockIdx.x >> 3);
    int wid = threadIdx.x >> 6, lane = threadIdx.x & 63;
    int n = swz * 4 + wid;

    const char* xbase = (const char*)xlr + lane * 16;
    float4 xr4 = *reinterpret_cast<const float4*>(xlr + (size_t)n * 512 + 256 + lane * 4);
    float4 at4 = *reinterpret_cast<const float4*>(att + lane * 4);
    float4 hr4 = *reinterpret_cast<const float4*>(h + (size_t)n * CN + lane * 4);

    int e0 = rowptr[n], e1 = rowptr[n + 1];
    float s_r = 0.f;
    float a0 = 0.f, a1 = 0.f, a2 = 0.f, a3 = 0.f;

    float4 A4 = *reinterpret_cast<const float4*>(xbase + csrcB[e0]);
    float4 B4 = make_float4(0.f, 0.f, 0.f, 0.f);
    if (e0 + 1 < e1)
        B4 = *reinterpret_cast<const float4*>(xbase + csrcB[e0 + 1]);

    for (int e = e0; e < e1; e += 2) {
        bool two = (e + 1 < e1);
        float4 xa = A4, xb = B4;
        if (e + 2 < e1)
            A4 = *reinterpret_cast<const float4*>(xbase + csrcB[e + 2]);
        if (e + 3 < e1)
            B4 = *reinterpret_cast<const float4*>(xbase + csrcB[e + 3]);

        float z, pa = 0.f, pb = 0.f;
        z = xa.x + xr4.x; z = fmaxf(z, 0.2f * z); pa += z * at4.x;
        z = xa.y + xr4.y; z = fmaxf(z, 0.2f * z); pa += z * at4.y;
        z = xa.z + xr4.z; z = fmaxf(z, 0.2f * z); pa += z * at4.z;
        z = xa.w + xr4.w; z = fmaxf(z, 0.2f * z); pa += z * at4.w;
        z = xb.x + xr4.x; z = fmaxf(z, 0.2f * z); pb += z * at4.x;
        z = xb.y + xr4.y; z = fmaxf(z, 0.2f * z); pb += z * at4.y;
        z = xb.z + xr4.z; z = fmaxf(z, 0.2f * z); pb += z * at4.z;
        z = xb.w + xr4.w; z = fmaxf(z, 0.2f * z); pb += z * at4.w;
        pa = grp8_sum(pa);
        pb = grp8_sum(pb);
        pa = fminf(pa, 60.f);
        pb = two ? fminf(pb, 60.f) : -INFINITY;

        float wa = expf(pa);
        float wb = expf(pb);            // exp(-inf) = 0 handles odd tail
        s_r += wa + wb;
        a0 += wa * xa.x + wb * xb.x;
        a1 += wa * xa.y + wb * xb.y;
        a2 += wa * xa.z + wb * xb.z;
        a3 += wa * xa.w + wb * xb.w;
    }

    float inv = 1.f / s_r;
    float4 bi4 = *reinterpret_cast<const float4*>(bias + lane * 4);
    float v0 = hr4.x + fmaxf(a0 * inv + bi4.x, 0.f);
    float v1 = hr4.y + fmaxf(a1 * inv + bi4.y, 0.f);
    float v2 = hr4.z + fmaxf(a2 * inv + bi4.z, 0.f);
    float v3 = hr4.w + fmaxf(a3 * inv + bi4.w, 0.f);

    float sum = v0 + v1 + v2 + v3;
    float sq = v0 * v0 + v1 * v1 + v2 * v2 + v3 * v3;
    #pragma unroll
    for (int o = 32; o; o >>= 1) { sum += __shfl_xor(sum, o); sq += __shfl_xor(sq, o); }
    float mu = sum / CN;
    float var = sq / CN - mu * mu;
    float ninv = rsqrtf(var + 1e-5f);
    float4 lg4 = *reinterpret_cast<const float4*>(lng + lane * 4);
    float4 lb4 = *reinterpret_cast<const float4*>(lnb + lane * 4);
    float o0 = (v0 - mu) * ninv * lg4.x + lb4.x;
    float o1 = (v1 - mu) * ninv * lg4.y + lb4.y;
    float o2 = (v2 - mu) * ninv * lg4.z + lb4.z;
    float o3 = (v3 - mu) * ninv * lg4.w + lb4.w;
    *reinterpret_cast<float4*>(h + (size_t)n * CN + lane * 4) = make_float4(o0, o1, o2, o3);

    ushort4 uh, ul;
    unsigned short t;
    t = f2bf(o0); uh.x = t; ul.x = f2bf(o0 - bf2f(t));
    t = f2bf(o1); uh.y = t; ul.y = f2bf(o1 - bf2f(t));
    t = f2bf(o2); uh.z = t; ul.z = f2bf(o2 - bf2f(t));
    t = f2bf(o3); uh.w = t; ul.w = f2bf(o3 - bf2f(t));
    *reinterpret_cast<ushort4*>(hh + (size_t)n * CN + lane * 4) = uh;
    *reinterpret_cast<ushort4*>(hl + (size_t)n * CN + lane * 4) = ul;
}

// ---------------------------------------------------------------------------
// gate[n] = relu(gtmp[n]) . gW2 + gb2
// ---------------------------------------------------------------------------
__global__ __launch_bounds__(256) void gate2_kernel(const float* __restrict__ gtmp,
                                                    const float* __restrict__ gW2,
                                                    const float* __restrict__ gb2,
                                                    float* __restrict__ gate, int N) {
    int n = blockIdx.x * 4 + (threadIdx.x >> 6);
    if (n >= N) return;
    int lane = threadIdx.x & 63;
    float2 t = *reinterpret_cast<const float2*>(gtmp + (size_t)n * GATE_DIM + lane * 2);
    float2 w = *reinterpret_cast<const float2*>(gW2 + lane * 2);
    float c = fmaxf(t.x, 0.f) * w.x + fmaxf(t.y, 0.f) * w.y;
    #pragma unroll
    for (int o = 32; o; o >>= 1) c += __shfl_xor(c, o);
    if (lane == 0) gate[n] = c + gb2[0];
}

// ---------------------------------------------------------------------------
// Pool: segment softmax over contiguous 88-node graphs + weighted sum -> emb
// ---------------------------------------------------------------------------
__global__ __launch_bounds__(256) void pool_kernel(const float* __restrict__ gate,
                                                   const float* __restrict__ h,
                                                   float* __restrict__ emb) {
    __shared__ float a[KPG];
    __shared__ float wm[4];
    int g = blockIdx.x, tid = threadIdx.x;
    int wid = tid >> 6, lane = tid & 63;
    float gv = (tid < KPG) ? gate[g * KPG + tid] : -INFINITY;
    float m = gv;
    #pragma unroll
    for (int o = 32; o; o >>= 1) m = fmaxf(m, __shfl_xor(m, o));
    if (lane == 0) wm[wid] = m;
    __syncthreads();
    m = fmaxf(fmaxf(wm[0], wm[1]), fmaxf(wm[2], wm[3]));
    __syncthreads();
    float av = (tid < KPG) ? expf(gv - m) : 0.f;
    if (tid < KPG) a[tid] = av;
    float s = av;
    #pragma unroll
    for (int o = 32; o; o >>= 1) s += __shfl_xor(s, o);
    if (lane == 0) wm[wid] = s;
    __syncthreads();
    s = wm[0] + wm[1] + wm[2] + wm[3];
    float inv = 1.f / s;
    float acc = 0.f;
    const float* hg = h + (size_t)g * KPG * CN;
    for (int i = 0; i < KPG; ++i) acc += a[i] * hg[i * CN + tid];
    emb[(size_t)g * CN + tid] = acc * inv;
}

// ---------------------------------------------------------------------------
// Heads: t1 = relu(LN(emb@pW1+pb1)) (bf16 split out); value head full
// ---------------------------------------------------------------------------
__global__ __launch_bounds__(256) void head_kernel(const float* __restrict__ emb,
    const float* __restrict__ pW1, const float* __restrict__ pb1,
    const float* __restrict__ plng, const float* __restrict__ plnb,
    const float* __restrict__ vW1, const float* __restrict__ vb1,
    const float* __restrict__ vW2, const float* __restrict__ vb2,
    unsigned short* __restrict__ t1h, unsigned short* __restrict__ t1l,
    float* __restrict__ value_out) {
    __shared__ float e_l[CN];
    __shared__ float rsum[4], rsq[4];
    int g = blockIdx.x, tid = threadIdx.x;
    int wid = tid >> 6, lane = tid & 63;
    e_l[tid] = emb[(size_t)g * CN + tid];
    __syncthreads();
    float p = pb1[tid], v = vb1[tid];
    for (int k = 0; k < CN; ++k) {
        float e = e_l[k];
        p += e * pW1[k * CN + tid];
        v += e * vW1[k * CN + tid];
    }
    float sum = p, sq = p * p;
    #pragma unroll
    for (int o = 32; o; o >>= 1) { sum += __shfl_xor(sum, o); sq += __shfl_xor(sq, o); }
    if (lane == 0) { rsum[wid] = sum; rsq[wid] = sq; }
    __syncthreads();
    sum = rsum[0] + rsum[1] + rsum[2] + rsum[3];
    sq  = rsq[0] + rsq[1] + rsq[2] + rsq[3];
    float mu = sum / CN;
    float var = sq / CN - mu * mu;
    float inv = rsqrtf(var + 1e-5f);
    float t1v = fmaxf((p - mu) * inv * plng[tid] + plnb[tid], 0.f);
    unsigned short th = f2bf(t1v);
    t1h[(size_t)g * CN + tid] = th;
    t1l[(size_t)g * CN + tid] = f2bf(t1v - bf2f(th));
    float contrib = fmaxf(v, 0.f) * vW2[tid];
    __syncthreads();
    #pragma unroll
    for (int o = 32; o; o >>= 1) contrib += __shfl_xor(contrib, o);
    if (lane == 0) rsum[wid] = contrib;
    __syncthreads();
    if (tid == 0)
        value_out[g] = tanhf(rsum[0] + rsum[1] + rsum[2] + rsum[3] + vb2[0]);
}

// ---------------------------------------------------------------------------
extern "C" void kernel_launch(void* const* d_in, const int* in_sizes, int n_in,
                              void* d_out, int out_size, void* d_ws, size_t ws_size,
                              hipStream_t stream) {
    const float* x        = (const float*)d_in[0];
    const int*   ei       = (const int*)d_in[1];
    const float* W_emb    = (const float*)d_in[4];
    const float* b_emb    = (const float*)d_in[5];
    const float* pos_emb  = (const float*)d_in[6];
    const float* gat_Wsrc = (const float*)d_in[7];
    const float* gat_Wdst = (const float*)d_in[8];
    const float* gat_att  = (const float*)d_in[9];
    const float* gat_bias = (const float*)d_in[10];
    const float* ln_g     = (const float*)d_in[11];
    const float* ln_b     = (const float*)d_in[12];
    const float* gW1      = (const float*)d_in[13];
    const float* gb1      = (const float*)d_in[14];
    const float* gW2      = (const float*)d_in[15];
    const float* gb2      = (const float*)d_in[16];
    const float* pW1      = (const float*)d_in[17];
    const float* pb1      = (const float*)d_in[18];
    const float* p_ln_g   = (const float*)d_in[19];
    const float* p_ln_b   = (const float*)d_in[20];
    const float* pW2      = (const float*)d_in[21];
    const float* pb2      = (const float*)d_in[22];
    const float* vW1      = (const float*)d_in[23];
    const float* vb1      = (const float*)d_in[24];
    const float* vW2      = (const float*)d_in[25];
    const float* vb2      = (const float*)d_in[26];

    const int N = in_sizes[2];      // 22528
    const int E = in_sizes[1] / 2;  // 405504
    const int G = N / KPG;          // 256
    const int NB_SC = (N + 1023) / 1024;

    const int NB_CAT = 32;                        // 512/16
    const int NB_G1  = 8;                         // 128/16
    const int GY_POL = (ACT_DIM + 127) / 128;     // 37
    const int NB_POL = GY_POL * 8;                // 296 (padded)

    char* ws = (char*)d_ws;
    size_t off = 0;
    auto alloc = [&](size_t nbytes) {
        void* pp = ws + off;
        off = (off + nbytes + 255) & ~(size_t)255;
        return pp;
    };
    float* h      = (float*)alloc((size_t)N * CN * 4);
    unsigned short* hh = (unsigned short*)alloc((size_t)N * CN * 2);
    unsigned short* hl = (unsigned short*)alloc((size_t)N * CN * 2);
    float* xlr    = (float*)alloc((size_t)N * 512 * 4);       // reused as gtmp
    unsigned short* WcatH = (unsigned short*)alloc((size_t)4 * 8 * NB_CAT * 512 * 2);
    unsigned short* WcatL = (unsigned short*)alloc((size_t)4 * 8 * NB_CAT * 512 * 2);
    unsigned short* gW1H  = (unsigned short*)alloc((size_t)8 * NB_G1 * 512 * 2);
    unsigned short* gW1L  = (unsigned short*)alloc((size_t)8 * NB_G1 * 512 * 2);
    unsigned short* pW2H  = (unsigned short*)alloc((size_t)8 * NB_POL * 512 * 2);
    unsigned short* pW2L  = (unsigned short*)alloc((size_t)8 * NB_POL * 512 * 2);
    float* gate   = (float*)alloc((size_t)N * 4);
    float* emb    = (float*)alloc((size_t)G * CN * 4);
    unsigned short* t1h = (unsigned short*)alloc((size_t)G * CN * 2);
    unsigned short* t1l = (unsigned short*)alloc((size_t)G * CN * 2);
    int*   rowptr = (int*)alloc((size_t)(N + 1) * 4);
    int*   cnt    = (int*)alloc((size_t)N * 4);
    int*   cursor = (int*)alloc((size_t)N * 4);
    int*   btot   = (int*)alloc((size_t)64 * 4);
    int*   csrcB  = (int*)alloc((size_t)E * 4);
    float* gtmp   = xlr;

    const int* e_src = ei;
    const int* e_dst = ei + E;

    hipMemsetAsync(cnt, 0, (size_t)N * 4, stream);
    hipMemsetAsync(cursor, 0, (size_t)N * 4, stream);
    count_kernel<<<(E + 255) / 256, 256, 0, stream>>>(e_dst, cnt, E);
    scan1_kernel<<<NB_SC, 1024, 0, stream>>>(cnt, rowptr, btot, N);
    scan2_kernel<<<1, 64, 0, stream>>>(btot, NB_SC);
    scan3_kernel<<<(N + 1024) / 1024, 1024, 0, stream>>>(rowptr, btot, N, NB_SC);
    fill_kernel<<<(E + 255) / 256, 256, 0, stream>>>(e_src, e_dst, rowptr, cursor, csrcB, E);

    embed_kernel<<<N / 16, 256, 0, stream>>>(x, W_emb, b_emb, pos_emb, h, hh, hl);

    {
        int totc = 8 * NB_CAT * 512;
        dim3 gw((totc + 255) / 256, 4);
        wconv_cat_kernel<<<gw, 256, 0, stream>>>(gat_Wsrc, gat_Wdst, WcatH, WcatL, NB_CAT, totc);
        int totg = 8 * NB_G1 * 512;
        wconv_kernel<<<(totg + 255) / 256, 256, 0, stream>>>(gW1, gW1H, gW1L, GATE_DIM, NB_G1, totg);
        int totp = 8 * NB_POL * 512;
        wconv_kernel<<<(totp + 255) / 256, 256, 0, stream>>>(pW2, pW2H, pW2L, ACT_DIM, NB_POL, totp);
    }

    for (int l = 0; l < 4; ++l) {
        size_t wo = (size_t)l * 8 * NB_CAT * 512;
        dim3 g1(N / 128, 512 / 128);
        mgemm<false><<<g1, 256, 0, stream>>>(hh, hl, WcatH + wo, WcatL + wo, nullptr,
                                             xlr, N, 512, NB_CAT, CN);
        gat_agg<<<N / 4, 256, 0, stream>>>(xlr, rowptr, csrcB, gat_att + l * CN,
                                           gat_bias + l * CN, ln_g + l * CN, ln_b + l * CN,
                                           h, hh, hl);
    }

    // gate MLP
    {
        dim3 g1(N / 128, 1);
        mgemm<true><<<g1, 256, 0, stream>>>(hh, hl, gW1H, gW1L, gb1, gtmp, N, GATE_DIM, NB_G1, CN);
        gate2_kernel<<<(N + 3) / 4, 256, 0, stream>>>(gtmp, gW2, gb2, gate, N);
    }
    pool_kernel<<<G, 256, 0, stream>>>(gate, h, emb);

    float* policy = (float*)d_out;
    float* value  = (float*)d_out + (size_t)G * ACT_DIM;
    head_kernel<<<G, 256, 0, stream>>>(emb, pW1, pb1, p_ln_g, p_ln_b,
                                       vW1, vb1, vW2, vb2, t1h, t1l, value);
    dim3 g2(G / 128, GY_POL);
    mgemm<true><<<g2, 256, 0, stream>>>(t1h, t1l, pW2H, pW2L, pb2, policy, G, ACT_DIM, NB_POL, CN);
}

// Round 7
// 382.392 us; speedup vs baseline: 3.3129x; 1.0445x over previous
//
#include <hip/hip_runtime.h>
#include <math.h>

constexpr int CN = 256;        // channels
constexpr int NHEAD = 8;       // attention heads
constexpr int KPG = 88;        // nodes per graph
constexpr int NIDF = 16;       // input node features
constexpr int GATE_DIM = 128;
constexpr int ACT_DIM = 4644;
constexpr float LOG2E = 1.4426950408889634f;

typedef __attribute__((ext_vector_type(8))) short bf16x8;
typedef __attribute__((ext_vector_type(4))) float f32x4;

__device__ __forceinline__ unsigned short f2bf(float f) {
    unsigned int u = __float_as_uint(f);
    unsigned int r = (u + 0x7fffu + ((u >> 16) & 1u)) >> 16;
    return (unsigned short)r;
}
__device__ __forceinline__ float bf2f(unsigned short h) {
    return __uint_as_float(((unsigned int)h) << 16);
}

__device__ __forceinline__ void glds16(const void* g, void* l) {
    __builtin_amdgcn_global_load_lds(
        (const __attribute__((address_space(1))) unsigned int*)g,
        (__attribute__((address_space(3))) unsigned int*)l, 16, 0, 0);
}

// raw v_exp_f32: w = 2^x  (inputs pre-scaled by log2e; clamped <= 80, -inf -> 0)
__device__ __forceinline__ float fexp2(float x) {
    float r;
    asm("v_exp_f32 %0, %1" : "=v"(r) : "v"(x));
    return r;
}

// 8-lane group sum via DPP (VALU-speed, no LDS pipe)
__device__ __forceinline__ float grp8_sum(float p) {
    int t;
    t = __builtin_amdgcn_mov_dpp(__float_as_int(p), 0xB1, 0xF, 0xF, true);
    p += __int_as_float(t);
    t = __builtin_amdgcn_mov_dpp(__float_as_int(p), 0x4E, 0xF, 0xF, true);
    p += __int_as_float(t);
    t = __builtin_amdgcn_mov_dpp(__float_as_int(p), 0x141, 0xF, 0xF, true);
    p += __int_as_float(t);
    return p;
}

// ---------------------------------------------------------------------------
// CSR build: count -> hierarchical scan -> fill (csrcB = byte offsets)
// ---------------------------------------------------------------------------
__global__ void count_kernel(const int* __restrict__ dst, int* __restrict__ cnt, int E) {
    int e = blockIdx.x * 256 + threadIdx.x;
    if (e < E) atomicAdd(&cnt[dst[e]], 1);
}

__global__ __launch_bounds__(1024) void scan1_kernel(const int* __restrict__ cnt,
                                                     int* __restrict__ rowptr,
                                                     int* __restrict__ btot, int n) {
    __shared__ int buf[1024];
    int tid = threadIdx.x;
    int i = blockIdx.x * 1024 + tid;
    int v = (i < n) ? cnt[i] : 0;
    buf[tid] = v;
    __syncthreads();
    for (int off = 1; off < 1024; off <<= 1) {
        int t = (tid >= off) ? buf[tid - off] : 0;
        __syncthreads();
        buf[tid] += t;
        __syncthreads();
    }
    if (i < n) rowptr[i] = buf[tid] - v;
    if (tid == 1023) btot[blockIdx.x] = buf[1023];
}

__global__ void scan2_kernel(int* __restrict__ btot, int nb) {
    if (threadIdx.x == 0 && blockIdx.x == 0) {
        int s = 0;
        for (int b = 0; b < nb; ++b) { int t = btot[b]; btot[b] = s; s += t; }
        btot[nb] = s;
    }
}

__global__ __launch_bounds__(1024) void scan3_kernel(int* __restrict__ rowptr,
                                                     const int* __restrict__ btot,
                                                     int n, int nb) {
    int i = blockIdx.x * 1024 + threadIdx.x;
    if (i < n) rowptr[i] += btot[i >> 10];
    else if (i == n) rowptr[n] = btot[nb];
}

__global__ void fill_kernel(const int* __restrict__ src, const int* __restrict__ dst,
                            const int* __restrict__ rowptr, int* __restrict__ cursor,
                            int* __restrict__ csrcB, int E) {
    int e = blockIdx.x * 256 + threadIdx.x;
    if (e < E) {
        int d = dst[e];
        int p = atomicAdd(&cursor[d], 1);
        csrcB[rowptr[d] + p] = src[e] * 2048;   // byte offset into xlr (512 f32/row)
    }
}

// ---------------------------------------------------------------------------
// Embedding: h = relu(x @ W_emb + b_emb) + pos_emb[n % 88]; also bf16 hi/lo
// ---------------------------------------------------------------------------
__global__ __launch_bounds__(256) void embed_kernel(const float* __restrict__ x,
                                                    const float* __restrict__ Wemb,
                                                    const float* __restrict__ bemb,
                                                    const float* __restrict__ pos,
                                                    float* __restrict__ h,
                                                    unsigned short* __restrict__ hh,
                                                    unsigned short* __restrict__ hl) {
    __shared__ float Wl[NIDF][CN];
    int tid = threadIdx.x;
    for (int i = tid; i < NIDF * CN; i += 256) Wl[i >> 8][i & 255] = Wemb[i];
    __syncthreads();
    float bias = bemb[tid];
    int node0 = blockIdx.x * 16;
    for (int q = 0; q < 16; ++q) {
        int n = node0 + q;
        float acc = bias;
        #pragma unroll
        for (int k = 0; k < NIDF; ++k) acc += x[n * NIDF + k] * Wl[k][tid];
        float val = fmaxf(acc, 0.f) + pos[(n % KPG) * CN + tid];
        h[(size_t)n * CN + tid] = val;
        unsigned short vh = f2bf(val);
        hh[(size_t)n * CN + tid] = vh;
        hl[(size_t)n * CN + tid] = f2bf(val - bf2f(vh));
    }
}

// ---------------------------------------------------------------------------
// Weight decompose + fragment-order relayout (concat Ws|Wd), all 4 layers
// ---------------------------------------------------------------------------
__global__ void wconv_cat_kernel(const float* __restrict__ Ws, const float* __restrict__ Wd,
                                 unsigned short* __restrict__ Bh,
                                 unsigned short* __restrict__ Bl, int NB, int tot) {
    int o = blockIdx.x * 256 + threadIdx.x;
    if (o >= tot) return;
    int l4 = blockIdx.y;
    const float* ws = Ws + (size_t)l4 * 256 * 256;
    const float* wd = Wd + (size_t)l4 * 256 * 256;
    int idx = o & 511;
    int nb = (o >> 9) % NB;
    int kb = o / (512 * NB);
    int l = idx >> 3, j = idx & 7;
    int k = kb * 32 + (l >> 4) * 8 + j;
    int c = nb * 16 + (l & 15);
    float v = (c < 256) ? ws[(size_t)k * 256 + c] : wd[(size_t)k * 256 + (c - 256)];
    unsigned short hh = f2bf(v);
    Bh[(size_t)l4 * tot + o] = hh;
    Bl[(size_t)l4 * tot + o] = f2bf(v - bf2f(hh));
}

__global__ void wconv_kernel(const float* __restrict__ W, unsigned short* __restrict__ Bh,
                             unsigned short* __restrict__ Bl, int Nn, int NB, int tot) {
    int o = blockIdx.x * 256 + threadIdx.x;
    if (o >= tot) return;
    int idx = o & 511;
    int nb = (o >> 9) % NB;
    int kb = o / (512 * NB);
    int l = idx >> 3, j = idx & 7;
    int k = kb * 32 + (l >> 4) * 8 + j;
    int c = nb * 16 + (l & 15);
    float v = (c < Nn) ? W[(size_t)k * Nn + c] : 0.f;
    unsigned short hh = f2bf(v);
    Bh[o] = hh;
    Bl[o] = f2bf(v - bf2f(hh));
}

// ---------------------------------------------------------------------------
// MFMA GEMM, bf16 split 3-product: C = A[M,K] @ B[K,N] (+bias)
// ---------------------------------------------------------------------------
template <bool BIAS>
__global__ __launch_bounds__(256) void mgemm(const unsigned short* __restrict__ Ah,
                                             const unsigned short* __restrict__ Al,
                                             const unsigned short* __restrict__ Bh,
                                             const unsigned short* __restrict__ Bl,
                                             const float* __restrict__ bias,
                                             float* __restrict__ C,
                                             int M, int Nlog, int NB, int K) {
    __shared__ unsigned short AhL[8 * 64 * 8];
    __shared__ unsigned short AlL[8 * 64 * 8];
    __shared__ unsigned short BhL[8 * 64 * 8];
    __shared__ unsigned short BlL[8 * 64 * 8];
    int tid = threadIdx.x;
    int wid = tid >> 6, lane = tid & 63;
    int row0 = blockIdx.x * 128;
    int cb = blockIdx.y;
    int wr = wid >> 1, wc = wid & 1;

    int rr = lane & 15, kq = lane >> 4;

    f32x4 acc[4][4] = {};

    for (int k0 = 0; k0 < K; k0 += 32) {
        int kb = k0 >> 5;
        {
            int mb0 = wid * 2;
            const unsigned short* s0 = Ah + (size_t)(row0 + mb0 * 16 + rr) * K + k0 + kq * 8;
            const unsigned short* s1 = Ah + (size_t)(row0 + mb0 * 16 + 16 + rr) * K + k0 + kq * 8;
            glds16(s0, &AhL[mb0 * 512]);
            glds16(s1, &AhL[mb0 * 512 + 512]);
            const unsigned short* t0 = Al + (size_t)(row0 + mb0 * 16 + rr) * K + k0 + kq * 8;
            const unsigned short* t1 = Al + (size_t)(row0 + mb0 * 16 + 16 + rr) * K + k0 + kq * 8;
            glds16(t0, &AlL[mb0 * 512]);
            glds16(t1, &AlL[mb0 * 512 + 512]);
        }
        {
            size_t base = ((size_t)kb * NB + (size_t)cb * 8) * 512;
            for (int ch = wid; ch < 8; ch += 4) {
                glds16(Bh + base + ch * 512 + lane * 8, &BhL[ch * 512]);
                glds16(Bl + base + ch * 512 + lane * 8, &BlL[ch * 512]);
            }
        }
        __syncthreads();
        bf16x8 a_h[4], a_l[4], b_h[4], b_l[4];
        #pragma unroll
        for (int mf = 0; mf < 4; ++mf) {
            int off = ((wr * 4 + mf) * 64 + lane) * 8;
            a_h[mf] = *reinterpret_cast<const bf16x8*>(&AhL[off]);
            a_l[mf] = *reinterpret_cast<const bf16x8*>(&AlL[off]);
        }
        #pragma unroll
        for (int nf = 0; nf < 4; ++nf) {
            int off = ((wc * 4 + nf) * 64 + lane) * 8;
            b_h[nf] = *reinterpret_cast<const bf16x8*>(&BhL[off]);
            b_l[nf] = *reinterpret_cast<const bf16x8*>(&BlL[off]);
        }
        #pragma unroll
        for (int mf = 0; mf < 4; ++mf)
            #pragma unroll
            for (int nf = 0; nf < 4; ++nf) {
                acc[mf][nf] = __builtin_amdgcn_mfma_f32_16x16x32_bf16(a_h[mf], b_h[nf], acc[mf][nf], 0, 0, 0);
                acc[mf][nf] = __builtin_amdgcn_mfma_f32_16x16x32_bf16(a_h[mf], b_l[nf], acc[mf][nf], 0, 0, 0);
                acc[mf][nf] = __builtin_amdgcn_mfma_f32_16x16x32_bf16(a_l[mf], b_h[nf], acc[mf][nf], 0, 0, 0);
            }
        __syncthreads();
    }
    #pragma unroll
    for (int mf = 0; mf < 4; ++mf) {
        #pragma unroll
        for (int nf = 0; nf < 4; ++nf) {
            int col = cb * 128 + wc * 64 + nf * 16 + (lane & 15);
            if (col < Nlog) {
                float bv = BIAS ? bias[col] : 0.f;
                #pragma unroll
                for (int rg = 0; rg < 4; ++rg) {
                    int row = row0 + wr * 64 + mf * 16 + (lane >> 4) * 4 + rg;
                    C[(size_t)row * Nlog + col] = acc[mf][nf][rg] + bv;
                }
            }
        }
    }
}

// ---------------------------------------------------------------------------
// GAT aggregate v6: one wave per node, 4 nodes/block, no LDS/barriers.
// Base-2 softmax: att pre-scaled by log2e, raw v_exp_f32, clamp 80 in log2
// domain, no running max (shift-invariance; LN'd features keep scores small).
// Unroll-4 edges, 4-ahead prefetch (tail loads clamped to last edge, tail
// scores masked to -inf -> exp = 0). DPP 8-lane reduce. XCD swizzle.
// ---------------------------------------------------------------------------
__global__ __launch_bounds__(256) void gat_agg(const float* __restrict__ xlr,
                                               const int* __restrict__ rowptr,
                                               const int* __restrict__ csrcB,
                                               const float* __restrict__ att,
                                               const float* __restrict__ bias,
                                               const float* __restrict__ lng,
                                               const float* __restrict__ lnb,
                                               float* __restrict__ h,
                                               unsigned short* __restrict__ hh,
                                               unsigned short* __restrict__ hl) {
    int cpx = gridDim.x >> 3;
    int swz = (blockIdx.x & 7) * cpx + (blockIdx.x >> 3);
    int wid = threadIdx.x >> 6, lane = threadIdx.x & 63;
    int n = swz * 4 + wid;

    const char* xbase = (const char*)xlr + lane * 16;
    float4 xr4 = *reinterpret_cast<const float4*>(xlr + (size_t)n * 512 + 256 + lane * 4);
    float4 at4 = *reinterpret_cast<const float4*>(att + lane * 4);
    at4.x *= LOG2E; at4.y *= LOG2E; at4.z *= LOG2E; at4.w *= LOG2E;
    float4 hr4 = *reinterpret_cast<const float4*>(h + (size_t)n * CN + lane * 4);

    int e0 = rowptr[n], e1 = rowptr[n + 1];
    int last = e1 - 1;
    float s_r = 0.f;
    float a0 = 0.f, a1 = 0.f, a2 = 0.f, a3 = 0.f;

    float4 X0 = *reinterpret_cast<const float4*>(xbase + csrcB[e0]);
    float4 X1 = *reinterpret_cast<const float4*>(xbase + csrcB[min(e0 + 1, last)]);
    float4 X2 = *reinterpret_cast<const float4*>(xbase + csrcB[min(e0 + 2, last)]);
    float4 X3 = *reinterpret_cast<const float4*>(xbase + csrcB[min(e0 + 3, last)]);

    for (int e = e0; e < e1; e += 4) {
        float4 xa = X0, xb = X1, xc = X2, xd = X3;
        int ne = e + 4;
        if (ne < e1) {
            X0 = *reinterpret_cast<const float4*>(xbase + csrcB[ne]);
            X1 = *reinterpret_cast<const float4*>(xbase + csrcB[min(ne + 1, last)]);
            X2 = *reinterpret_cast<const float4*>(xbase + csrcB[min(ne + 2, last)]);
            X3 = *reinterpret_cast<const float4*>(xbase + csrcB[min(ne + 3, last)]);
        }

        float z, pa = 0.f, pb = 0.f, pc = 0.f, pd = 0.f;
        z = xa.x + xr4.x; z = fmaxf(z, 0.2f * z); pa += z * at4.x;
        z = xa.y + xr4.y; z = fmaxf(z, 0.2f * z); pa += z * at4.y;
        z = xa.z + xr4.z; z = fmaxf(z, 0.2f * z); pa += z * at4.z;
        z = xa.w + xr4.w; z = fmaxf(z, 0.2f * z); pa += z * at4.w;
        z = xb.x + xr4.x; z = fmaxf(z, 0.2f * z); pb += z * at4.x;
        z = xb.y + xr4.y; z = fmaxf(z, 0.2f * z); pb += z * at4.y;
        z = xb.z + xr4.z; z = fmaxf(z, 0.2f * z); pb += z * at4.z;
        z = xb.w + xr4.w; z = fmaxf(z, 0.2f * z); pb += z * at4.w;
        z = xc.x + xr4.x; z = fmaxf(z, 0.2f * z); pc += z * at4.x;
        z = xc.y + xr4.y; z = fmaxf(z, 0.2f * z); pc += z * at4.y;
        z = xc.z + xr4.z; z = fmaxf(z, 0.2f * z); pc += z * at4.z;
        z = xc.w + xr4.w; z = fmaxf(z, 0.2f * z); pc += z * at4.w;
        z = xd.x + xr4.x; z = fmaxf(z, 0.2f * z); pd += z * at4.x;
        z = xd.y + xr4.y; z = fmaxf(z, 0.2f * z); pd += z * at4.y;
        z = xd.z + xr4.z; z = fmaxf(z, 0.2f * z); pd += z * at4.z;
        z = xd.w + xr4.w; z = fmaxf(z, 0.2f * z); pd += z * at4.w;

        pa = grp8_sum(pa);
        pb = grp8_sum(pb);
        pc = grp8_sum(pc);
        pd = grp8_sum(pd);
        pa = fminf(pa, 80.f);
        pb = (e + 1 < e1) ? fminf(pb, 80.f) : -INFINITY;
        pc = (e + 2 < e1) ? fminf(pc, 80.f) : -INFINITY;
        pd = (e + 3 < e1) ? fminf(pd, 80.f) : -INFINITY;

        float wa = fexp2(pa);
        float wb = fexp2(pb);
        float wc = fexp2(pc);
        float wd = fexp2(pd);
        s_r += (wa + wb) + (wc + wd);
        a0 += wa * xa.x + wb * xb.x + wc * xc.x + wd * xd.x;
        a1 += wa * xa.y + wb * xb.y + wc * xc.y + wd * xd.y;
        a2 += wa * xa.z + wb * xb.z + wc * xc.z + wd * xd.z;
        a3 += wa * xa.w + wb * xb.w + wc * xc.w + wd * xd.w;
    }

    float inv = 1.f / s_r;
    float4 bi4 = *reinterpret_cast<const float4*>(bias + lane * 4);
    float v0 = hr4.x + fmaxf(a0 * inv + bi4.x, 0.f);
    float v1 = hr4.y + fmaxf(a1 * inv + bi4.y, 0.f);
    float v2 = hr4.z + fmaxf(a2 * inv + bi4.z, 0.f);
    float v3 = hr4.w + fmaxf(a3 * inv + bi4.w, 0.f);

    float sum = v0 + v1 + v2 + v3;
    float sq = v0 * v0 + v1 * v1 + v2 * v2 + v3 * v3;
    #pragma unroll
    for (int o = 32; o; o >>= 1) { sum += __shfl_xor(sum, o); sq += __shfl_xor(sq, o); }
    float mu = sum / CN;
    float var = sq / CN - mu * mu;
    float ninv = rsqrtf(var + 1e-5f);
    float4 lg4 = *reinterpret_cast<const float4*>(lng + lane * 4);
    float4 lb4 = *reinterpret_cast<const float4*>(lnb + lane * 4);
    float o0 = (v0 - mu) * ninv * lg4.x + lb4.x;
    float o1 = (v1 - mu) * ninv * lg4.y + lb4.y;
    float o2 = (v2 - mu) * ninv * lg4.z + lb4.z;
    float o3 = (v3 - mu) * ninv * lg4.w + lb4.w;
    *reinterpret_cast<float4*>(h + (size_t)n * CN + lane * 4) = make_float4(o0, o1, o2, o3);

    ushort4 uh, ul;
    unsigned short t;
    t = f2bf(o0); uh.x = t; ul.x = f2bf(o0 - bf2f(t));
    t = f2bf(o1); uh.y = t; ul.y = f2bf(o1 - bf2f(t));
    t = f2bf(o2); uh.z = t; ul.z = f2bf(o2 - bf2f(t));
    t = f2bf(o3); uh.w = t; ul.w = f2bf(o3 - bf2f(t));
    *reinterpret_cast<ushort4*>(hh + (size_t)n * CN + lane * 4) = uh;
    *reinterpret_cast<ushort4*>(hl + (size_t)n * CN + lane * 4) = ul;
}

// ---------------------------------------------------------------------------
// gate[n] = relu(gtmp[n]) . gW2 + gb2
// ---------------------------------------------------------------------------
__global__ __launch_bounds__(256) void gate2_kernel(const float* __restrict__ gtmp,
                                                    const float* __restrict__ gW2,
                                                    const float* __restrict__ gb2,
                                                    float* __restrict__ gate, int N) {
    int n = blockIdx.x * 4 + (threadIdx.x >> 6);
    if (n >= N) return;
    int lane = threadIdx.x & 63;
    float2 t = *reinterpret_cast<const float2*>(gtmp + (size_t)n * GATE_DIM + lane * 2);
    float2 w = *reinterpret_cast<const float2*>(gW2 + lane * 2);
    float c = fmaxf(t.x, 0.f) * w.x + fmaxf(t.y, 0.f) * w.y;
    #pragma unroll
    for (int o = 32; o; o >>= 1) c += __shfl_xor(c, o);
    if (lane == 0) gate[n] = c + gb2[0];
}

// ---------------------------------------------------------------------------
// Pool: segment softmax over contiguous 88-node graphs + weighted sum -> emb
// ---------------------------------------------------------------------------
__global__ __launch_bounds__(256) void pool_kernel(const float* __restrict__ gate,
                                                   const float* __restrict__ h,
                                                   float* __restrict__ emb) {
    __shared__ float a[KPG];
    __shared__ float wm[4];
    int g = blockIdx.x, tid = threadIdx.x;
    int wid = tid >> 6, lane = tid & 63;
    float gv = (tid < KPG) ? gate[g * KPG + tid] : -INFINITY;
    float m = gv;
    #pragma unroll
    for (int o = 32; o; o >>= 1) m = fmaxf(m, __shfl_xor(m, o));
    if (lane == 0) wm[wid] = m;
    __syncthreads();
    m = fmaxf(fmaxf(wm[0], wm[1]), fmaxf(wm[2], wm[3]));
    __syncthreads();
    float av = (tid < KPG) ? expf(gv - m) : 0.f;
    if (tid < KPG) a[tid] = av;
    float s = av;
    #pragma unroll
    for (int o = 32; o; o >>= 1) s += __shfl_xor(s, o);
    if (lane == 0) wm[wid] = s;
    __syncthreads();
    s = wm[0] + wm[1] + wm[2] + wm[3];
    float inv = 1.f / s;
    float acc = 0.f;
    const float* hg = h + (size_t)g * KPG * CN;
    for (int i = 0; i < KPG; ++i) acc += a[i] * hg[i * CN + tid];
    emb[(size_t)g * CN + tid] = acc * inv;
}

// ---------------------------------------------------------------------------
// Heads: t1 = relu(LN(emb@pW1+pb1)) (bf16 split out); value head full
// ---------------------------------------------------------------------------
__global__ __launch_bounds__(256) void head_kernel(const float* __restrict__ emb,
    const float* __restrict__ pW1, const float* __restrict__ pb1,
    const float* __restrict__ plng, const float* __restrict__ plnb,
    const float* __restrict__ vW1, const float* __restrict__ vb1,
    const float* __restrict__ vW2, const float* __restrict__ vb2,
    unsigned short* __restrict__ t1h, unsigned short* __restrict__ t1l,
    float* __restrict__ value_out) {
    __shared__ float e_l[CN];
    __shared__ float rsum[4], rsq[4];
    int g = blockIdx.x, tid = threadIdx.x;
    int wid = tid >> 6, lane = tid & 63;
    e_l[tid] = emb[(size_t)g * CN + tid];
    __syncthreads();
    float p = pb1[tid], v = vb1[tid];
    for (int k = 0; k < CN; ++k) {
        float e = e_l[k];
        p += e * pW1[k * CN + tid];
        v += e * vW1[k * CN + tid];
    }
    float sum = p, sq = p * p;
    #pragma unroll
    for (int o = 32; o; o >>= 1) { sum += __shfl_xor(sum, o); sq += __shfl_xor(sq, o); }
    if (lane == 0) { rsum[wid] = sum; rsq[wid] = sq; }
    __syncthreads();
    sum = rsum[0] + rsum[1] + rsum[2] + rsum[3];
    sq  = rsq[0] + rsq[1] + rsq[2] + rsq[3];
    float mu = sum / CN;
    float var = sq / CN - mu * mu;
    float inv = rsqrtf(var + 1e-5f);
    float t1v = fmaxf((p - mu) * inv * plng[tid] + plnb[tid], 0.f);
    unsigned short th = f2bf(t1v);
    t1h[(size_t)g * CN + tid] = th;
    t1l[(size_t)g * CN + tid] = f2bf(t1v - bf2f(th));
    float contrib = fmaxf(v, 0.f) * vW2[tid];
    __syncthreads();
    #pragma unroll
    for (int o = 32; o; o >>= 1) contrib += __shfl_xor(contrib, o);
    if (lane == 0) rsum[wid] = contrib;
    __syncthreads();
    if (tid == 0)
        value_out[g] = tanhf(rsum[0] + rsum[1] + rsum[2] + rsum[3] + vb2[0]);
}

// ---------------------------------------------------------------------------
extern "C" void kernel_launch(void* const* d_in, const int* in_sizes, int n_in,
                              void* d_out, int out_size, void* d_ws, size_t ws_size,
                              hipStream_t stream) {
    const float* x        = (const float*)d_in[0];
    const int*   ei       = (const int*)d_in[1];
    const float* W_emb    = (const float*)d_in[4];
    const float* b_emb    = (const float*)d_in[5];
    const float* pos_emb  = (const float*)d_in[6];
    const float* gat_Wsrc = (const float*)d_in[7];
    const float* gat_Wdst = (const float*)d_in[8];
    const float* gat_att  = (const float*)d_in[9];
    const float* gat_bias = (const float*)d_in[10];
    const float* ln_g     = (const float*)d_in[11];
    const float* ln_b     = (const float*)d_in[12];
    const float* gW1      = (const float*)d_in[13];
    const float* gb1      = (const float*)d_in[14];
    const float* gW2      = (const float*)d_in[15];
    const float* gb2      = (const float*)d_in[16];
    const float* pW1      = (const float*)d_in[17];
    const float* pb1      = (const float*)d_in[18];
    const float* p_ln_g   = (const float*)d_in[19];
    const float* p_ln_b   = (const float*)d_in[20];
    const float* pW2      = (const float*)d_in[21];
    const float* pb2      = (const float*)d_in[22];
    const float* vW1      = (const float*)d_in[23];
    const float* vb1      = (const float*)d_in[24];
    const float* vW2      = (const float*)d_in[25];
    const float* vb2      = (const float*)d_in[26];

    const int N = in_sizes[2];      // 22528
    const int E = in_sizes[1] / 2;  // 405504
    const int G = N / KPG;          // 256
    const int NB_SC = (N + 1023) / 1024;

    const int NB_CAT = 32;                        // 512/16
    const int NB_G1  = 8;                         // 128/16
    const int GY_POL = (ACT_DIM + 127) / 128;     // 37
    const int NB_POL = GY_POL * 8;                // 296 (padded)

    char* ws = (char*)d_ws;
    size_t off = 0;
    auto alloc = [&](size_t nbytes) {
        void* pp = ws + off;
        off = (off + nbytes + 255) & ~(size_t)255;
        return pp;
    };
    float* h      = (float*)alloc((size_t)N * CN * 4);
    unsigned short* hh = (unsigned short*)alloc((size_t)N * CN * 2);
    unsigned short* hl = (unsigned short*)alloc((size_t)N * CN * 2);
    float* xlr    = (float*)alloc((size_t)N * 512 * 4);       // reused as gtmp
    unsigned short* WcatH = (unsigned short*)alloc((size_t)4 * 8 * NB_CAT * 512 * 2);
    unsigned short* WcatL = (unsigned short*)alloc((size_t)4 * 8 * NB_CAT * 512 * 2);
    unsigned short* gW1H  = (unsigned short*)alloc((size_t)8 * NB_G1 * 512 * 2);
    unsigned short* gW1L  = (unsigned short*)alloc((size_t)8 * NB_G1 * 512 * 2);
    unsigned short* pW2H  = (unsigned short*)alloc((size_t)8 * NB_POL * 512 * 2);
    unsigned short* pW2L  = (unsigned short*)alloc((size_t)8 * NB_POL * 512 * 2);
    float* gate   = (float*)alloc((size_t)N * 4);
    float* emb    = (float*)alloc((size_t)G * CN * 4);
    unsigned short* t1h = (unsigned short*)alloc((size_t)G * CN * 2);
    unsigned short* t1l = (unsigned short*)alloc((size_t)G * CN * 2);
    int*   rowptr = (int*)alloc((size_t)(N + 1) * 4);
    int*   cnt    = (int*)alloc((size_t)N * 4);
    int*   cursor = (int*)alloc((size_t)N * 4);
    int*   btot   = (int*)alloc((size_t)64 * 4);
    int*   csrcB  = (int*)alloc((size_t)E * 4);
    float* gtmp   = xlr;

    const int* e_src = ei;
    const int* e_dst = ei + E;

    hipMemsetAsync(cnt, 0, (size_t)N * 4, stream);
    hipMemsetAsync(cursor, 0, (size_t)N * 4, stream);
    count_kernel<<<(E + 255) / 256, 256, 0, stream>>>(e_dst, cnt, E);
    scan1_kernel<<<NB_SC, 1024, 0, stream>>>(cnt, rowptr, btot, N);
    scan2_kernel<<<1, 64, 0, stream>>>(btot, NB_SC);
    scan3_kernel<<<(N + 1024) / 1024, 1024, 0, stream>>>(rowptr, btot, N, NB_SC);
    fill_kernel<<<(E + 255) / 256, 256, 0, stream>>>(e_src, e_dst, rowptr, cursor, csrcB, E);

    embed_kernel<<<N / 16, 256, 0, stream>>>(x, W_emb, b_emb, pos_emb, h, hh, hl);

    {
        int totc = 8 * NB_CAT * 512;
        dim3 gw((totc + 255) / 256, 4);
        wconv_cat_kernel<<<gw, 256, 0, stream>>>(gat_Wsrc, gat_Wdst, WcatH, WcatL, NB_CAT, totc);
        int totg = 8 * NB_G1 * 512;
        wconv_kernel<<<(totg + 255) / 256, 256, 0, stream>>>(gW1, gW1H, gW1L, GATE_DIM, NB_G1, totg);
        int totp = 8 * NB_POL * 512;
        wconv_kernel<<<(totp + 255) / 256, 256, 0, stream>>>(pW2, pW2H, pW2L, ACT_DIM, NB_POL, totp);
    }

    for (int l = 0; l < 4; ++l) {
        size_t wo = (size_t)l * 8 * NB_CAT * 512;
        dim3 g1(N / 128, 512 / 128);
        mgemm<false><<<g1, 256, 0, stream>>>(hh, hl, WcatH + wo, WcatL + wo, nullptr,
                                             xlr, N, 512, NB_CAT, CN);
        gat_agg<<<N / 4, 256, 0, stream>>>(xlr, rowptr, csrcB, gat_att + l * CN,
                                           gat_bias + l * CN, ln_g + l * CN, ln_b + l * CN,
                                           h, hh, hl);
    }

    // gate MLP
    {
        dim3 g1(N / 128, 1);
        mgemm<true><<<g1, 256, 0, stream>>>(hh, hl, gW1H, gW1L, gb1, gtmp, N, GATE_DIM, NB_G1, CN);
        gate2_kernel<<<(N + 3) / 4, 256, 0, stream>>>(gtmp, gW2, gb2, gate, N);
    }
    pool_kernel<<<G, 256, 0, stream>>>(gate, h, emb);

    float* policy = (float*)d_out;
    float* value  = (float*)d_out + (size_t)G * ACT_DIM;
    head_kernel<<<G, 256, 0, stream>>>(emb, pW1, pb1, p_ln_g, p_ln_b,
                                       vW1, vb1, vW2, vb2, t1h, t1l, value);
    dim3 g2(G / 128, GY_POL);
    mgemm<true><<<g2, 256, 0, stream>>>(t1h, t1l, pW2H, pW2L, pb2, policy, G, ACT_DIM, NB_POL, CN);
}

// Round 9
// 369.115 us; speedup vs baseline: 3.4321x; 1.0360x over previous
//
#include <hip/hip_runtime.h>
#include <math.h>

constexpr int CN = 256;        // channels
constexpr int NHEAD = 8;       // attention heads
constexpr int KPG = 88;        // nodes per graph
constexpr int NIDF = 16;       // input node features
constexpr int GATE_DIM = 128;
constexpr int ACT_DIM = 4644;
constexpr float LOG2E = 1.4426950408889634f;

typedef __attribute__((ext_vector_type(8))) short bf16x8;
typedef __attribute__((ext_vector_type(4))) float f32x4;

__device__ __forceinline__ unsigned short f2bf(float f) {
    unsigned int u = __float_as_uint(f);
    unsigned int r = (u + 0x7fffu + ((u >> 16) & 1u)) >> 16;
    return (unsigned short)r;
}
__device__ __forceinline__ float bf2f(unsigned short h) {
    return __uint_as_float(((unsigned int)h) << 16);
}

__device__ __forceinline__ void glds16(const void* g, void* l) {
    __builtin_amdgcn_global_load_lds(
        (const __attribute__((address_space(1))) unsigned int*)g,
        (__attribute__((address_space(3))) unsigned int*)l, 16, 0, 0);
}

// raw v_exp_f32: w = 2^x  (inputs pre-scaled by log2e; clamped <= 80, -inf -> 0)
__device__ __forceinline__ float fexp2(float x) {
    float r;
    asm("v_exp_f32 %0, %1" : "=v"(r) : "v"(x));
    return r;
}

// 8-lane group sum via DPP (VALU-speed, no LDS pipe)
__device__ __forceinline__ float grp8_sum(float p) {
    int t;
    t = __builtin_amdgcn_mov_dpp(__float_as_int(p), 0xB1, 0xF, 0xF, true);
    p += __int_as_float(t);
    t = __builtin_amdgcn_mov_dpp(__float_as_int(p), 0x4E, 0xF, 0xF, true);
    p += __int_as_float(t);
    t = __builtin_amdgcn_mov_dpp(__float_as_int(p), 0x141, 0xF, 0xF, true);
    p += __int_as_float(t);
    return p;
}

// ---------------------------------------------------------------------------
// CSR build: count -> hierarchical scan -> fill (csrcB = byte offsets)
// ---------------------------------------------------------------------------
__global__ void count_kernel(const int* __restrict__ dst, int* __restrict__ cnt, int E) {
    int e = blockIdx.x * 256 + threadIdx.x;
    if (e < E) atomicAdd(&cnt[dst[e]], 1);
}

__global__ __launch_bounds__(1024) void scan1_kernel(const int* __restrict__ cnt,
                                                     int* __restrict__ rowptr,
                                                     int* __restrict__ btot, int n) {
    __shared__ int buf[1024];
    int tid = threadIdx.x;
    int i = blockIdx.x * 1024 + tid;
    int v = (i < n) ? cnt[i] : 0;
    buf[tid] = v;
    __syncthreads();
    for (int off = 1; off < 1024; off <<= 1) {
        int t = (tid >= off) ? buf[tid - off] : 0;
        __syncthreads();
        buf[tid] += t;
        __syncthreads();
    }
    if (i < n) rowptr[i] = buf[tid] - v;
    if (tid == 1023) btot[blockIdx.x] = buf[1023];
}

__global__ void scan2_kernel(int* __restrict__ btot, int nb) {
    if (threadIdx.x == 0 && blockIdx.x == 0) {
        int s = 0;
        for (int b = 0; b < nb; ++b) { int t = btot[b]; btot[b] = s; s += t; }
        btot[nb] = s;
    }
}

__global__ __launch_bounds__(1024) void scan3_kernel(int* __restrict__ rowptr,
                                                     const int* __restrict__ btot,
                                                     int n, int nb) {
    int i = blockIdx.x * 1024 + threadIdx.x;
    if (i < n) rowptr[i] += btot[i >> 10];
    else if (i == n) rowptr[n] = btot[nb];
}

__global__ void fill_kernel(const int* __restrict__ src, const int* __restrict__ dst,
                            const int* __restrict__ rowptr, int* __restrict__ cursor,
                            int* __restrict__ csrcB, int E) {
    int e = blockIdx.x * 256 + threadIdx.x;
    if (e < E) {
        int d = dst[e];
        int p = atomicAdd(&cursor[d], 1);
        csrcB[rowptr[d] + p] = src[e] * 2048;   // byte offset into xlr (512 f32/row)
    }
}

// ---------------------------------------------------------------------------
// Embedding: h = relu(x @ W_emb + b_emb) + pos_emb[n % 88]; also bf16 hi/lo
// ---------------------------------------------------------------------------
__global__ __launch_bounds__(256) void embed_kernel(const float* __restrict__ x,
                                                    const float* __restrict__ Wemb,
                                                    const float* __restrict__ bemb,
                                                    const float* __restrict__ pos,
                                                    float* __restrict__ h,
                                                    unsigned short* __restrict__ hh,
                                                    unsigned short* __restrict__ hl) {
    __shared__ float Wl[NIDF][CN];
    int tid = threadIdx.x;
    for (int i = tid; i < NIDF * CN; i += 256) Wl[i >> 8][i & 255] = Wemb[i];
    __syncthreads();
    float bias = bemb[tid];
    int node0 = blockIdx.x * 16;
    for (int q = 0; q < 16; ++q) {
        int n = node0 + q;
        float acc = bias;
        #pragma unroll
        for (int k = 0; k < NIDF; ++k) acc += x[n * NIDF + k] * Wl[k][tid];
        float val = fmaxf(acc, 0.f) + pos[(n % KPG) * CN + tid];
        h[(size_t)n * CN + tid] = val;
        unsigned short vh = f2bf(val);
        hh[(size_t)n * CN + tid] = vh;
        hl[(size_t)n * CN + tid] = f2bf(val - bf2f(vh));
    }
}

// ---------------------------------------------------------------------------
// Weight decompose + fragment-order relayout (concat Ws|Wd), all 4 layers
// ---------------------------------------------------------------------------
__global__ void wconv_cat_kernel(const float* __restrict__ Ws, const float* __restrict__ Wd,
                                 unsigned short* __restrict__ Bh,
                                 unsigned short* __restrict__ Bl, int NB, int tot) {
    int o = blockIdx.x * 256 + threadIdx.x;
    if (o >= tot) return;
    int l4 = blockIdx.y;
    const float* ws = Ws + (size_t)l4 * 256 * 256;
    const float* wd = Wd + (size_t)l4 * 256 * 256;
    int idx = o & 511;
    int nb = (o >> 9) % NB;
    int kb = o / (512 * NB);
    int l = idx >> 3, j = idx & 7;
    int k = kb * 32 + (l >> 4) * 8 + j;
    int c = nb * 16 + (l & 15);
    float v = (c < 256) ? ws[(size_t)k * 256 + c] : wd[(size_t)k * 256 + (c - 256)];
    unsigned short hh = f2bf(v);
    Bh[(size_t)l4 * tot + o] = hh;
    Bl[(size_t)l4 * tot + o] = f2bf(v - bf2f(hh));
}

__global__ void wconv_kernel(const float* __restrict__ W, unsigned short* __restrict__ Bh,
                             unsigned short* __restrict__ Bl, int Nn, int NB, int tot) {
    int o = blockIdx.x * 256 + threadIdx.x;
    if (o >= tot) return;
    int idx = o & 511;
    int nb = (o >> 9) % NB;
    int kb = o / (512 * NB);
    int l = idx >> 3, j = idx & 7;
    int k = kb * 32 + (l >> 4) * 8 + j;
    int c = nb * 16 + (l & 15);
    float v = (c < Nn) ? W[(size_t)k * Nn + c] : 0.f;
    unsigned short hh = f2bf(v);
    Bh[o] = hh;
    Bl[o] = f2bf(v - bf2f(hh));
}

// ---------------------------------------------------------------------------
// MFMA GEMM, bf16 split 3-product: C = A[M,K] @ B[K,N] (+bias)
// ---------------------------------------------------------------------------
template <bool BIAS>
__global__ __launch_bounds__(256) void mgemm(const unsigned short* __restrict__ Ah,
                                             const unsigned short* __restrict__ Al,
                                             const unsigned short* __restrict__ Bh,
                                             const unsigned short* __restrict__ Bl,
                                             const float* __restrict__ bias,
                                             float* __restrict__ C,
                                             int M, int Nlog, int NB, int K) {
    __shared__ unsigned short AhL[8 * 64 * 8];
    __shared__ unsigned short AlL[8 * 64 * 8];
    __shared__ unsigned short BhL[8 * 64 * 8];
    __shared__ unsigned short BlL[8 * 64 * 8];
    int tid = threadIdx.x;
    int wid = tid >> 6, lane = tid & 63;
    int row0 = blockIdx.x * 128;
    int cb = blockIdx.y;
    int wr = wid >> 1, wc = wid & 1;

    int rr = lane & 15, kq = lane >> 4;

    f32x4 acc[4][4] = {};

    for (int k0 = 0; k0 < K; k0 += 32) {
        int kb = k0 >> 5;
        {
            int mb0 = wid * 2;
            const unsigned short* s0 = Ah + (size_t)(row0 + mb0 * 16 + rr) * K + k0 + kq * 8;
            const unsigned short* s1 = Ah + (size_t)(row0 + mb0 * 16 + 16 + rr) * K + k0 + kq * 8;
            glds16(s0, &AhL[mb0 * 512]);
            glds16(s1, &AhL[mb0 * 512 + 512]);
            const unsigned short* t0 = Al + (size_t)(row0 + mb0 * 16 + rr) * K + k0 + kq * 8;
            const unsigned short* t1 = Al + (size_t)(row0 + mb0 * 16 + 16 + rr) * K + k0 + kq * 8;
            glds16(t0, &AlL[mb0 * 512]);
            glds16(t1, &AlL[mb0 * 512 + 512]);
        }
        {
            size_t base = ((size_t)kb * NB + (size_t)cb * 8) * 512;
            for (int ch = wid; ch < 8; ch += 4) {
                glds16(Bh + base + ch * 512 + lane * 8, &BhL[ch * 512]);
                glds16(Bl + base + ch * 512 + lane * 8, &BlL[ch * 512]);
            }
        }
        __syncthreads();
        bf16x8 a_h[4], a_l[4], b_h[4], b_l[4];
        #pragma unroll
        for (int mf = 0; mf < 4; ++mf) {
            int off = ((wr * 4 + mf) * 64 + lane) * 8;
            a_h[mf] = *reinterpret_cast<const bf16x8*>(&AhL[off]);
            a_l[mf] = *reinterpret_cast<const bf16x8*>(&AlL[off]);
        }
        #pragma unroll
        for (int nf = 0; nf < 4; ++nf) {
            int off = ((wc * 4 + nf) * 64 + lane) * 8;
            b_h[nf] = *reinterpret_cast<const bf16x8*>(&BhL[off]);
            b_l[nf] = *reinterpret_cast<const bf16x8*>(&BlL[off]);
        }
        #pragma unroll
        for (int mf = 0; mf < 4; ++mf)
            #pragma unroll
            for (int nf = 0; nf < 4; ++nf) {
                acc[mf][nf] = __builtin_amdgcn_mfma_f32_16x16x32_bf16(a_h[mf], b_h[nf], acc[mf][nf], 0, 0, 0);
                acc[mf][nf] = __builtin_amdgcn_mfma_f32_16x16x32_bf16(a_h[mf], b_l[nf], acc[mf][nf], 0, 0, 0);
                acc[mf][nf] = __builtin_amdgcn_mfma_f32_16x16x32_bf16(a_l[mf], b_h[nf], acc[mf][nf], 0, 0, 0);
            }
        __syncthreads();
    }
    #pragma unroll
    for (int mf = 0; mf < 4; ++mf) {
        #pragma unroll
        for (int nf = 0; nf < 4; ++nf) {
            int col = cb * 128 + wc * 64 + nf * 16 + (lane & 15);
            if (col < Nlog) {
                float bv = BIAS ? bias[col] : 0.f;
                #pragma unroll
                for (int rg = 0; rg < 4; ++rg) {
                    int row = row0 + wr * 64 + mf * 16 + (lane >> 4) * 4 + rg;
                    C[(size_t)row * Nlog + col] = acc[mf][nf][rg] + bv;
                }
            }
        }
    }
}

// ---------------------------------------------------------------------------
// GAT aggregate v7b: one wave per node, 4 nodes/block, no LDS/barriers.
// Scalarized CSR walk (readfirstlane n/e0/e1 -> SALU control, s_load indices,
// scalar-base gathers). 8 edges in flight (two 4-edge register banks).
// Base-2 softmax, no running max (clamp 80). DPP 8-lane reduce. XCD swizzle.
// ---------------------------------------------------------------------------
__global__ __launch_bounds__(256) void gat_agg(const float* __restrict__ xlr,
                                               const int* __restrict__ rowptr,
                                               const int* __restrict__ csrcB,
                                               const float* __restrict__ att,
                                               const float* __restrict__ bias,
                                               const float* __restrict__ lng,
                                               const float* __restrict__ lnb,
                                               float* __restrict__ h,
                                               unsigned short* __restrict__ hh,
                                               unsigned short* __restrict__ hl) {
    int cpx = gridDim.x >> 3;
    int swz = (blockIdx.x & 7) * cpx + (blockIdx.x >> 3);
    int wid = threadIdx.x >> 6, lane = threadIdx.x & 63;
    int n = __builtin_amdgcn_readfirstlane(swz * 4 + wid);
    int voff = lane * 16;                    // byte offset, loop-invariant VGPR

    float4 xr4 = *reinterpret_cast<const float4*>(xlr + (size_t)n * 512 + 256 + lane * 4);
    float4 at4 = *reinterpret_cast<const float4*>(att + lane * 4);
    at4.x *= LOG2E; at4.y *= LOG2E; at4.z *= LOG2E; at4.w *= LOG2E;
    float4 hr4 = *reinterpret_cast<const float4*>(h + (size_t)n * CN + lane * 4);

    int e0 = __builtin_amdgcn_readfirstlane(rowptr[n]);
    int e1 = __builtin_amdgcn_readfirstlane(rowptr[n + 1]);
    int last = e1 - 1;

    float s_r = 0.f;
    float a0 = 0.f, a1 = 0.f, a2 = 0.f, a3 = 0.f;
    const char* xB = (const char*)xlr;

    auto ld4 = [&](float4* X, int eb) {
        #pragma unroll
        for (int j = 0; j < 4; ++j) {
            int f = csrcB[min(eb + j, last)];
            X[j] = *reinterpret_cast<const float4*>(xB + (unsigned)f + voff);
        }
    };
    auto group4 = [&](const float4* X, int eb) {
        float p[4];
        #pragma unroll
        for (int j = 0; j < 4; ++j) {
            float z, pp = 0.f;
            z = X[j].x + xr4.x; z = fmaxf(z, 0.2f * z); pp += z * at4.x;
            z = X[j].y + xr4.y; z = fmaxf(z, 0.2f * z); pp += z * at4.y;
            z = X[j].z + xr4.z; z = fmaxf(z, 0.2f * z); pp += z * at4.z;
            z = X[j].w + xr4.w; z = fmaxf(z, 0.2f * z); pp += z * at4.w;
            p[j] = grp8_sum(pp);
        }
        float w[4];
        #pragma unroll
        for (int j = 0; j < 4; ++j) {
            float pc = (eb + j < e1) ? fminf(p[j], 80.f) : -INFINITY;
            w[j] = fexp2(pc);
        }
        s_r += (w[0] + w[1]) + (w[2] + w[3]);
        #pragma unroll
        for (int j = 0; j < 4; ++j) {
            a0 += w[j] * X[j].x;
            a1 += w[j] * X[j].y;
            a2 += w[j] * X[j].z;
            a3 += w[j] * X[j].w;
        }
    };

    float4 A[4], B[4];
    ld4(A, e0);
    ld4(B, e0 + 4);
    for (int e = e0; e < e1; e += 8) {
        group4(A, e);
        if (e + 8 < e1) ld4(A, e + 8);
        if (e + 4 < e1) {
            group4(B, e + 4);
            if (e + 12 < e1) ld4(B, e + 12);
        }
    }

    float inv = 1.f / s_r;
    float4 bi4 = *reinterpret_cast<const float4*>(bias + lane * 4);
    float v0 = hr4.x + fmaxf(a0 * inv + bi4.x, 0.f);
    float v1 = hr4.y + fmaxf(a1 * inv + bi4.y, 0.f);
    float v2 = hr4.z + fmaxf(a2 * inv + bi4.z, 0.f);
    float v3 = hr4.w + fmaxf(a3 * inv + bi4.w, 0.f);

    float sum = v0 + v1 + v2 + v3;
    float sq = v0 * v0 + v1 * v1 + v2 * v2 + v3 * v3;
    #pragma unroll
    for (int o = 32; o; o >>= 1) { sum += __shfl_xor(sum, o); sq += __shfl_xor(sq, o); }
    float mu = sum / CN;
    float var = sq / CN - mu * mu;
    float ninv = rsqrtf(var + 1e-5f);
    float4 lg4 = *reinterpret_cast<const float4*>(lng + lane * 4);
    float4 lb4 = *reinterpret_cast<const float4*>(lnb + lane * 4);
    float o0 = (v0 - mu) * ninv * lg4.x + lb4.x;
    float o1 = (v1 - mu) * ninv * lg4.y + lb4.y;
    float o2 = (v2 - mu) * ninv * lg4.z + lb4.z;
    float o3 = (v3 - mu) * ninv * lg4.w + lb4.w;
    *reinterpret_cast<float4*>(h + (size_t)n * CN + lane * 4) = make_float4(o0, o1, o2, o3);

    ushort4 uh, ul;
    unsigned short t;
    t = f2bf(o0); uh.x = t; ul.x = f2bf(o0 - bf2f(t));
    t = f2bf(o1); uh.y = t; ul.y = f2bf(o1 - bf2f(t));
    t = f2bf(o2); uh.z = t; ul.z = f2bf(o2 - bf2f(t));
    t = f2bf(o3); uh.w = t; ul.w = f2bf(o3 - bf2f(t));
    *reinterpret_cast<ushort4*>(hh + (size_t)n * CN + lane * 4) = uh;
    *reinterpret_cast<ushort4*>(hl + (size_t)n * CN + lane * 4) = ul;
}

// ---------------------------------------------------------------------------
// gate[n] = relu(gtmp[n]) . gW2 + gb2
// ---------------------------------------------------------------------------
__global__ __launch_bounds__(256) void gate2_kernel(const float* __restrict__ gtmp,
                                                    const float* __restrict__ gW2,
                                                    const float* __restrict__ gb2,
                                                    float* __restrict__ gate, int N) {
    int n = blockIdx.x * 4 + (threadIdx.x >> 6);
    if (n >= N) return;
    int lane = threadIdx.x & 63;
    float2 t = *reinterpret_cast<const float2*>(gtmp + (size_t)n * GATE_DIM + lane * 2);
    float2 w = *reinterpret_cast<const float2*>(gW2 + lane * 2);
    float c = fmaxf(t.x, 0.f) * w.x + fmaxf(t.y, 0.f) * w.y;
    #pragma unroll
    for (int o = 32; o; o >>= 1) c += __shfl_xor(c, o);
    if (lane == 0) gate[n] = c + gb2[0];
}

// ---------------------------------------------------------------------------
// Pool: segment softmax over contiguous 88-node graphs + weighted sum -> emb
// ---------------------------------------------------------------------------
__global__ __launch_bounds__(256) void pool_kernel(const float* __restrict__ gate,
                                                   const float* __restrict__ h,
                                                   float* __restrict__ emb) {
    __shared__ float a[KPG];
    __shared__ float wm[4];
    int g = blockIdx.x, tid = threadIdx.x;
    int wid = tid >> 6, lane = tid & 63;
    float gv = (tid < KPG) ? gate[g * KPG + tid] : -INFINITY;
    float m = gv;
    #pragma unroll
    for (int o = 32; o; o >>= 1) m = fmaxf(m, __shfl_xor(m, o));
    if (lane == 0) wm[wid] = m;
    __syncthreads();
    m = fmaxf(fmaxf(wm[0], wm[1]), fmaxf(wm[2], wm[3]));
    __syncthreads();
    float av = (tid < KPG) ? expf(gv - m) : 0.f;
    if (tid < KPG) a[tid] = av;
    float s = av;
    #pragma unroll
    for (int o = 32; o; o >>= 1) s += __shfl_xor(s, o);
    if (lane == 0) wm[wid] = s;
    __syncthreads();
    s = wm[0] + wm[1] + wm[2] + wm[3];
    float inv = 1.f / s;
    float acc = 0.f;
    const float* hg = h + (size_t)g * KPG * CN;
    for (int i = 0; i < KPG; ++i) acc += a[i] * hg[i * CN + tid];
    emb[(size_t)g * CN + tid] = acc * inv;
}

// ---------------------------------------------------------------------------
// Heads: t1 = relu(LN(emb@pW1+pb1)) (bf16 split out); value head full
// ---------------------------------------------------------------------------
__global__ __launch_bounds__(256) void head_kernel(const float* __restrict__ emb,
    const float* __restrict__ pW1, const float* __restrict__ pb1,
    const float* __restrict__ plng, const float* __restrict__ plnb,
    const float* __restrict__ vW1, const float* __restrict__ vb1,
    const float* __restrict__ vW2, const float* __restrict__ vb2,
    unsigned short* __restrict__ t1h, unsigned short* __restrict__ t1l,
    float* __restrict__ value_out) {
    __shared__ float e_l[CN];
    __shared__ float rsum[4], rsq[4];
    int g = blockIdx.x, tid = threadIdx.x;
    int wid = tid >> 6, lane = tid & 63;
    e_l[tid] = emb[(size_t)g * CN + tid];
    __syncthreads();
    float p = pb1[tid], v = vb1[tid];
    for (int k = 0; k < CN; ++k) {
        float e = e_l[k];
        p += e * pW1[k * CN + tid];
        v += e * vW1[k * CN + tid];
    }
    float sum = p, sq = p * p;
    #pragma unroll
    for (int o = 32; o; o >>= 1) { sum += __shfl_xor(sum, o); sq += __shfl_xor(sq, o); }
    if (lane == 0) { rsum[wid] = sum; rsq[wid] = sq; }
    __syncthreads();
    sum = rsum[0] + rsum[1] + rsum[2] + rsum[3];
    sq  = rsq[0] + rsq[1] + rsq[2] + rsq[3];
    float mu = sum / CN;
    float var = sq / CN - mu * mu;
    float inv = rsqrtf(var + 1e-5f);
    float t1v = fmaxf((p - mu) * inv * plng[tid] + plnb[tid], 0.f);
    unsigned short th = f2bf(t1v);
    t1h[(size_t)g * CN + tid] = th;
    t1l[(size_t)g * CN + tid] = f2bf(t1v - bf2f(th));
    float contrib = fmaxf(v, 0.f) * vW2[tid];
    __syncthreads();
    #pragma unroll
    for (int o = 32; o; o >>= 1) contrib += __shfl_xor(contrib, o);
    if (lane == 0) rsum[wid] = contrib;
    __syncthreads();
    if (tid == 0)
        value_out[g] = tanhf(rsum[0] + rsum[1] + rsum[2] + rsum[3] + vb2[0]);
}

// ---------------------------------------------------------------------------
extern "C" void kernel_launch(void* const* d_in, const int* in_sizes, int n_in,
                              void* d_out, int out_size, void* d_ws, size_t ws_size,
                              hipStream_t stream) {
    const float* x        = (const float*)d_in[0];
    const int*   ei       = (const int*)d_in[1];
    const float* W_emb    = (const float*)d_in[4];
    const float* b_emb    = (const float*)d_in[5];
    const float* pos_emb  = (const float*)d_in[6];
    const float* gat_Wsrc = (const float*)d_in[7];
    const float* gat_Wdst = (const float*)d_in[8];
    const float* gat_att  = (const float*)d_in[9];
    const float* gat_bias = (const float*)d_in[10];
    const float* ln_g     = (const float*)d_in[11];
    const float* ln_b     = (const float*)d_in[12];
    const float* gW1      = (const float*)d_in[13];
    const float* gb1      = (const float*)d_in[14];
    const float* gW2      = (const float*)d_in[15];
    const float* gb2      = (const float*)d_in[16];
    const float* pW1      = (const float*)d_in[17];
    const float* pb1      = (const float*)d_in[18];
    const float* p_ln_g   = (const float*)d_in[19];
    const float* p_ln_b   = (const float*)d_in[20];
    const float* pW2      = (const float*)d_in[21];
    const float* pb2      = (const float*)d_in[22];
    const float* vW1      = (const float*)d_in[23];
    const float* vb1      = (const float*)d_in[24];
    const float* vW2      = (const float*)d_in[25];
    const float* vb2      = (const float*)d_in[26];

    const int N = in_sizes[2];      // 22528
    const int E = in_sizes[1] / 2;  // 405504
    const int G = N / KPG;          // 256
    const int NB_SC = (N + 1023) / 1024;

    const int NB_CAT = 32;                        // 512/16
    const int NB_G1  = 8;                         // 128/16
    const int GY_POL = (ACT_DIM + 127) / 128;     // 37
    const int NB_POL = GY_POL * 8;                // 296 (padded)

    char* ws = (char*)d_ws;
    size_t off = 0;
    auto alloc = [&](size_t nbytes) {
        void* pp = ws + off;
        off = (off + nbytes + 255) & ~(size_t)255;
        return pp;
    };
    float* h      = (float*)alloc((size_t)N * CN * 4);
    unsigned short* hh = (unsigned short*)alloc((size_t)N * CN * 2);
    unsigned short* hl = (unsigned short*)alloc((size_t)N * CN * 2);
    float* xlr    = (float*)alloc((size_t)N * 512 * 4);       // reused as gtmp
    unsigned short* WcatH = (unsigned short*)alloc((size_t)4 * 8 * NB_CAT * 512 * 2);
    unsigned short* WcatL = (unsigned short*)alloc((size_t)4 * 8 * NB_CAT * 512 * 2);
    unsigned short* gW1H  = (unsigned short*)alloc((size_t)8 * NB_G1 * 512 * 2);
    unsigned short* gW1L  = (unsigned short*)alloc((size_t)8 * NB_G1 * 512 * 2);
    unsigned short* pW2H  = (unsigned short*)alloc((size_t)8 * NB_POL * 512 * 2);
    unsigned short* pW2L  = (unsigned short*)alloc((size_t)8 * NB_POL * 512 * 2);
    float* gate   = (float*)alloc((size_t)N * 4);
    float* emb    = (float*)alloc((size_t)G * CN * 4);
    unsigned short* t1h = (unsigned short*)alloc((size_t)G * CN * 2);
    unsigned short* t1l = (unsigned short*)alloc((size_t)G * CN * 2);
    int*   rowptr = (int*)alloc((size_t)(N + 1) * 4);
    int*   cnt    = (int*)alloc((size_t)N * 4);
    int*   cursor = (int*)alloc((size_t)N * 4);
    int*   btot   = (int*)alloc((size_t)64 * 4);
    int*   csrcB  = (int*)alloc((size_t)E * 4);
    float* gtmp   = xlr;

    const int* e_src = ei;
    const int* e_dst = ei + E;

    hipMemsetAsync(cnt, 0, (size_t)N * 4, stream);
    hipMemsetAsync(cursor, 0, (size_t)N * 4, stream);
    count_kernel<<<(E + 255) / 256, 256, 0, stream>>>(e_dst, cnt, E);
    scan1_kernel<<<NB_SC, 1024, 0, stream>>>(cnt, rowptr, btot, N);
    scan2_kernel<<<1, 64, 0, stream>>>(btot, NB_SC);
    scan3_kernel<<<(N + 1024) / 1024, 1024, 0, stream>>>(rowptr, btot, N, NB_SC);
    fill_kernel<<<(E + 255) / 256, 256, 0, stream>>>(e_src, e_dst, rowptr, cursor, csrcB, E);

    embed_kernel<<<N / 16, 256, 0, stream>>>(x, W_emb, b_emb, pos_emb, h, hh, hl);

    {
        int totc = 8 * NB_CAT * 512;
        dim3 gw((totc + 255) / 256, 4);
        wconv_cat_kernel<<<gw, 256, 0, stream>>>(gat_Wsrc, gat_Wdst, WcatH, WcatL, NB_CAT, totc);
        int totg = 8 * NB_G1 * 512;
        wconv_kernel<<<(totg + 255) / 256, 256, 0, stream>>>(gW1, gW1H, gW1L, GATE_DIM, NB_G1, totg);
        int totp = 8 * NB_POL * 512;
        wconv_kernel<<<(totp + 255) / 256, 256, 0, stream>>>(pW2, pW2H, pW2L, ACT_DIM, NB_POL, totp);
    }

    for (int l = 0; l < 4; ++l) {
        size_t wo = (size_t)l * 8 * NB_CAT * 512;
        dim3 g1(N / 128, 512 / 128);
        mgemm<false><<<g1, 256, 0, stream>>>(hh, hl, WcatH + wo, WcatL + wo, nullptr,
                                             xlr, N, 512, NB_CAT, CN);
        gat_agg<<<N / 4, 256, 0, stream>>>(xlr, rowptr, csrcB, gat_att + l * CN,
                                           gat_bias + l * CN, ln_g + l * CN, ln_b + l * CN,
                                           h, hh, hl);
    }

    // gate MLP
    {
        dim3 g1(N / 128, 1);
        mgemm<true><<<g1, 256, 0, stream>>>(hh, hl, gW1H, gW1L, gb1, gtmp, N, GATE_DIM, NB_G1, CN);
        gate2_kernel<<<(N + 3) / 4, 256, 0, stream>>>(gtmp, gW2, gb2, gate, N);
    }
    pool_kernel<<<G, 256, 0, stream>>>(gate, h, emb);

    float* policy = (float*)d_out;
    float* value  = (float*)d_out + (size_t)G * ACT_DIM;
    head_kernel<<<G, 256, 0, stream>>>(emb, pW1, pb1, p_ln_g, p_ln_b,
                                       vW1, vb1, vW2, vb2, t1h, t1l, value);
    dim3 g2(G / 128, GY_POL);
    mgemm<true><<<g2, 256, 0, stream>>>(t1h, t1l, pW2H, pW2L, pb2, policy, G, ACT_DIM, NB_POL, CN);
}